// Round 9
// baseline (196.054 us; speedup 1.0000x reference)
//
#include <hip/hip_runtime.h>
#include <hip/hip_bf16.h>

#define PI_F 3.14159265358979323846f

// Loader insurance: keep a kernel with the stub's exact name (not launched).
__global__ void Static_82300163326800_kernel() {}

typedef _Float16 f16x8 __attribute__((ext_vector_type(8)));
typedef _Float16 f16x4 __attribute__((ext_vector_type(4)));
typedef float f32x4 __attribute__((ext_vector_type(4)));

// ===================== shared gate-matrix helpers =====================
struct M2 { float2 m00, m01, m10, m11; };

__device__ __forceinline__ float2 cmul2(float2 a, float2 b) {
    return make_float2(a.x*b.x - a.y*b.y, a.x*b.y + a.y*b.x);
}
__device__ __forceinline__ float2 cadd2(float2 a, float2 b) {
    return make_float2(a.x+b.x, a.y+b.y);
}
__device__ __forceinline__ float2 shx(float2 v, int m) {
    return make_float2(__shfl_xor(v.x, m), __shfl_xor(v.y, m));
}
__device__ __forceinline__ M2 m2mul(M2 b, M2 a) {   // gate a first, then b => b*a
    return { cadd2(cmul2(b.m00,a.m00), cmul2(b.m01,a.m10)),
             cadd2(cmul2(b.m00,a.m01), cmul2(b.m01,a.m11)),
             cadd2(cmul2(b.m10,a.m00), cmul2(b.m11,a.m10)),
             cadd2(cmul2(b.m10,a.m01), cmul2(b.m11,a.m11)) };
}
__device__ __forceinline__ M2 mrx(float th) {
    float s, c; __sincosf(0.5f * th, &s, &c);
    return { make_float2(c,0.f), make_float2(0.f,-s), make_float2(0.f,-s), make_float2(c,0.f) };
}
__device__ __forceinline__ M2 mry(float th) {
    float s, c; __sincosf(0.5f * th, &s, &c);
    return { make_float2(c,0.f), make_float2(-s,0.f), make_float2(s,0.f), make_float2(c,0.f) };
}
__device__ __forceinline__ M2 mrot(float phi, float th, float om) {
    float s, c;  __sincosf(0.5f * th, &s, &c);
    float sa, ca; __sincosf(0.5f * (phi + om), &sa, &ca);
    float sd, cd; __sincosf(0.5f * (phi - om), &sd, &cd);
    return { make_float2(ca*c, -sa*c), make_float2(-cd*s, -sd*s),
             make_float2(cd*s, -sd*s), make_float2(ca*c,  sa*c) };
}
__device__ __forceinline__ M2 mu2(float phi, float lam) {
    const float r = 0.7071067811865476f;
    float sl, cl;   __sincosf(lam, &sl, &cl);
    float sp, cp;   __sincosf(phi, &sp, &cp);
    float spl, cpl; __sincosf(phi + lam, &spl, &cpl);
    return { make_float2(r,0.f), make_float2(-r*cl,-r*sl),
             make_float2(r*cp, r*sp), make_float2(r*cpl, r*spl) };
}
__device__ __forceinline__ M2 mu3(float th, float phi, float lam) {
    float s, c;     __sincosf(0.5f * th, &s, &c);
    float sl, cl;   __sincosf(lam, &sl, &cl);
    float sp, cp;   __sincosf(phi, &sp, &cp);
    float spl, cpl; __sincosf(phi + lam, &spl, &cpl);
    return { make_float2(c,0.f), make_float2(-cl*s,-sl*s),
             make_float2(cp*s, sp*s), make_float2(cpl*c, spl*c) };
}

// ===================== per-wave register circuit primitives =====================
// Amplitude index i = (lane<<4) | r.  wire w<=5 -> lane bit (5-w); w>=6 -> r bit (9-w).

__device__ __forceinline__ void applyL(float2* s, M2 m, int lane, int q) {
    const int bitv = (lane >> q) & 1;
    const float2 cA = bitv ? m.m11 : m.m00;
    const float2 cB = bitv ? m.m10 : m.m01;
    float ox[16], oy[16];
#pragma unroll
    for (int r = 0; r < 16; ++r) {
        ox[r] = __shfl_xor(s[r].x, 1 << q);
        oy[r] = __shfl_xor(s[r].y, 1 << q);
    }
#pragma unroll
    for (int r = 0; r < 16; ++r)
        s[r] = make_float2(cA.x*s[r].x - cA.y*s[r].y + cB.x*ox[r] - cB.y*oy[r],
                           cA.x*s[r].y + cA.y*s[r].x + cB.x*oy[r] + cB.y*ox[r]);
}
template<int P>
__device__ __forceinline__ void applyR(float2* s, M2 m) {
#pragma unroll
    for (int r0 = 0; r0 < 16; ++r0) {
        if (r0 & (1 << P)) continue;
        const int r1 = r0 | (1 << P);
        float2 a = s[r0], d = s[r1];
        s[r0] = cadd2(cmul2(m.m00, a), cmul2(m.m01, d));
        s[r1] = cadd2(cmul2(m.m10, a), cmul2(m.m11, d));
    }
}
__device__ __forceinline__ void diagL(float2* s, float2 d0, float2 d1, int lane, int q) {
    const int bitv = (lane >> q) & 1;
    const float2 f = bitv ? d1 : d0;
#pragma unroll
    for (int r = 0; r < 16; ++r) s[r] = cmul2(f, s[r]);
}
template<int P>
__device__ __forceinline__ void diagR(float2* s, float2 d0, float2 d1) {
#pragma unroll
    for (int r = 0; r < 16; ++r) {
        const float2 f = (r & (1 << P)) ? d1 : d0;
        s[r] = cmul2(f, s[r]);
    }
}
__device__ __forceinline__ void cnotLL(float2* s, int lane, int qc, int qw) {
    const int cb = (lane >> qc) & 1;
    float ox[16], oy[16];
#pragma unroll
    for (int r = 0; r < 16; ++r) {
        ox[r] = __shfl_xor(s[r].x, 1 << qw);
        oy[r] = __shfl_xor(s[r].y, 1 << qw);
    }
#pragma unroll
    for (int r = 0; r < 16; ++r)
        s[r] = cb ? make_float2(ox[r], oy[r]) : s[r];
}
__device__ __forceinline__ void capplyLL(float2* s, M2 m, int lane, int qc, int qw) {
    const int cb = (lane >> qc) & 1, tb = (lane >> qw) & 1;
    float2 cA = tb ? m.m11 : m.m00;
    float2 cB = tb ? m.m10 : m.m01;
    cA = cb ? cA : make_float2(1.f, 0.f);
    cB = cb ? cB : make_float2(0.f, 0.f);
    float ox[16], oy[16];
#pragma unroll
    for (int r = 0; r < 16; ++r) {
        ox[r] = __shfl_xor(s[r].x, 1 << qw);
        oy[r] = __shfl_xor(s[r].y, 1 << qw);
    }
#pragma unroll
    for (int r = 0; r < 16; ++r)
        s[r] = make_float2(cA.x*s[r].x - cA.y*s[r].y + cB.x*ox[r] - cB.y*oy[r],
                           cA.x*s[r].y + cA.y*s[r].x + cB.x*oy[r] + cB.y*ox[r]);
}
__device__ __forceinline__ void cdiagLL(float2* s, float2 d0, float2 d1, int lane, int qc, int qw) {
    const int cb = (lane >> qc) & 1, tb = (lane >> qw) & 1;
    float2 f = tb ? d1 : d0;
    f = cb ? f : make_float2(1.f, 0.f);
#pragma unroll
    for (int r = 0; r < 16; ++r) s[r] = cmul2(f, s[r]);
}
template<int P>
__device__ __forceinline__ void capplyRL(float2* s, M2 m, int lane, int qc) {
    const int cb = (lane >> qc) & 1;
#pragma unroll
    for (int r0 = 0; r0 < 16; ++r0) {
        if (r0 & (1 << P)) continue;
        const int r1 = r0 | (1 << P);
        float2 a = s[r0], d = s[r1];
        float2 na = cadd2(cmul2(m.m00, a), cmul2(m.m01, d));
        float2 nd = cadd2(cmul2(m.m10, a), cmul2(m.m11, d));
        s[r0] = cb ? na : a;
        s[r1] = cb ? nd : d;
    }
}

// ============ per-wave circuit kernel (fc2 fused): 1 wave = 1 sample ============
__global__ __launch_bounds__(256, 1) void circuit_wave(
    const float* __restrict__ part, const float* __restrict__ fb1,
    const float* __restrict__ fw2, const float* __restrict__ fb2,
    const float* __restrict__ q_rx, const float* __restrict__ q_rz3,
    const float* __restrict__ q_ps6, const float* __restrict__ q_rot7,
    const float* __restrict__ q_mrz8, const float* __restrict__ q_crx9,
    const float* __restrict__ q_cry10, const float* __restrict__ q_crz11,
    const float* __restrict__ q_u2, const float* __restrict__ q_u3,
    float* __restrict__ out)
{
    const int t = threadIdx.x, lane = t & 63, wv = t >> 6;
    const int b = blockIdx.x * 4 + wv;

    // fused fc2: h = relu(fb1 + sum_kb part), angles = 2pi*sigmoid(fw2 h + fb2)
    float h0 = fb1[lane], h1 = fb1[lane + 64];
#pragma unroll
    for (int kb = 0; kb < 16; ++kb) {
        h0 += part[(size_t)kb * 131072 + b * 128 + lane];
        h1 += part[(size_t)kb * 131072 + b * 128 + lane + 64];
    }
    h0 = fmaxf(h0, 0.f); h1 = fmaxf(h1, 0.f);
    float ang[10];
#pragma unroll
    for (int j = 0; j < 10; ++j) {
        float v = h0 * fw2[j * 128 + lane] + h1 * fw2[j * 128 + 64 + lane];
        v += __shfl_xor(v, 1); v += __shfl_xor(v, 2); v += __shfl_xor(v, 4);
        v += __shfl_xor(v, 8); v += __shfl_xor(v, 16); v += __shfl_xor(v, 32);
        ang[j] = 6.283185307179586f / (1.f + expf(-(fb2[j] + v)));
    }

    float2 s[16];
#pragma unroll
    for (int r = 0; r < 16; ++r) s[r] = make_float2(0.f, 0.f);
    if (lane == 0) s[0].x = 1.f;

    // L1: trainable RX on wires 0..9
    applyL(s, mrx(q_rx[0]), lane, 5);
    applyL(s, mrx(q_rx[1]), lane, 4);
    applyL(s, mrx(q_rx[2]), lane, 3);
    applyL(s, mrx(q_rx[3]), lane, 2);
    applyL(s, mrx(q_rx[4]), lane, 1);
    applyL(s, mrx(q_rx[5]), lane, 0);
    applyR<3>(s, mrx(q_rx[6]));
    applyR<2>(s, mrx(q_rx[7]));
    applyR<1>(s, mrx(q_rx[8]));
    applyR<0>(s, mrx(q_rx[9]));
    // L2 fused: RY(ang[k]) on k, then the ten commuting RX(ang0) -> RX(10*ang0)
    applyL(s, mry(ang[0]), lane, 5);
    applyL(s, mry(ang[1]), lane, 4);
    applyL(s, mry(ang[2]), lane, 3);
    applyL(s, mry(ang[3]), lane, 2);
    applyL(s, mry(ang[4]), lane, 1);
    applyL(s, mry(ang[5]), lane, 0);
    applyR<3>(s, mry(ang[6]));
    applyR<2>(s, mry(ang[7]));
    applyR<1>(s, mry(ang[8]));
    applyR<0>(s, mry(ang[9]));
    applyL(s, mrx(10.f * ang[0]), lane, 5);
    // CNOT ring (k,k+1) then (9,0)
    cnotLL(s, lane, 5, 4);
    cnotLL(s, lane, 4, 3);
    cnotLL(s, lane, 3, 2);
    cnotLL(s, lane, 2, 1);
    cnotLL(s, lane, 1, 0);
    { // (5,6): ctrl lane bit0, target r bit3
        const int cb = lane & 1;
#pragma unroll
        for (int r0 = 0; r0 < 8; ++r0) {
            float2 a = s[r0], d = s[r0 + 8];
            s[r0] = cb ? d : a; s[r0 + 8] = cb ? a : d;
        }
    }
    { // (6,7)
        float2 u;
        u = s[8];  s[8]  = s[12]; s[12] = u;
        u = s[9];  s[9]  = s[13]; s[13] = u;
        u = s[10]; s[10] = s[14]; s[14] = u;
        u = s[11]; s[11] = s[15]; s[15] = u;
    }
    { // (7,8)
        float2 u;
        u = s[4];  s[4]  = s[6];  s[6]  = u;
        u = s[5];  s[5]  = s[7];  s[7]  = u;
        u = s[12]; s[12] = s[14]; s[14] = u;
        u = s[13]; s[13] = s[15]; s[15] = u;
    }
    { // (8,9)
        float2 u;
        u = s[2];  s[2]  = s[3];  s[3]  = u;
        u = s[6];  s[6]  = s[7];  s[7]  = u;
        u = s[10]; s[10] = s[11]; s[11] = u;
        u = s[14]; s[14] = s[15]; s[15] = u;
    }
    { // (9,0): r bit0 ctrl, target lane bit5
        float ox[8], oy[8];
#pragma unroll
        for (int k = 0; k < 8; ++k) {
            ox[k] = __shfl_xor(s[2*k+1].x, 32);
            oy[k] = __shfl_xor(s[2*k+1].y, 32);
        }
#pragma unroll
        for (int k = 0; k < 8; ++k) s[2*k+1] = make_float2(ox[k], oy[k]);
    }

    applyL(s, mrx(ang[1]), lane, 4);
    applyL(s, mrx(-PI_F / 4.f), lane, 0);
    applyL(s, mry(ang[2]), lane, 3);
    { float sn, cs; __sincosf(0.5f * ang[3], &sn, &cs);
      diagL(s, make_float2(cs,-sn), make_float2(cs,sn), lane, 2); }          // RZ on 3
    diagL(s, make_float2(1.f,0.f), make_float2(0.f,1.f), lane, 1);           // S on 4
    diagL(s, make_float2(1.f,0.f),
          make_float2(0.7071067811865476f, 0.7071067811865476f), lane, 0);   // T on 5
    { float sn, cs; __sincosf(0.5f * q_rz3[0], &sn, &cs);
      diagR<3>(s, make_float2(cs,-sn), make_float2(cs,sn)); }                // RZ on 6
    { M2 m = { make_float2(0.5f,0.5f), make_float2(0.5f,-0.5f),
               make_float2(0.5f,-0.5f), make_float2(0.5f,0.5f) };
      applyR<2>(s, m); }                                                     // SX on 7
    { // CZ;CNOT;CY on (0,5) fused: phase -i iff wire0 bit = 1
        const int cb = (lane >> 5) & 1;
#pragma unroll
        for (int r = 0; r < 16; ++r)
            s[r] = cb ? make_float2(s[r].y, -s[r].x) : s[r];
    }
    { // CY(3,8): ctrl lane bit2, target r bit1
        const int cb = (lane >> 2) & 1;
#pragma unroll
        for (int r0 = 0; r0 < 16; ++r0) {
            if (r0 & 2) continue;
            const int r1 = r0 | 2;
            float2 a = s[r0], d = s[r1];
            float2 na = make_float2(d.y, -d.x);
            float2 nd = make_float2(-a.y, a.x);
            s[r0] = cb ? na : a; s[r1] = cb ? nd : d;
        }
    }
    { // SWAP(2,3): lane bits 3,2
        const int pr = ((lane >> 3) & 1) ^ ((lane >> 2) & 1);
        float ox[16], oy[16];
#pragma unroll
        for (int r = 0; r < 16; ++r) {
            ox[r] = __shfl_xor(s[r].x, 12);
            oy[r] = __shfl_xor(s[r].y, 12);
        }
#pragma unroll
        for (int r = 0; r < 16; ++r)
            s[r] = pr ? make_float2(ox[r], oy[r]) : s[r];
    }
    { // CSWAP(4;5,6): ctrl lane bit1; swap lane bit0 <-> r bit3
        float ox[16], oy[16];
#pragma unroll
        for (int r = 0; r < 16; ++r) {
            ox[r] = __shfl_xor(s[r ^ 8].x, 1);
            oy[r] = __shfl_xor(s[r ^ 8].y, 1);
        }
        const int cb = (lane >> 1) & 1, lb = lane & 1;
#pragma unroll
        for (int r = 0; r < 16; ++r) {
            const int pr = cb & ((r & 8) ? (1 - lb) : lb);
            s[r] = pr ? make_float2(ox[r], oy[r]) : s[r];
        }
    }
    { // TOFF(8,5;0): ctrl r bit1 & lane bit0; target lane bit5
        const int lb = lane & 1;
        float ox[8], oy[8];
        const int idx8[8] = {2,3,6,7,10,11,14,15};
#pragma unroll
        for (int k = 0; k < 8; ++k) {
            ox[k] = __shfl_xor(s[idx8[k]].x, 32);
            oy[k] = __shfl_xor(s[idx8[k]].y, 32);
        }
#pragma unroll
        for (int k = 0; k < 8; ++k)
            s[idx8[k]] = lb ? make_float2(ox[k], oy[k]) : s[idx8[k]];
    }
    { float sn, cs; __sincosf(q_ps6[0], &sn, &cs);
      diagR<1>(s, make_float2(1.f,0.f), make_float2(cs,sn)); }               // PS on 8
    { float sn, cs; __sincosf(ang[7], &sn, &cs);
      diagR<2>(s, make_float2(1.f,0.f), make_float2(cs,sn)); }               // PS on 7
    applyL(s, mrot(q_rot7[0], q_rot7[1], q_rot7[2]), lane, 1);               // ROT on 4
    applyL(s, mrot(ang[6], ang[7], ang[8]), lane, 0);                        // ROT on 5
    { // multiRZ(q_mrz8) wires (2,3,4,5,6)
        float sh, ch; __sincosf(0.5f * q_mrz8[0], &sh, &ch);
        const int lp = __popc(lane & 0xF) & 1;
        const float sg0 = lp ? sh : -sh;
#pragma unroll
        for (int r = 0; r < 16; ++r) {
            const float sg = (r & 8) ? -sg0 : sg0;
            float2 a = s[r];
            s[r] = make_float2(ch*a.x - sg*a.y, ch*a.y + sg*a.x);
        }
    }
    { // multiRZ(ang[5]) wires (3,4,6,7,8)
        float sh, ch; __sincosf(0.5f * ang[5], &sh, &ch);
        const int lp = __popc(lane & 6) & 1;
        const float sg0 = lp ? sh : -sh;
#pragma unroll
        for (int r = 0; r < 16; ++r) {
            const int rp = __popc(r & 14) & 1;
            const float sg = rp ? -sg0 : sg0;
            float2 a = s[r];
            s[r] = make_float2(ch*a.x - sg*a.y, ch*a.y + sg*a.x);
        }
    }
    capplyLL(s, mrx(ang[6]), lane, 5, 4);       // CRX(0,1)
    capplyLL(s, mrx(q_crx9[0]), lane, 1, 0);    // CRX(4,5)
    capplyLL(s, mry(ang[6]), lane, 5, 4);       // CRY(0,1)
    capplyLL(s, mry(q_cry10[0]), lane, 1, 0);   // CRY(4,5)
    { float sn, cs; __sincosf(0.5f * ang[6], &sn, &cs);
      cdiagLL(s, make_float2(cs,-sn), make_float2(cs,sn), lane, 5, 4); }     // CRZ(0,1)
    { float sn, cs; __sincosf(0.5f * q_crz11[0], &sn, &cs);
      cdiagLL(s, make_float2(cs,-sn), make_float2(cs,sn), lane, 1, 0); }     // CRZ(4,5)
    capplyRL<3>(s, mrot(-PI_F/4.f, PI_F/4.f, PI_F/2.f), lane, 0);            // CROT(5,6)
    { // CROT(7,8): pairs {4,5,12,13}
        M2 m = mrot(ang[5], ang[6], ang[7]);
        const int idx4[4] = {4, 5, 12, 13};
#pragma unroll
        for (int k = 0; k < 4; ++k) {
            const int r0 = idx4[k], r1 = r0 | 2;
            float2 a = s[r0], d = s[r1];
            s[r0] = cadd2(cmul2(m.m00, a), cmul2(m.m01, d));
            s[r1] = cadd2(cmul2(m.m10, a), cmul2(m.m11, d));
        }
    }
    { float sn, cs; __sincosf(PI_F / 7.f, &sn, &cs);
      diagL(s, make_float2(1.f,0.f), make_float2(cs,sn), lane, 4); }         // U1 on 1
    { float sn, cs; __sincosf(ang[9], &sn, &cs);
      diagL(s, make_float2(1.f,0.f), make_float2(cs,sn), lane, 3); }         // PS on 2
    applyR<1>(s, mu2(q_u2[0], q_u2[1]));                                     // U2 on 8
    applyL(s, mu2(ang[0], ang[1]), lane, 1);                                 // U2 on 4
    applyL(s, m2mul(mu3(ang[4], ang[5], ang[6]),
                    mu3(q_u3[0], q_u3[1], q_u3[2])), lane, 0);               // U3*U3 on 5
    cnotLL(s, lane, 4, 3);                                                   // CNOT(1,2)

    // <Y_w> then log_softmax
    float ev[10];
#pragma unroll
    for (int w = 0; w < 6; ++w) {
        const int q = 5 - w;
        const int bitv = (lane >> q) & 1;
        float ox[16], oy[16];
#pragma unroll
        for (int r = 0; r < 16; ++r) {
            ox[r] = __shfl_xor(s[r].x, 1 << q);
            oy[r] = __shfl_xor(s[r].y, 1 << q);
        }
        float acc = 0.f;
#pragma unroll
        for (int r = 0; r < 16; ++r)
            acc += s[r].x * oy[r] - s[r].y * ox[r];
        ev[w] = bitv ? 0.f : 2.f * acc;
    }
#pragma unroll
    for (int w = 6; w < 10; ++w) {
        const int P = 9 - w;
        float acc = 0.f;
#pragma unroll
        for (int r0 = 0; r0 < 16; ++r0) {
            if (r0 & (1 << P)) continue;
            const int r1 = r0 | (1 << P);
            acc += s[r0].x * s[r1].y - s[r0].y * s[r1].x;
        }
        ev[w] = 2.f * acc;
    }
#pragma unroll
    for (int w = 0; w < 10; ++w) {
        float v = ev[w];
        v += __shfl_down(v, 32); v += __shfl_down(v, 16); v += __shfl_down(v, 8);
        v += __shfl_down(v, 4);  v += __shfl_down(v, 2);  v += __shfl_down(v, 1);
        ev[w] = v;
    }
    if (lane == 0) {
        float mx = ev[0];
#pragma unroll
        for (int i = 1; i < 10; ++i) mx = fmaxf(mx, ev[i]);
        float ss = 0.f;
#pragma unroll
        for (int i = 0; i < 10; ++i) ss += expf(ev[i] - mx);
        const float ls = logf(ss);
#pragma unroll
        for (int i = 0; i < 10; ++i) out[b * 10 + i] = ev[i] - mx - ls;
    }
}

// ============ prep (merged): fw1 -> f16 and w2 -> transposed f16 ============
__global__ __launch_bounds__(256) void prep_all(
    const float* __restrict__ fw1, _Float16* __restrict__ fw1h,
    const float* __restrict__ w2, _Float16* __restrict__ w2t)
{
    const int blk = blockIdx.x;
    if (blk < 1152) {
        int i = blk * 256 + threadIdx.x;   // 294912 float4 groups
        float4 v = ((const float4*)fw1)[i];
        f16x4 o = { (_Float16)v.x, (_Float16)v.y, (_Float16)v.z, (_Float16)v.w };
        *(f16x4*)(fw1h + i * 4) = o;
    } else {
        int idx = (blk - 1152) * 256 + threadIdx.x;
        if (idx < 18432) {
            int oc = idx / 288, r = idx - oc * 288;
            int s = r >> 5, ic = r & 31;
            w2t[idx] = (_Float16)w2[oc * 288 + ic * 9 + s];
        }
    }
}

// ===================== MFMA convnet =====================
// conv1: thread = (pixel-slot = t>>2, ic-group = t&3 of 8 ics); weights in regs via
// LDS-transposed w1t[k][ic]; per pixel: 9 xs reads, 72 FMA, one packed ds_write_b128.
__global__ __launch_bounds__(256, 2) void convnet_mfma(
    const float* __restrict__ x, const float* __restrict__ w1, const float* __restrict__ b1,
    const _Float16* __restrict__ w2t, const float* __restrict__ b2,
    _Float16* __restrict__ flat)
{
    __shared__ float xs[784];
    __shared__ __align__(16) float w1t[288];              // [k][ic] transposed
    __shared__ __align__(16) _Float16 h1t[676 * 40];      // [pix][ic], stride 40
    const int n = blockIdx.x, t = threadIdx.x;
    const int lane = t & 63, wv = t >> 6;
    const int m = lane & 15, quad = lane >> 4;

    for (int i = t; i < 784; i += 256) xs[i] = x[n * 784 + i];
    // r8 BUG FIX: 288 entries under a 256-thread block needs a grid-stride loop;
    // `if (t < 288)` left w1t[256..287] (ics 28..31) uninitialized -> absmax 0.14.
    for (int i = t; i < 288; i += 256) {
        int ic = i / 9, k = i - ic * 9;
        w1t[k * 32 + ic] = w1[i];
    }
    __syncthreads();

    // conv1
    {
        const int icg = t & 3;
        float w[9][8];
#pragma unroll
        for (int k = 0; k < 9; ++k) {
            float4 a = *(const float4*)&w1t[k * 32 + icg * 8];
            float4 bsec = *(const float4*)&w1t[k * 32 + icg * 8 + 4];
            w[k][0] = a.x; w[k][1] = a.y; w[k][2] = a.z; w[k][3] = a.w;
            w[k][4] = bsec.x; w[k][5] = bsec.y; w[k][6] = bsec.z; w[k][7] = bsec.w;
        }
        float bb[8];
#pragma unroll
        for (int j = 0; j < 8; ++j) bb[j] = b1[icg * 8 + j];
        for (int pix = t >> 2; pix < 676; pix += 64) {
            const int yy = pix / 26, xx = pix - yy * 26;
            const float* xp = xs + yy * 28 + xx;
            float acc[8];
#pragma unroll
            for (int j = 0; j < 8; ++j) acc[j] = bb[j];
#pragma unroll
            for (int ky = 0; ky < 3; ++ky)
#pragma unroll
                for (int kx = 0; kx < 3; ++kx) {
                    const float xv = xp[ky * 28 + kx];
                    const int k = ky * 3 + kx;
#pragma unroll
                    for (int j = 0; j < 8; ++j) acc[j] += xv * w[k][j];
                }
            f16x8 o;
#pragma unroll
            for (int j = 0; j < 8; ++j) o[j] = (_Float16)fmaxf(acc[j], 0.f);
            *(f16x8*)&h1t[pix * 40 + icg * 8] = o;
        }
    }

    // B fragments loaded after conv1 (frees VGPRs during conv1; L2-resident)
    f16x8 bq[9][4];
#pragma unroll
    for (int s = 0; s < 9; ++s)
#pragma unroll
        for (int nt = 0; nt < 4; ++nt)
            bq[s][nt] = *(const f16x8*)(w2t + (nt * 16 + m) * 288 + s * 32 + quad * 8);

    __syncthreads();

    float bb2[4];
#pragma unroll
    for (int nt = 0; nt < 4; ++nt) bb2[nt] = b2[nt * 16 + m];

    _Float16* outp = flat + (size_t)n * 9216;

    for (int q = 0; q < 9; ++q) {
        const int mt = wv + q * 4;
        const int a = mt / 3, b3 = mt - a * 3;
        const int y0 = 2 * a + (m & 1), x0 = 8 * b3 + (m >> 1);
        f32x4 acc[4] = {};
#pragma unroll
        for (int s = 0; s < 9; ++s) {
            const int ky = s / 3, kx = s - ky * 3;
            f16x8 af = *(const f16x8*)&h1t[((y0 + ky) * 26 + x0 + kx) * 40 + quad * 8];
#pragma unroll
            for (int nt = 0; nt < 4; ++nt)
                acc[nt] = __builtin_amdgcn_mfma_f32_16x16x32_f16(af, bq[s][nt], acc[nt], 0, 0, 0);
        }
        const int pooled_idx = a * 12 + 4 * b3 + quad;
#pragma unroll
        for (int nt = 0; nt < 4; ++nt) {
            float v = fmaxf(fmaxf(acc[nt][0], acc[nt][1]), fmaxf(acc[nt][2], acc[nt][3]));
            outp[(nt * 16 + m) * 144 + pooled_idx] = (_Float16)fmaxf(v + bb2[nt], 0.f);
        }
    }
}

// ===================== fc1 MFMA: [1024,9216]f16 @ [128,9216]^T f16, K split 16 ======
__global__ __launch_bounds__(256) void fc1_mfma(
    const _Float16* __restrict__ A, const _Float16* __restrict__ B, float* __restrict__ part)
{
    const int m0 = blockIdx.x * 64, n0 = blockIdx.y * 64, kb = blockIdx.z;
    const int t = threadIdx.x, lane = t & 63, wv = t >> 6;
    const int r = lane & 15, quad = lane >> 4;
    const _Float16* ap = A + (size_t)(m0 + wv * 16 + r) * 9216 + kb * 576 + quad * 8;
    const _Float16* bp = B + (size_t)(n0 + r) * 9216 + kb * 576 + quad * 8;
    f32x4 acc[4] = {};
    for (int ks = 0; ks < 576; ks += 32) {
        f16x8 af = *(const f16x8*)(ap + ks);
#pragma unroll
        for (int nt = 0; nt < 4; ++nt) {
            f16x8 bfr = *(const f16x8*)(bp + (size_t)nt * 16 * 9216 + ks);
            acc[nt] = __builtin_amdgcn_mfma_f32_16x16x32_f16(af, bfr, acc[nt], 0, 0, 0);
        }
    }
    float* pp = part + (size_t)kb * 131072 + (size_t)(m0 + wv * 16 + quad * 4) * 128 + n0 + r;
#pragma unroll
    for (int nt = 0; nt < 4; ++nt)
#pragma unroll
        for (int reg = 0; reg < 4; ++reg)
            pp[reg * 128 + nt * 16] = acc[nt][reg];
}

// ===================== FALLBACK: fully fused fp32, zero workspace =====================
__device__ __forceinline__ int ins1(int x, int p) {
    return ((x >> p) << (p + 1)) | (x & ((1 << p) - 1));
}
__device__ __forceinline__ void apply1(float2* st, int t, int w, M2 m) {
    int p = 9 - w;
    int i0 = ins1(t, p), i1 = i0 | (1 << p);
    float2 a = st[i0], d = st[i1];
    st[i0] = cadd2(cmul2(m.m00, a), cmul2(m.m01, d));
    st[i1] = cadd2(cmul2(m.m10, a), cmul2(m.m11, d));
}
__device__ __forceinline__ void diag1(float2* st, int t, int w, float2 d0, float2 d1) {
    int p = 9 - w;
    int i0 = ins1(t, p), i1 = i0 | (1 << p);
    st[i0] = cmul2(d0, st[i0]);
    st[i1] = cmul2(d1, st[i1]);
}
__device__ __forceinline__ void capply1(float2* st, int t, int c, int w, M2 m) {
    if (t < 256) {
        int pc = 9 - c, pw = 9 - w;
        int pl = pc < pw ? pc : pw, ph = pc + pw - pl;
        int base = ins1(ins1(t, pl), ph) | (1 << pc);
        int i0 = base, i1 = base | (1 << pw);
        float2 a = st[i0], d = st[i1];
        st[i0] = cadd2(cmul2(m.m00, a), cmul2(m.m01, d));
        st[i1] = cadd2(cmul2(m.m10, a), cmul2(m.m11, d));
    }
}
__device__ __forceinline__ void cdiag1(float2* st, int t, int c, int w, float2 d0, float2 d1) {
    if (t < 256) {
        int pc = 9 - c, pw = 9 - w;
        int pl = pc < pw ? pc : pw, ph = pc + pw - pl;
        int base = ins1(ins1(t, pl), ph) | (1 << pc);
        st[base] = cmul2(d0, st[base]);
        st[base | (1 << pw)] = cmul2(d1, st[base | (1 << pw)]);
    }
}
__device__ __forceinline__ void cnotg(float2* st, int t, int c, int w) {
    if (t < 256) {
        int pc = 9 - c, pw = 9 - w;
        int pl = pc < pw ? pc : pw, ph = pc + pw - pl;
        int base = ins1(ins1(t, pl), ph) | (1 << pc);
        int i1 = base | (1 << pw);
        float2 a = st[base]; st[base] = st[i1]; st[i1] = a;
    }
}
__device__ __forceinline__ void czg(float2* st, int t, int c, int w) {
    if (t < 256) {
        int pc = 9 - c, pw = 9 - w;
        int pl = pc < pw ? pc : pw, ph = pc + pw - pl;
        int i = ins1(ins1(t, pl), ph) | (1 << pc) | (1 << pw);
        st[i] = make_float2(-st[i].x, -st[i].y);
    }
}
__device__ __forceinline__ void swapg(float2* st, int t, int a, int b_) {
    if (t < 256) {
        int pa = 9 - a, pb = 9 - b_;
        int pl = pa < pb ? pa : pb, ph = pa + pb - pl;
        int base = ins1(ins1(t, pl), ph);
        int iA = base | (1 << pa), iB = base | (1 << pb);
        float2 u = st[iA]; st[iA] = st[iB]; st[iB] = u;
    }
}
__device__ __forceinline__ void cswap456f(float2* st, int t) {
    if (t < 128) {
        int base = ins1(ins1(ins1(t, 3), 4), 5) | (1 << 5);
        int iA = base | (1 << 4), iB = base | (1 << 3);
        float2 u = st[iA]; st[iA] = st[iB]; st[iB] = u;
    }
}
__device__ __forceinline__ void toff850f(float2* st, int t) {
    if (t < 128) {
        int base = ins1(ins1(ins1(t, 1), 4), 9) | (1 << 1) | (1 << 4);
        int i1 = base | (1 << 9);
        float2 u = st[base]; st[base] = st[i1]; st[i1] = u;
    }
}
__device__ __forceinline__ void mrzg(float2* st, int t, int mask, float th) {
    float sh, ch; __sincosf(0.5f * th, &sh, &ch);
#pragma unroll
    for (int q = 0; q < 2; ++q) {
        int i = t + q * 512;
        float sg = (__popc(i & mask) & 1) ? sh : -sh;
        float2 a = st[i];
        st[i] = make_float2(ch*a.x - sg*a.y, ch*a.y + sg*a.x);
    }
}
__device__ __forceinline__ void run_circ(
    float2* st, float (*red)[10], float* evs, int t, const float* ang,
    const float* q_rx, const float* q_rz3, const float* q_ps6, const float* q_rot7,
    const float* q_mrz8, const float* q_crx9, const float* q_cry10, const float* q_crz11,
    const float* q_u2, const float* q_u3, float* outf)
{
    st[t] = make_float2(t == 0 ? 1.f : 0.f, 0.f);
    st[t + 512] = make_float2(0.f, 0.f);
#pragma unroll
    for (int k = 0; k < 10; ++k) { M2 m = mrx(q_rx[k]); __syncthreads(); apply1(st, t, k, m); }
    {
        M2 mx0 = mrx(ang[0]);
#pragma unroll
        for (int k = 0; k < 10; ++k) {
            M2 m = mry(ang[k]); __syncthreads(); apply1(st, t, k, m);
            __syncthreads(); apply1(st, t, 0, mx0);
        }
    }
#pragma unroll
    for (int k = 0; k < 9; ++k) { __syncthreads(); cnotg(st, t, k, k + 1); }
    __syncthreads(); cnotg(st, t, 9, 0);
    { M2 m = mrx(ang[1]);      __syncthreads(); apply1(st, t, 1, m); }
    { M2 m = mrx(-PI_F / 4.f); __syncthreads(); apply1(st, t, 5, m); }
    { M2 m = mry(ang[2]);      __syncthreads(); apply1(st, t, 2, m); }
    { float s, c; __sincosf(0.5f * ang[3], &s, &c);
      __syncthreads(); diag1(st, t, 3, make_float2(c,-s), make_float2(c,s)); }
    __syncthreads(); diag1(st, t, 4, make_float2(1.f,0.f), make_float2(0.f,1.f));
    __syncthreads(); diag1(st, t, 5, make_float2(1.f,0.f),
                           make_float2(0.7071067811865476f, 0.7071067811865476f));
    { float s, c; __sincosf(0.5f * q_rz3[0], &s, &c);
      __syncthreads(); diag1(st, t, 6, make_float2(c,-s), make_float2(c,s)); }
    { M2 m = { make_float2(0.5f,0.5f), make_float2(0.5f,-0.5f),
               make_float2(0.5f,-0.5f), make_float2(0.5f,0.5f) };
      __syncthreads(); apply1(st, t, 7, m); }
    __syncthreads(); czg(st, t, 0, 5);
    __syncthreads(); cnotg(st, t, 0, 5);
    { M2 y = { make_float2(0.f,0.f), make_float2(0.f,-1.f),
               make_float2(0.f,1.f), make_float2(0.f,0.f) };
      __syncthreads(); capply1(st, t, 0, 5, y);
      __syncthreads(); capply1(st, t, 3, 8, y); }
    __syncthreads(); swapg(st, t, 2, 3);
    __syncthreads(); cswap456f(st, t);
    __syncthreads(); toff850f(st, t);
    { float s, c; __sincosf(q_ps6[0], &s, &c);
      __syncthreads(); diag1(st, t, 8, make_float2(1.f,0.f), make_float2(c,s)); }
    { float s, c; __sincosf(ang[7], &s, &c);
      __syncthreads(); diag1(st, t, 7, make_float2(1.f,0.f), make_float2(c,s)); }
    { M2 m = mrot(q_rot7[0], q_rot7[1], q_rot7[2]); __syncthreads(); apply1(st, t, 4, m); }
    { M2 m = mrot(ang[6], ang[7], ang[8]);          __syncthreads(); apply1(st, t, 5, m); }
    __syncthreads(); mrzg(st, t, 0xF8, q_mrz8[0]);
    __syncthreads(); mrzg(st, t, 0x6E, ang[5]);
    { M2 m = mrx(ang[6]);      __syncthreads(); capply1(st, t, 0, 1, m); }
    { M2 m = mrx(q_crx9[0]);   __syncthreads(); capply1(st, t, 4, 5, m); }
    { M2 m = mry(ang[6]);      __syncthreads(); capply1(st, t, 0, 1, m); }
    { M2 m = mry(q_cry10[0]);  __syncthreads(); capply1(st, t, 4, 5, m); }
    { float s, c; __sincosf(0.5f * ang[6], &s, &c);
      __syncthreads(); cdiag1(st, t, 0, 1, make_float2(c,-s), make_float2(c,s)); }
    { float s, c; __sincosf(0.5f * q_crz11[0], &s, &c);
      __syncthreads(); cdiag1(st, t, 4, 5, make_float2(c,-s), make_float2(c,s)); }
    { M2 m = mrot(-PI_F/4.f, PI_F/4.f, PI_F/2.f); __syncthreads(); capply1(st, t, 5, 6, m); }
    { M2 m = mrot(ang[5], ang[6], ang[7]);        __syncthreads(); capply1(st, t, 7, 8, m); }
    { float s, c; __sincosf(PI_F/7.f, &s, &c);
      __syncthreads(); diag1(st, t, 1, make_float2(1.f,0.f), make_float2(c,s)); }
    { float s, c; __sincosf(ang[9], &s, &c);
      __syncthreads(); diag1(st, t, 2, make_float2(1.f,0.f), make_float2(c,s)); }
    { M2 m = mu2(q_u2[0], q_u2[1]); __syncthreads(); apply1(st, t, 8, m); }
    { M2 m = mu2(ang[0], ang[1]);   __syncthreads(); apply1(st, t, 4, m); }
    { M2 m = mu3(q_u3[0], q_u3[1], q_u3[2]); __syncthreads(); apply1(st, t, 5, m); }
    { M2 m = mu3(ang[4], ang[5], ang[6]);    __syncthreads(); apply1(st, t, 5, m); }
    __syncthreads(); cnotg(st, t, 1, 2);
    __syncthreads();
    float loc[10];
#pragma unroll
    for (int w = 0; w < 10; ++w) {
        int p = 9 - w;
        int i0 = ins1(t, p), i1 = i0 | (1 << p);
        float2 a = st[i0], c = st[i1];
        loc[w] = 2.f * (a.x * c.y - a.y * c.x);
    }
    int lane = t & 63, wvv = t >> 6;
#pragma unroll
    for (int w = 0; w < 10; ++w) {
        float v = loc[w];
        v += __shfl_down(v, 32); v += __shfl_down(v, 16); v += __shfl_down(v, 8);
        v += __shfl_down(v, 4);  v += __shfl_down(v, 2);  v += __shfl_down(v, 1);
        if (lane == 0) red[wvv][w] = v;
    }
    __syncthreads();
    if (t < 10) {
        float e = 0.f;
#pragma unroll
        for (int i = 0; i < 8; ++i) e += red[i][t];
        evs[t] = e;
    }
    __syncthreads();
    if (t < 10) {
        float mx = evs[0];
#pragma unroll
        for (int i = 1; i < 10; ++i) mx = fmaxf(mx, evs[i]);
        float ss = 0.f;
#pragma unroll
        for (int i = 0; i < 10; ++i) ss += expf(evs[i] - mx);
        outf[t] = evs[t] - mx - logf(ss);
    }
}
template <int NT>
__device__ __forceinline__ void conv_stage(
    float* buf, int n, int t,
    const float* __restrict__ x, const float* __restrict__ w1, const float* __restrict__ b1,
    const float* __restrict__ w2, const float* __restrict__ b2)
{
    float* xs  = buf;
    float* w1s = buf + 784;
    float* h1s = buf + 1072;
    float* w2s = buf + 1748;
    const int ocq = t / 24, r = t - ocq * 24;
    const bool active = (t < 384);
    for (int i = t; i < 784; i += NT) xs[i] = x[n * 784 + i];
    for (int i = t; i < 288; i += NT) w1s[i] = w1[i];
    float acc[4][24];
#pragma unroll
    for (int j = 0; j < 4; ++j)
#pragma unroll
        for (int xo = 0; xo < 24; ++xo) acc[j][xo] = 0.f;
    for (int ic = 0; ic < 32; ++ic) {
        __syncthreads();
        float bb1 = b1[ic];
        for (int i = t; i < 676; i += NT) {
            int yy = i / 26, xx = i - yy * 26;
            const float* xp = xs + yy * 28 + xx;
            const float* wp = w1s + ic * 9;
            float s = bb1;
#pragma unroll
            for (int ky = 0; ky < 3; ++ky)
#pragma unroll
                for (int kx = 0; kx < 3; ++kx)
                    s += xp[ky * 28 + kx] * wp[ky * 3 + kx];
            h1s[i] = fmaxf(s, 0.f);
        }
        for (int i = t; i < 576; i += NT) {
            int oc = i / 9, k = i - oc * 9;
            w2s[i] = w2[oc * 288 + ic * 9 + k];
        }
        __syncthreads();
        if (active) {
            float wr[4][9];
#pragma unroll
            for (int j = 0; j < 4; ++j)
#pragma unroll
                for (int k = 0; k < 9; ++k)
                    wr[j][k] = w2s[(ocq * 4 + j) * 9 + k];
            float c0[3], c1[3];
#pragma unroll
            for (int q = 0; q < 3; ++q) { c0[q] = h1s[(r + q) * 26]; c1[q] = h1s[(r + q) * 26 + 1]; }
#pragma unroll
            for (int xo = 0; xo < 24; ++xo) {
                float c2[3];
#pragma unroll
                for (int q = 0; q < 3; ++q) c2[q] = h1s[(r + q) * 26 + xo + 2];
#pragma unroll
                for (int j = 0; j < 4; ++j) {
                    acc[j][xo] += wr[j][0]*c0[0] + wr[j][1]*c1[0] + wr[j][2]*c2[0]
                                + wr[j][3]*c0[1] + wr[j][4]*c1[1] + wr[j][5]*c2[1]
                                + wr[j][6]*c0[2] + wr[j][7]*c1[2] + wr[j][8]*c2[2];
                }
#pragma unroll
                for (int q = 0; q < 3; ++q) { c0[q] = c1[q]; c1[q] = c2[q]; }
            }
        }
    }
    __syncthreads();
    if (active && (r & 1)) {
#pragma unroll
        for (int j = 0; j < 4; ++j) {
            int oc = ocq * 4 + j;
            float bb = b2[oc];
#pragma unroll
            for (int px = 0; px < 12; ++px) {
                float v0 = fmaxf(acc[j][2*px]   + bb, 0.f);
                float v1 = fmaxf(acc[j][2*px+1] + bb, 0.f);
                buf[oc * 144 + (r >> 1) * 12 + px] = fmaxf(v0, v1);
            }
        }
    }
    __syncthreads();
    if (active && !(r & 1)) {
#pragma unroll
        for (int j = 0; j < 4; ++j) {
            int oc = ocq * 4 + j;
            float bb = b2[oc];
#pragma unroll
            for (int px = 0; px < 12; ++px) {
                float v0 = fmaxf(acc[j][2*px]   + bb, 0.f);
                float v1 = fmaxf(acc[j][2*px+1] + bb, 0.f);
                int idx = oc * 144 + (r >> 1) * 12 + px;
                buf[idx] = fmaxf(fmaxf(v0, v1), buf[idx]);
            }
        }
    }
    __syncthreads();
}
__global__ __launch_bounds__(512) void fused_kernel(
    const float* __restrict__ x, const float* __restrict__ w1, const float* __restrict__ b1,
    const float* __restrict__ w2, const float* __restrict__ b2,
    const float* __restrict__ fw1, const float* __restrict__ fb1,
    const float* __restrict__ fw2, const float* __restrict__ fb2,
    const float* __restrict__ q_rx, const float* __restrict__ q_rz3,
    const float* __restrict__ q_ps6, const float* __restrict__ q_rot7,
    const float* __restrict__ q_mrz8, const float* __restrict__ q_crx9,
    const float* __restrict__ q_cry10, const float* __restrict__ q_crz11,
    const float* __restrict__ q_u2, const float* __restrict__ q_u3,
    float* __restrict__ out)
{
    __shared__ float buf[9216];
    __shared__ float2 st[1024];
    __shared__ float hred[512];
    __shared__ float hvec[128];
    __shared__ float angs[10];
    __shared__ float red[8][10];
    __shared__ float evs[10];
    const int n = blockIdx.x, t = threadIdx.x;
    conv_stage<512>(buf, n, t, x, w1, b1, w2, b2);
    {
        const int j = t >> 2, q = t & 3;
        const float* wrow = fw1 + (size_t)j * 9216 + q * 2304;
        const float* arow = buf + q * 2304;
        float s = 0.f;
        for (int k = 0; k < 2304; k += 4) {
            float4 w = *(const float4*)(wrow + k);
            s += w.x * arow[k] + w.y * arow[k+1] + w.z * arow[k+2] + w.w * arow[k+3];
        }
        hred[t] = s;
    }
    __syncthreads();
    if (t < 128)
        hvec[t] = fmaxf(fb1[t] + hred[t*4] + hred[t*4+1] + hred[t*4+2] + hred[t*4+3], 0.f);
    __syncthreads();
    if (t < 10) {
        float d = fb2[t];
#pragma unroll 16
        for (int k = 0; k < 128; ++k) d += hvec[k] * fw2[t * 128 + k];
        angs[t] = 6.283185307179586f / (1.f + expf(-d));
    }
    __syncthreads();
    run_circ(st, red, evs, t, angs, q_rx, q_rz3, q_ps6, q_rot7, q_mrz8,
             q_crx9, q_cry10, q_crz11, q_u2, q_u3, out + n * 10);
}

// ===================== launch =====================
extern "C" void kernel_launch(void* const* d_in, const int* in_sizes, int n_in,
                              void* d_out, int out_size, void* d_ws, size_t ws_size,
                              hipStream_t stream)
{
    (void)in_sizes; (void)n_in;
    const float* x    = (const float*)d_in[0];
    const float* w1   = (const float*)d_in[1];
    const float* b1   = (const float*)d_in[2];
    const float* w2   = (const float*)d_in[3];
    const float* b2   = (const float*)d_in[4];
    const float* fw1  = (const float*)d_in[5];
    const float* fb1  = (const float*)d_in[6];
    const float* fw2  = (const float*)d_in[7];
    const float* fb2  = (const float*)d_in[8];
    const float* qrx  = (const float*)d_in[9];
    const float* qrz3 = (const float*)d_in[10];
    const float* qps6 = (const float*)d_in[11];
    const float* qrot7 = (const float*)d_in[12];
    const float* qmrz8 = (const float*)d_in[13];
    const float* qcrx9 = (const float*)d_in[14];
    const float* qcry10 = (const float*)d_in[15];
    const float* qcrz11 = (const float*)d_in[16];
    const float* qu2  = (const float*)d_in[17];
    const float* qu3  = (const float*)d_in[18];
    float* out = (float*)d_out;

    const size_t flat_bytes = (size_t)1024 * 9216 * 2;
    const size_t part_bytes = (size_t)16 * 1024 * 128 * 4;
    const size_t w2t_bytes  = (size_t)18432 * 2;
    const size_t fw1h_bytes = (size_t)128 * 9216 * 2;
    const size_t o_flat = 0;
    const size_t o_part = o_flat + flat_bytes;
    const size_t o_w2t  = o_part + part_bytes;
    const size_t o_fw1h = o_w2t + w2t_bytes;
    const size_t need   = o_fw1h + fw1h_bytes;

    (void)hipGetLastError();

    if (ws_size >= need) {
        _Float16* flat = (_Float16*)((char*)d_ws + o_flat);
        float*    part = (float*)((char*)d_ws + o_part);
        _Float16* w2t  = (_Float16*)((char*)d_ws + o_w2t);
        _Float16* fw1h = (_Float16*)((char*)d_ws + o_fw1h);
        prep_all<<<1224, 256, 0, stream>>>(fw1, fw1h, w2, w2t);
        convnet_mfma<<<1024, 256, 0, stream>>>(x, w1, b1, w2t, b2, flat);
        fc1_mfma<<<dim3(16, 2, 16), 256, 0, stream>>>(flat, fw1h, part);
        circuit_wave<<<256, 256, 0, stream>>>(part, fb1, fw2, fb2,
                                              qrx, qrz3, qps6, qrot7, qmrz8,
                                              qcrx9, qcry10, qcrz11, qu2, qu3, out);
    } else {
        fused_kernel<<<1024, 512, 0, stream>>>(x, w1, b1, w2, b2, fw1, fb1, fw2, fb2,
                                               qrx, qrz3, qps6, qrot7, qmrz8,
                                               qcrx9, qcry10, qcrz11, qu2, qu3, out);
    }
    if (hipGetLastError() != hipSuccess) {
        (void)hipMemsetAsync(d_out, 0x7F, (size_t)out_size * 2, stream);
    }
}

// Round 10
// 188.366 us; speedup vs baseline: 1.0408x; 1.0408x over previous
//
#include <hip/hip_runtime.h>
#include <hip/hip_bf16.h>

#define PI_F 3.14159265358979323846f

// Loader insurance: keep a kernel with the stub's exact name (not launched).
__global__ void Static_82300163326800_kernel() {}

typedef _Float16 f16x8 __attribute__((ext_vector_type(8)));
typedef _Float16 f16x4 __attribute__((ext_vector_type(4)));
typedef float f32x4 __attribute__((ext_vector_type(4)));

// ===================== shared gate-matrix helpers =====================
struct M2 { float2 m00, m01, m10, m11; };

__device__ __forceinline__ float2 cmul2(float2 a, float2 b) {
    return make_float2(a.x*b.x - a.y*b.y, a.x*b.y + a.y*b.x);
}
__device__ __forceinline__ float2 cadd2(float2 a, float2 b) {
    return make_float2(a.x+b.x, a.y+b.y);
}
// readfirstlane helpers: pin wave-uniform values into SGPRs (frees VGPRs; VOP3
// may read 1 SGPR per instruction, and the 4-FMA complex-mul form satisfies that).
__device__ __forceinline__ float sflf(float v) {
    return __uint_as_float(__builtin_amdgcn_readfirstlane(__float_as_uint(v)));
}
__device__ __forceinline__ float2 sfl2(float2 v) { return make_float2(sflf(v.x), sflf(v.y)); }
__device__ __forceinline__ M2 sflM(M2 m) {
    return { sfl2(m.m00), sfl2(m.m01), sfl2(m.m10), sfl2(m.m11) };
}
__device__ __forceinline__ M2 m2mul(M2 b, M2 a) {   // gate a first, then b => b*a
    return { cadd2(cmul2(b.m00,a.m00), cmul2(b.m01,a.m10)),
             cadd2(cmul2(b.m00,a.m01), cmul2(b.m01,a.m11)),
             cadd2(cmul2(b.m10,a.m00), cmul2(b.m11,a.m10)),
             cadd2(cmul2(b.m10,a.m01), cmul2(b.m11,a.m11)) };
}
__device__ __forceinline__ M2 mrx(float th) {
    float s, c; __sincosf(0.5f * th, &s, &c);
    return { make_float2(c,0.f), make_float2(0.f,-s), make_float2(0.f,-s), make_float2(c,0.f) };
}
__device__ __forceinline__ M2 mry(float th) {
    float s, c; __sincosf(0.5f * th, &s, &c);
    return { make_float2(c,0.f), make_float2(-s,0.f), make_float2(s,0.f), make_float2(c,0.f) };
}
__device__ __forceinline__ M2 mrot(float phi, float th, float om) {
    float s, c;  __sincosf(0.5f * th, &s, &c);
    float sa, ca; __sincosf(0.5f * (phi + om), &sa, &ca);
    float sd, cd; __sincosf(0.5f * (phi - om), &sd, &cd);
    return { make_float2(ca*c, -sa*c), make_float2(-cd*s, -sd*s),
             make_float2(cd*s, -sd*s), make_float2(ca*c,  sa*c) };
}
__device__ __forceinline__ M2 mu2(float phi, float lam) {
    const float r = 0.7071067811865476f;
    float sl, cl;   __sincosf(lam, &sl, &cl);
    float sp, cp;   __sincosf(phi, &sp, &cp);
    float spl, cpl; __sincosf(phi + lam, &spl, &cpl);
    return { make_float2(r,0.f), make_float2(-r*cl,-r*sl),
             make_float2(r*cp, r*sp), make_float2(r*cpl, r*spl) };
}
__device__ __forceinline__ M2 mu3(float th, float phi, float lam) {
    float s, c;     __sincosf(0.5f * th, &s, &c);
    float sl, cl;   __sincosf(lam, &sl, &cl);
    float sp, cp;   __sincosf(phi, &sp, &cp);
    float spl, cpl; __sincosf(phi + lam, &spl, &cpl);
    return { make_float2(c,0.f), make_float2(-cl*s,-sl*s),
             make_float2(cp*s, sp*s), make_float2(cpl*c, spl*c) };
}

// ===================== per-wave register circuit primitives =====================
// Amplitude index i = (lane<<4) | r.  wire w<=5 -> lane bit (5-w); w>=6 -> r bit (9-w).

__device__ __forceinline__ void applyL(float2* s, M2 m, int lane, int q) {
    const int bitv = (lane >> q) & 1;
    const float2 cA = bitv ? m.m11 : m.m00;
    const float2 cB = bitv ? m.m10 : m.m01;
    float ox[16], oy[16];
#pragma unroll
    for (int r = 0; r < 16; ++r) {
        ox[r] = __shfl_xor(s[r].x, 1 << q);
        oy[r] = __shfl_xor(s[r].y, 1 << q);
    }
#pragma unroll
    for (int r = 0; r < 16; ++r)
        s[r] = make_float2(cA.x*s[r].x - cA.y*s[r].y + cB.x*ox[r] - cB.y*oy[r],
                           cA.x*s[r].y + cA.y*s[r].x + cB.x*oy[r] + cB.y*ox[r]);
}
template<int P>
__device__ __forceinline__ void applyR(float2* s, M2 m) {
#pragma unroll
    for (int r0 = 0; r0 < 16; ++r0) {
        if (r0 & (1 << P)) continue;
        const int r1 = r0 | (1 << P);
        float2 a = s[r0], d = s[r1];
        s[r0] = cadd2(cmul2(m.m00, a), cmul2(m.m01, d));
        s[r1] = cadd2(cmul2(m.m10, a), cmul2(m.m11, d));
    }
}
__device__ __forceinline__ void diagL(float2* s, float2 d0, float2 d1, int lane, int q) {
    const int bitv = (lane >> q) & 1;
    const float2 f = bitv ? d1 : d0;
#pragma unroll
    for (int r = 0; r < 16; ++r) s[r] = cmul2(f, s[r]);
}
template<int P>
__device__ __forceinline__ void diagR(float2* s, float2 d0, float2 d1) {
#pragma unroll
    for (int r = 0; r < 16; ++r) {
        const float2 f = (r & (1 << P)) ? d1 : d0;
        s[r] = cmul2(f, s[r]);
    }
}
__device__ __forceinline__ void cnotLL(float2* s, int lane, int qc, int qw) {
    const int cb = (lane >> qc) & 1;
    float ox[16], oy[16];
#pragma unroll
    for (int r = 0; r < 16; ++r) {
        ox[r] = __shfl_xor(s[r].x, 1 << qw);
        oy[r] = __shfl_xor(s[r].y, 1 << qw);
    }
#pragma unroll
    for (int r = 0; r < 16; ++r)
        s[r] = cb ? make_float2(ox[r], oy[r]) : s[r];
}
__device__ __forceinline__ void capplyLL(float2* s, M2 m, int lane, int qc, int qw) {
    const int cb = (lane >> qc) & 1, tb = (lane >> qw) & 1;
    float2 cA = tb ? m.m11 : m.m00;
    float2 cB = tb ? m.m10 : m.m01;
    cA = cb ? cA : make_float2(1.f, 0.f);
    cB = cb ? cB : make_float2(0.f, 0.f);
    float ox[16], oy[16];
#pragma unroll
    for (int r = 0; r < 16; ++r) {
        ox[r] = __shfl_xor(s[r].x, 1 << qw);
        oy[r] = __shfl_xor(s[r].y, 1 << qw);
    }
#pragma unroll
    for (int r = 0; r < 16; ++r)
        s[r] = make_float2(cA.x*s[r].x - cA.y*s[r].y + cB.x*ox[r] - cB.y*oy[r],
                           cA.x*s[r].y + cA.y*s[r].x + cB.x*oy[r] + cB.y*ox[r]);
}
__device__ __forceinline__ void cdiagLL(float2* s, float2 d0, float2 d1, int lane, int qc, int qw) {
    const int cb = (lane >> qc) & 1, tb = (lane >> qw) & 1;
    float2 f = tb ? d1 : d0;
    f = cb ? f : make_float2(1.f, 0.f);
#pragma unroll
    for (int r = 0; r < 16; ++r) s[r] = cmul2(f, s[r]);
}
template<int P>
__device__ __forceinline__ void capplyRL(float2* s, M2 m, int lane, int qc) {
    const int cb = (lane >> qc) & 1;
#pragma unroll
    for (int r0 = 0; r0 < 16; ++r0) {
        if (r0 & (1 << P)) continue;
        const int r1 = r0 | (1 << P);
        float2 a = s[r0], d = s[r1];
        float2 na = cadd2(cmul2(m.m00, a), cmul2(m.m01, d));
        float2 nd = cadd2(cmul2(m.m10, a), cmul2(m.m11, d));
        s[r0] = cb ? na : a;
        s[r1] = cb ? nd : d;
    }
}

// ============ per-wave circuit kernel (fc2 fused): 1 wave = 1 sample ============
// Grid = 1024 waves = exactly 1 wave/EU chip-wide, so waves_per_eu(1,1) costs no
// occupancy and unlocks the full VGPR budget (r9: allocator squeezed to 64 VGPRs
// and serialized every shfl batch at DS latency).
__global__ __launch_bounds__(256)
__attribute__((amdgpu_waves_per_eu(1, 1)))
void circuit_wave(
    const float* __restrict__ part, const float* __restrict__ fb1,
    const float* __restrict__ fw2, const float* __restrict__ fb2,
    const float* __restrict__ q_rx, const float* __restrict__ q_rz3,
    const float* __restrict__ q_ps6, const float* __restrict__ q_rot7,
    const float* __restrict__ q_mrz8, const float* __restrict__ q_crx9,
    const float* __restrict__ q_cry10, const float* __restrict__ q_crz11,
    const float* __restrict__ q_u2, const float* __restrict__ q_u3,
    float* __restrict__ out)
{
    const int t = threadIdx.x, lane = t & 63, wv = t >> 6;
    const int b = blockIdx.x * 4 + wv;

    // fused fc2: h = relu(fb1 + sum_kb part), angles = 2pi*sigmoid(fw2 h + fb2)
    float h0 = fb1[lane], h1 = fb1[lane + 64];
#pragma unroll
    for (int kb = 0; kb < 16; ++kb) {
        h0 += part[(size_t)kb * 131072 + b * 128 + lane];
        h1 += part[(size_t)kb * 131072 + b * 128 + lane + 64];
    }
    h0 = fmaxf(h0, 0.f); h1 = fmaxf(h1, 0.f);
    float ang[10];
#pragma unroll
    for (int j = 0; j < 10; ++j) {
        float v = h0 * fw2[j * 128 + lane] + h1 * fw2[j * 128 + 64 + lane];
        v += __shfl_xor(v, 1); v += __shfl_xor(v, 2); v += __shfl_xor(v, 4);
        v += __shfl_xor(v, 8); v += __shfl_xor(v, 16); v += __shfl_xor(v, 32);
        // butterfly result is wave-uniform: pin to SGPR so ang[] doesn't eat VGPRs
        ang[j] = sflf(6.283185307179586f / (1.f + expf(-(fb2[j] + sflf(v)))));
    }

    float2 s[16];
#pragma unroll
    for (int r = 0; r < 16; ++r) s[r] = make_float2(0.f, 0.f);
    if (lane == 0) s[0].x = 1.f;

    // L1: trainable RX on wires 0..9
    applyL(s, sflM(mrx(q_rx[0])), lane, 5);
    applyL(s, sflM(mrx(q_rx[1])), lane, 4);
    applyL(s, sflM(mrx(q_rx[2])), lane, 3);
    applyL(s, sflM(mrx(q_rx[3])), lane, 2);
    applyL(s, sflM(mrx(q_rx[4])), lane, 1);
    applyL(s, sflM(mrx(q_rx[5])), lane, 0);
    applyR<3>(s, sflM(mrx(q_rx[6])));
    applyR<2>(s, sflM(mrx(q_rx[7])));
    applyR<1>(s, sflM(mrx(q_rx[8])));
    applyR<0>(s, sflM(mrx(q_rx[9])));
    // L2 fused: RY(ang[k]) on k, then the ten commuting RX(ang0) -> RX(10*ang0)
    applyL(s, sflM(mry(ang[0])), lane, 5);
    applyL(s, sflM(mry(ang[1])), lane, 4);
    applyL(s, sflM(mry(ang[2])), lane, 3);
    applyL(s, sflM(mry(ang[3])), lane, 2);
    applyL(s, sflM(mry(ang[4])), lane, 1);
    applyL(s, sflM(mry(ang[5])), lane, 0);
    applyR<3>(s, sflM(mry(ang[6])));
    applyR<2>(s, sflM(mry(ang[7])));
    applyR<1>(s, sflM(mry(ang[8])));
    applyR<0>(s, sflM(mry(ang[9])));
    applyL(s, sflM(mrx(10.f * ang[0])), lane, 5);
    // CNOT ring (k,k+1) then (9,0)
    cnotLL(s, lane, 5, 4);
    cnotLL(s, lane, 4, 3);
    cnotLL(s, lane, 3, 2);
    cnotLL(s, lane, 2, 1);
    cnotLL(s, lane, 1, 0);
    { // (5,6): ctrl lane bit0, target r bit3
        const int cb = lane & 1;
#pragma unroll
        for (int r0 = 0; r0 < 8; ++r0) {
            float2 a = s[r0], d = s[r0 + 8];
            s[r0] = cb ? d : a; s[r0 + 8] = cb ? a : d;
        }
    }
    { // (6,7)
        float2 u;
        u = s[8];  s[8]  = s[12]; s[12] = u;
        u = s[9];  s[9]  = s[13]; s[13] = u;
        u = s[10]; s[10] = s[14]; s[14] = u;
        u = s[11]; s[11] = s[15]; s[15] = u;
    }
    { // (7,8)
        float2 u;
        u = s[4];  s[4]  = s[6];  s[6]  = u;
        u = s[5];  s[5]  = s[7];  s[7]  = u;
        u = s[12]; s[12] = s[14]; s[14] = u;
        u = s[13]; s[13] = s[15]; s[15] = u;
    }
    { // (8,9)
        float2 u;
        u = s[2];  s[2]  = s[3];  s[3]  = u;
        u = s[6];  s[6]  = s[7];  s[7]  = u;
        u = s[10]; s[10] = s[11]; s[11] = u;
        u = s[14]; s[14] = s[15]; s[15] = u;
    }
    { // (9,0): r bit0 ctrl, target lane bit5
        float ox[8], oy[8];
#pragma unroll
        for (int k = 0; k < 8; ++k) {
            ox[k] = __shfl_xor(s[2*k+1].x, 32);
            oy[k] = __shfl_xor(s[2*k+1].y, 32);
        }
#pragma unroll
        for (int k = 0; k < 8; ++k) s[2*k+1] = make_float2(ox[k], oy[k]);
    }

    applyL(s, sflM(mrx(ang[1])), lane, 4);
    applyL(s, sflM(mrx(-PI_F / 4.f)), lane, 0);
    applyL(s, sflM(mry(ang[2])), lane, 3);
    { float sn, cs; __sincosf(0.5f * ang[3], &sn, &cs);
      sn = sflf(sn); cs = sflf(cs);
      diagL(s, make_float2(cs,-sn), make_float2(cs,sn), lane, 2); }          // RZ on 3
    diagL(s, make_float2(1.f,0.f), make_float2(0.f,1.f), lane, 1);           // S on 4
    diagL(s, make_float2(1.f,0.f),
          make_float2(0.7071067811865476f, 0.7071067811865476f), lane, 0);   // T on 5
    { float sn, cs; __sincosf(0.5f * q_rz3[0], &sn, &cs);
      sn = sflf(sn); cs = sflf(cs);
      diagR<3>(s, make_float2(cs,-sn), make_float2(cs,sn)); }                // RZ on 6
    { M2 m = { make_float2(0.5f,0.5f), make_float2(0.5f,-0.5f),
               make_float2(0.5f,-0.5f), make_float2(0.5f,0.5f) };
      applyR<2>(s, m); }                                                     // SX on 7
    { // CZ;CNOT;CY on (0,5) fused: phase -i iff wire0 bit = 1
        const int cb = (lane >> 5) & 1;
#pragma unroll
        for (int r = 0; r < 16; ++r)
            s[r] = cb ? make_float2(s[r].y, -s[r].x) : s[r];
    }
    { // CY(3,8): ctrl lane bit2, target r bit1
        const int cb = (lane >> 2) & 1;
#pragma unroll
        for (int r0 = 0; r0 < 16; ++r0) {
            if (r0 & 2) continue;
            const int r1 = r0 | 2;
            float2 a = s[r0], d = s[r1];
            float2 na = make_float2(d.y, -d.x);
            float2 nd = make_float2(-a.y, a.x);
            s[r0] = cb ? na : a; s[r1] = cb ? nd : d;
        }
    }
    { // SWAP(2,3): lane bits 3,2
        const int pr = ((lane >> 3) & 1) ^ ((lane >> 2) & 1);
        float ox[16], oy[16];
#pragma unroll
        for (int r = 0; r < 16; ++r) {
            ox[r] = __shfl_xor(s[r].x, 12);
            oy[r] = __shfl_xor(s[r].y, 12);
        }
#pragma unroll
        for (int r = 0; r < 16; ++r)
            s[r] = pr ? make_float2(ox[r], oy[r]) : s[r];
    }
    { // CSWAP(4;5,6): ctrl lane bit1; swap lane bit0 <-> r bit3
        float ox[16], oy[16];
#pragma unroll
        for (int r = 0; r < 16; ++r) {
            ox[r] = __shfl_xor(s[r ^ 8].x, 1);
            oy[r] = __shfl_xor(s[r ^ 8].y, 1);
        }
        const int cb = (lane >> 1) & 1, lb = lane & 1;
#pragma unroll
        for (int r = 0; r < 16; ++r) {
            const int pr = cb & ((r & 8) ? (1 - lb) : lb);
            s[r] = pr ? make_float2(ox[r], oy[r]) : s[r];
        }
    }
    { // TOFF(8,5;0): ctrl r bit1 & lane bit0; target lane bit5
        const int lb = lane & 1;
        float ox[8], oy[8];
        const int idx8[8] = {2,3,6,7,10,11,14,15};
#pragma unroll
        for (int k = 0; k < 8; ++k) {
            ox[k] = __shfl_xor(s[idx8[k]].x, 32);
            oy[k] = __shfl_xor(s[idx8[k]].y, 32);
        }
#pragma unroll
        for (int k = 0; k < 8; ++k)
            s[idx8[k]] = lb ? make_float2(ox[k], oy[k]) : s[idx8[k]];
    }
    { float sn, cs; __sincosf(q_ps6[0], &sn, &cs);
      sn = sflf(sn); cs = sflf(cs);
      diagR<1>(s, make_float2(1.f,0.f), make_float2(cs,sn)); }               // PS on 8
    { float sn, cs; __sincosf(ang[7], &sn, &cs);
      sn = sflf(sn); cs = sflf(cs);
      diagR<2>(s, make_float2(1.f,0.f), make_float2(cs,sn)); }               // PS on 7
    applyL(s, sflM(mrot(q_rot7[0], q_rot7[1], q_rot7[2])), lane, 1);         // ROT on 4
    applyL(s, sflM(mrot(ang[6], ang[7], ang[8])), lane, 0);                  // ROT on 5
    { // multiRZ(q_mrz8) wires (2,3,4,5,6)
        float sh, ch; __sincosf(0.5f * q_mrz8[0], &sh, &ch);
        sh = sflf(sh); ch = sflf(ch);
        const int lp = __popc(lane & 0xF) & 1;
        const float sg0 = lp ? sh : -sh;
#pragma unroll
        for (int r = 0; r < 16; ++r) {
            const float sg = (r & 8) ? -sg0 : sg0;
            float2 a = s[r];
            s[r] = make_float2(ch*a.x - sg*a.y, ch*a.y + sg*a.x);
        }
    }
    { // multiRZ(ang[5]) wires (3,4,6,7,8)
        float sh, ch; __sincosf(0.5f * ang[5], &sh, &ch);
        sh = sflf(sh); ch = sflf(ch);
        const int lp = __popc(lane & 6) & 1;
        const float sg0 = lp ? sh : -sh;
#pragma unroll
        for (int r = 0; r < 16; ++r) {
            const int rp = __popc(r & 14) & 1;
            const float sg = rp ? -sg0 : sg0;
            float2 a = s[r];
            s[r] = make_float2(ch*a.x - sg*a.y, ch*a.y + sg*a.x);
        }
    }
    capplyLL(s, sflM(mrx(ang[6])), lane, 5, 4);       // CRX(0,1)
    capplyLL(s, sflM(mrx(q_crx9[0])), lane, 1, 0);    // CRX(4,5)
    capplyLL(s, sflM(mry(ang[6])), lane, 5, 4);       // CRY(0,1)
    capplyLL(s, sflM(mry(q_cry10[0])), lane, 1, 0);   // CRY(4,5)
    { float sn, cs; __sincosf(0.5f * ang[6], &sn, &cs);
      sn = sflf(sn); cs = sflf(cs);
      cdiagLL(s, make_float2(cs,-sn), make_float2(cs,sn), lane, 5, 4); }     // CRZ(0,1)
    { float sn, cs; __sincosf(0.5f * q_crz11[0], &sn, &cs);
      sn = sflf(sn); cs = sflf(cs);
      cdiagLL(s, make_float2(cs,-sn), make_float2(cs,sn), lane, 1, 0); }     // CRZ(4,5)
    capplyRL<3>(s, sflM(mrot(-PI_F/4.f, PI_F/4.f, PI_F/2.f)), lane, 0);      // CROT(5,6)
    { // CROT(7,8): pairs {4,5,12,13}
        M2 m = sflM(mrot(ang[5], ang[6], ang[7]));
        const int idx4[4] = {4, 5, 12, 13};
#pragma unroll
        for (int k = 0; k < 4; ++k) {
            const int r0 = idx4[k], r1 = r0 | 2;
            float2 a = s[r0], d = s[r1];
            s[r0] = cadd2(cmul2(m.m00, a), cmul2(m.m01, d));
            s[r1] = cadd2(cmul2(m.m10, a), cmul2(m.m11, d));
        }
    }
    { float sn, cs; __sincosf(PI_F / 7.f, &sn, &cs);
      sn = sflf(sn); cs = sflf(cs);
      diagL(s, make_float2(1.f,0.f), make_float2(cs,sn), lane, 4); }         // U1 on 1
    { float sn, cs; __sincosf(ang[9], &sn, &cs);
      sn = sflf(sn); cs = sflf(cs);
      diagL(s, make_float2(1.f,0.f), make_float2(cs,sn), lane, 3); }         // PS on 2
    applyR<1>(s, sflM(mu2(q_u2[0], q_u2[1])));                               // U2 on 8
    applyL(s, sflM(mu2(ang[0], ang[1])), lane, 1);                           // U2 on 4
    applyL(s, sflM(m2mul(mu3(ang[4], ang[5], ang[6]),
                         mu3(q_u3[0], q_u3[1], q_u3[2]))), lane, 0);         // U3*U3 on 5
    cnotLL(s, lane, 4, 3);                                                   // CNOT(1,2)

    // <Y_w> then log_softmax
    float ev[10];
#pragma unroll
    for (int w = 0; w < 6; ++w) {
        const int q = 5 - w;
        const int bitv = (lane >> q) & 1;
        float ox[16], oy[16];
#pragma unroll
        for (int r = 0; r < 16; ++r) {
            ox[r] = __shfl_xor(s[r].x, 1 << q);
            oy[r] = __shfl_xor(s[r].y, 1 << q);
        }
        float acc = 0.f;
#pragma unroll
        for (int r = 0; r < 16; ++r)
            acc += s[r].x * oy[r] - s[r].y * ox[r];
        ev[w] = bitv ? 0.f : 2.f * acc;
    }
#pragma unroll
    for (int w = 6; w < 10; ++w) {
        const int P = 9 - w;
        float acc = 0.f;
#pragma unroll
        for (int r0 = 0; r0 < 16; ++r0) {
            if (r0 & (1 << P)) continue;
            const int r1 = r0 | (1 << P);
            acc += s[r0].x * s[r1].y - s[r0].y * s[r1].x;
        }
        ev[w] = 2.f * acc;
    }
#pragma unroll
    for (int w = 0; w < 10; ++w) {
        float v = ev[w];
        v += __shfl_down(v, 32); v += __shfl_down(v, 16); v += __shfl_down(v, 8);
        v += __shfl_down(v, 4);  v += __shfl_down(v, 2);  v += __shfl_down(v, 1);
        ev[w] = v;
    }
    if (lane == 0) {
        float mx = ev[0];
#pragma unroll
        for (int i = 1; i < 10; ++i) mx = fmaxf(mx, ev[i]);
        float ss = 0.f;
#pragma unroll
        for (int i = 0; i < 10; ++i) ss += expf(ev[i] - mx);
        const float ls = logf(ss);
#pragma unroll
        for (int i = 0; i < 10; ++i) out[b * 10 + i] = ev[i] - mx - ls;
    }
}

// ============ prep (merged): fw1 -> f16 and w2 -> transposed f16 ============
__global__ __launch_bounds__(256) void prep_all(
    const float* __restrict__ fw1, _Float16* __restrict__ fw1h,
    const float* __restrict__ w2, _Float16* __restrict__ w2t)
{
    const int blk = blockIdx.x;
    if (blk < 1152) {
        int i = blk * 256 + threadIdx.x;   // 294912 float4 groups
        float4 v = ((const float4*)fw1)[i];
        f16x4 o = { (_Float16)v.x, (_Float16)v.y, (_Float16)v.z, (_Float16)v.w };
        *(f16x4*)(fw1h + i * 4) = o;
    } else {
        int idx = (blk - 1152) * 256 + threadIdx.x;
        if (idx < 18432) {
            int oc = idx / 288, r = idx - oc * 288;
            int s = r >> 5, ic = r & 31;
            w2t[idx] = (_Float16)w2[oc * 288 + ic * 9 + s];
        }
    }
}

// ===================== MFMA convnet =====================
__global__ __launch_bounds__(256, 2) void convnet_mfma(
    const float* __restrict__ x, const float* __restrict__ w1, const float* __restrict__ b1,
    const _Float16* __restrict__ w2t, const float* __restrict__ b2,
    _Float16* __restrict__ flat)
{
    __shared__ float xs[784];
    __shared__ __align__(16) float w1t[288];              // [k][ic] transposed
    __shared__ __align__(16) _Float16 h1t[676 * 40];      // [pix][ic], stride 40
    const int n = blockIdx.x, t = threadIdx.x;
    const int lane = t & 63, wv = t >> 6;
    const int m = lane & 15, quad = lane >> 4;

    for (int i = t; i < 784; i += 256) xs[i] = x[n * 784 + i];
    for (int i = t; i < 288; i += 256) {   // grid-stride: 288 > 256 (r8 bug fix)
        int ic = i / 9, k = i - ic * 9;
        w1t[k * 32 + ic] = w1[i];
    }
    __syncthreads();

    // conv1
    {
        const int icg = t & 3;
        float w[9][8];
#pragma unroll
        for (int k = 0; k < 9; ++k) {
            float4 a = *(const float4*)&w1t[k * 32 + icg * 8];
            float4 bsec = *(const float4*)&w1t[k * 32 + icg * 8 + 4];
            w[k][0] = a.x; w[k][1] = a.y; w[k][2] = a.z; w[k][3] = a.w;
            w[k][4] = bsec.x; w[k][5] = bsec.y; w[k][6] = bsec.z; w[k][7] = bsec.w;
        }
        float bb[8];
#pragma unroll
        for (int j = 0; j < 8; ++j) bb[j] = b1[icg * 8 + j];
        for (int pix = t >> 2; pix < 676; pix += 64) {
            const int yy = pix / 26, xx = pix - yy * 26;
            const float* xp = xs + yy * 28 + xx;
            float acc[8];
#pragma unroll
            for (int j = 0; j < 8; ++j) acc[j] = bb[j];
#pragma unroll
            for (int ky = 0; ky < 3; ++ky)
#pragma unroll
                for (int kx = 0; kx < 3; ++kx) {
                    const float xv = xp[ky * 28 + kx];
                    const int k = ky * 3 + kx;
#pragma unroll
                    for (int j = 0; j < 8; ++j) acc[j] += xv * w[k][j];
                }
            f16x8 o;
#pragma unroll
            for (int j = 0; j < 8; ++j) o[j] = (_Float16)fmaxf(acc[j], 0.f);
            *(f16x8*)&h1t[pix * 40 + icg * 8] = o;
        }
    }

    f16x8 bq[9][4];
#pragma unroll
    for (int s = 0; s < 9; ++s)
#pragma unroll
        for (int nt = 0; nt < 4; ++nt)
            bq[s][nt] = *(const f16x8*)(w2t + (nt * 16 + m) * 288 + s * 32 + quad * 8);

    __syncthreads();

    float bb2[4];
#pragma unroll
    for (int nt = 0; nt < 4; ++nt) bb2[nt] = b2[nt * 16 + m];

    _Float16* outp = flat + (size_t)n * 9216;

    for (int q = 0; q < 9; ++q) {
        const int mt = wv + q * 4;
        const int a = mt / 3, b3 = mt - a * 3;
        const int y0 = 2 * a + (m & 1), x0 = 8 * b3 + (m >> 1);
        f32x4 acc[4] = {};
#pragma unroll
        for (int s = 0; s < 9; ++s) {
            const int ky = s / 3, kx = s - ky * 3;
            f16x8 af = *(const f16x8*)&h1t[((y0 + ky) * 26 + x0 + kx) * 40 + quad * 8];
#pragma unroll
            for (int nt = 0; nt < 4; ++nt)
                acc[nt] = __builtin_amdgcn_mfma_f32_16x16x32_f16(af, bq[s][nt], acc[nt], 0, 0, 0);
        }
        const int pooled_idx = a * 12 + 4 * b3 + quad;
#pragma unroll
        for (int nt = 0; nt < 4; ++nt) {
            float v = fmaxf(fmaxf(acc[nt][0], acc[nt][1]), fmaxf(acc[nt][2], acc[nt][3]));
            outp[(nt * 16 + m) * 144 + pooled_idx] = (_Float16)fmaxf(v + bb2[nt], 0.f);
        }
    }
}

// ===================== fc1 MFMA: [1024,9216]f16 @ [128,9216]^T f16, K split 16 ======
__global__ __launch_bounds__(256) void fc1_mfma(
    const _Float16* __restrict__ A, const _Float16* __restrict__ B, float* __restrict__ part)
{
    const int m0 = blockIdx.x * 64, n0 = blockIdx.y * 64, kb = blockIdx.z;
    const int t = threadIdx.x, lane = t & 63, wv = t >> 6;
    const int r = lane & 15, quad = lane >> 4;
    const _Float16* ap = A + (size_t)(m0 + wv * 16 + r) * 9216 + kb * 576 + quad * 8;
    const _Float16* bp = B + (size_t)(n0 + r) * 9216 + kb * 576 + quad * 8;
    f32x4 acc[4] = {};
    for (int ks = 0; ks < 576; ks += 32) {
        f16x8 af = *(const f16x8*)(ap + ks);
#pragma unroll
        for (int nt = 0; nt < 4; ++nt) {
            f16x8 bfr = *(const f16x8*)(bp + (size_t)nt * 16 * 9216 + ks);
            acc[nt] = __builtin_amdgcn_mfma_f32_16x16x32_f16(af, bfr, acc[nt], 0, 0, 0);
        }
    }
    float* pp = part + (size_t)kb * 131072 + (size_t)(m0 + wv * 16 + quad * 4) * 128 + n0 + r;
#pragma unroll
    for (int nt = 0; nt < 4; ++nt)
#pragma unroll
        for (int reg = 0; reg < 4; ++reg)
            pp[reg * 128 + nt * 16] = acc[nt][reg];
}

// ===================== FALLBACK: fully fused fp32, zero workspace =====================
__device__ __forceinline__ int ins1(int x, int p) {
    return ((x >> p) << (p + 1)) | (x & ((1 << p) - 1));
}
__device__ __forceinline__ void apply1(float2* st, int t, int w, M2 m) {
    int p = 9 - w;
    int i0 = ins1(t, p), i1 = i0 | (1 << p);
    float2 a = st[i0], d = st[i1];
    st[i0] = cadd2(cmul2(m.m00, a), cmul2(m.m01, d));
    st[i1] = cadd2(cmul2(m.m10, a), cmul2(m.m11, d));
}
__device__ __forceinline__ void diag1(float2* st, int t, int w, float2 d0, float2 d1) {
    int p = 9 - w;
    int i0 = ins1(t, p), i1 = i0 | (1 << p);
    st[i0] = cmul2(d0, st[i0]);
    st[i1] = cmul2(d1, st[i1]);
}
__device__ __forceinline__ void capply1(float2* st, int t, int c, int w, M2 m) {
    if (t < 256) {
        int pc = 9 - c, pw = 9 - w;
        int pl = pc < pw ? pc : pw, ph = pc + pw - pl;
        int base = ins1(ins1(t, pl), ph) | (1 << pc);
        int i0 = base, i1 = base | (1 << pw);
        float2 a = st[i0], d = st[i1];
        st[i0] = cadd2(cmul2(m.m00, a), cmul2(m.m01, d));
        st[i1] = cadd2(cmul2(m.m10, a), cmul2(m.m11, d));
    }
}
__device__ __forceinline__ void cdiag1(float2* st, int t, int c, int w, float2 d0, float2 d1) {
    if (t < 256) {
        int pc = 9 - c, pw = 9 - w;
        int pl = pc < pw ? pc : pw, ph = pc + pw - pl;
        int base = ins1(ins1(t, pl), ph) | (1 << pc);
        st[base] = cmul2(d0, st[base]);
        st[base | (1 << pw)] = cmul2(d1, st[base | (1 << pw)]);
    }
}
__device__ __forceinline__ void cnotg(float2* st, int t, int c, int w) {
    if (t < 256) {
        int pc = 9 - c, pw = 9 - w;
        int pl = pc < pw ? pc : pw, ph = pc + pw - pl;
        int base = ins1(ins1(t, pl), ph) | (1 << pc);
        int i1 = base | (1 << pw);
        float2 a = st[base]; st[base] = st[i1]; st[i1] = a;
    }
}
__device__ __forceinline__ void czg(float2* st, int t, int c, int w) {
    if (t < 256) {
        int pc = 9 - c, pw = 9 - w;
        int pl = pc < pw ? pc : pw, ph = pc + pw - pl;
        int i = ins1(ins1(t, pl), ph) | (1 << pc) | (1 << pw);
        st[i] = make_float2(-st[i].x, -st[i].y);
    }
}
__device__ __forceinline__ void swapg(float2* st, int t, int a, int b_) {
    if (t < 256) {
        int pa = 9 - a, pb = 9 - b_;
        int pl = pa < pb ? pa : pb, ph = pa + pb - pl;
        int base = ins1(ins1(t, pl), ph);
        int iA = base | (1 << pa), iB = base | (1 << pb);
        float2 u = st[iA]; st[iA] = st[iB]; st[iB] = u;
    }
}
__device__ __forceinline__ void cswap456f(float2* st, int t) {
    if (t < 128) {
        int base = ins1(ins1(ins1(t, 3), 4), 5) | (1 << 5);
        int iA = base | (1 << 4), iB = base | (1 << 3);
        float2 u = st[iA]; st[iA] = st[iB]; st[iB] = u;
    }
}
__device__ __forceinline__ void toff850f(float2* st, int t) {
    if (t < 128) {
        int base = ins1(ins1(ins1(t, 1), 4), 9) | (1 << 1) | (1 << 4);
        int i1 = base | (1 << 9);
        float2 u = st[base]; st[base] = st[i1]; st[i1] = u;
    }
}
__device__ __forceinline__ void mrzg(float2* st, int t, int mask, float th) {
    float sh, ch; __sincosf(0.5f * th, &sh, &ch);
#pragma unroll
    for (int q = 0; q < 2; ++q) {
        int i = t + q * 512;
        float sg = (__popc(i & mask) & 1) ? sh : -sh;
        float2 a = st[i];
        st[i] = make_float2(ch*a.x - sg*a.y, ch*a.y + sg*a.x);
    }
}
__device__ __forceinline__ void run_circ(
    float2* st, float (*red)[10], float* evs, int t, const float* ang,
    const float* q_rx, const float* q_rz3, const float* q_ps6, const float* q_rot7,
    const float* q_mrz8, const float* q_crx9, const float* q_cry10, const float* q_crz11,
    const float* q_u2, const float* q_u3, float* outf)
{
    st[t] = make_float2(t == 0 ? 1.f : 0.f, 0.f);
    st[t + 512] = make_float2(0.f, 0.f);
#pragma unroll
    for (int k = 0; k < 10; ++k) { M2 m = mrx(q_rx[k]); __syncthreads(); apply1(st, t, k, m); }
    {
        M2 mx0 = mrx(ang[0]);
#pragma unroll
        for (int k = 0; k < 10; ++k) {
            M2 m = mry(ang[k]); __syncthreads(); apply1(st, t, k, m);
            __syncthreads(); apply1(st, t, 0, mx0);
        }
    }
#pragma unroll
    for (int k = 0; k < 9; ++k) { __syncthreads(); cnotg(st, t, k, k + 1); }
    __syncthreads(); cnotg(st, t, 9, 0);
    { M2 m = mrx(ang[1]);      __syncthreads(); apply1(st, t, 1, m); }
    { M2 m = mrx(-PI_F / 4.f); __syncthreads(); apply1(st, t, 5, m); }
    { M2 m = mry(ang[2]);      __syncthreads(); apply1(st, t, 2, m); }
    { float s, c; __sincosf(0.5f * ang[3], &s, &c);
      __syncthreads(); diag1(st, t, 3, make_float2(c,-s), make_float2(c,s)); }
    __syncthreads(); diag1(st, t, 4, make_float2(1.f,0.f), make_float2(0.f,1.f));
    __syncthreads(); diag1(st, t, 5, make_float2(1.f,0.f),
                           make_float2(0.7071067811865476f, 0.7071067811865476f));
    { float s, c; __sincosf(0.5f * q_rz3[0], &s, &c);
      __syncthreads(); diag1(st, t, 6, make_float2(c,-s), make_float2(c,s)); }
    { M2 m = { make_float2(0.5f,0.5f), make_float2(0.5f,-0.5f),
               make_float2(0.5f,-0.5f), make_float2(0.5f,0.5f) };
      __syncthreads(); apply1(st, t, 7, m); }
    __syncthreads(); czg(st, t, 0, 5);
    __syncthreads(); cnotg(st, t, 0, 5);
    { M2 y = { make_float2(0.f,0.f), make_float2(0.f,-1.f),
               make_float2(0.f,1.f), make_float2(0.f,0.f) };
      __syncthreads(); capply1(st, t, 0, 5, y);
      __syncthreads(); capply1(st, t, 3, 8, y); }
    __syncthreads(); swapg(st, t, 2, 3);
    __syncthreads(); cswap456f(st, t);
    __syncthreads(); toff850f(st, t);
    { float s, c; __sincosf(q_ps6[0], &s, &c);
      __syncthreads(); diag1(st, t, 8, make_float2(1.f,0.f), make_float2(c,s)); }
    { float s, c; __sincosf(ang[7], &s, &c);
      __syncthreads(); diag1(st, t, 7, make_float2(1.f,0.f), make_float2(c,s)); }
    { M2 m = mrot(q_rot7[0], q_rot7[1], q_rot7[2]); __syncthreads(); apply1(st, t, 4, m); }
    { M2 m = mrot(ang[6], ang[7], ang[8]);          __syncthreads(); apply1(st, t, 5, m); }
    __syncthreads(); mrzg(st, t, 0xF8, q_mrz8[0]);
    __syncthreads(); mrzg(st, t, 0x6E, ang[5]);
    { M2 m = mrx(ang[6]);      __syncthreads(); capply1(st, t, 0, 1, m); }
    { M2 m = mrx(q_crx9[0]);   __syncthreads(); capply1(st, t, 4, 5, m); }
    { M2 m = mry(ang[6]);      __syncthreads(); capply1(st, t, 0, 1, m); }
    { M2 m = mry(q_cry10[0]);  __syncthreads(); capply1(st, t, 4, 5, m); }
    { float s, c; __sincosf(0.5f * ang[6], &s, &c);
      __syncthreads(); cdiag1(st, t, 0, 1, make_float2(c,-s), make_float2(c,s)); }
    { float s, c; __sincosf(0.5f * q_crz11[0], &s, &c);
      __syncthreads(); cdiag1(st, t, 4, 5, make_float2(c,-s), make_float2(c,s)); }
    { M2 m = mrot(-PI_F/4.f, PI_F/4.f, PI_F/2.f); __syncthreads(); capply1(st, t, 5, 6, m); }
    { M2 m = mrot(ang[5], ang[6], ang[7]);        __syncthreads(); capply1(st, t, 7, 8, m); }
    { float s, c; __sincosf(PI_F/7.f, &s, &c);
      __syncthreads(); diag1(st, t, 1, make_float2(1.f,0.f), make_float2(c,s)); }
    { float s, c; __sincosf(ang[9], &s, &c);
      __syncthreads(); diag1(st, t, 2, make_float2(1.f,0.f), make_float2(c,s)); }
    { M2 m = mu2(q_u2[0], q_u2[1]); __syncthreads(); apply1(st, t, 8, m); }
    { M2 m = mu2(ang[0], ang[1]);   __syncthreads(); apply1(st, t, 4, m); }
    { M2 m = mu3(q_u3[0], q_u3[1], q_u3[2]); __syncthreads(); apply1(st, t, 5, m); }
    { M2 m = mu3(ang[4], ang[5], ang[6]);    __syncthreads(); apply1(st, t, 5, m); }
    __syncthreads(); cnotg(st, t, 1, 2);
    __syncthreads();
    float loc[10];
#pragma unroll
    for (int w = 0; w < 10; ++w) {
        int p = 9 - w;
        int i0 = ins1(t, p), i1 = i0 | (1 << p);
        float2 a = st[i0], c = st[i1];
        loc[w] = 2.f * (a.x * c.y - a.y * c.x);
    }
    int lane = t & 63, wvv = t >> 6;
#pragma unroll
    for (int w = 0; w < 10; ++w) {
        float v = loc[w];
        v += __shfl_down(v, 32); v += __shfl_down(v, 16); v += __shfl_down(v, 8);
        v += __shfl_down(v, 4);  v += __shfl_down(v, 2);  v += __shfl_down(v, 1);
        if (lane == 0) red[wvv][w] = v;
    }
    __syncthreads();
    if (t < 10) {
        float e = 0.f;
#pragma unroll
        for (int i = 0; i < 8; ++i) e += red[i][t];
        evs[t] = e;
    }
    __syncthreads();
    if (t < 10) {
        float mx = evs[0];
#pragma unroll
        for (int i = 1; i < 10; ++i) mx = fmaxf(mx, evs[i]);
        float ss = 0.f;
#pragma unroll
        for (int i = 0; i < 10; ++i) ss += expf(evs[i] - mx);
        outf[t] = evs[t] - mx - logf(ss);
    }
}
template <int NT>
__device__ __forceinline__ void conv_stage(
    float* buf, int n, int t,
    const float* __restrict__ x, const float* __restrict__ w1, const float* __restrict__ b1,
    const float* __restrict__ w2, const float* __restrict__ b2)
{
    float* xs  = buf;
    float* w1s = buf + 784;
    float* h1s = buf + 1072;
    float* w2s = buf + 1748;
    const int ocq = t / 24, r = t - ocq * 24;
    const bool active = (t < 384);
    for (int i = t; i < 784; i += NT) xs[i] = x[n * 784 + i];
    for (int i = t; i < 288; i += NT) w1s[i] = w1[i];
    float acc[4][24];
#pragma unroll
    for (int j = 0; j < 4; ++j)
#pragma unroll
        for (int xo = 0; xo < 24; ++xo) acc[j][xo] = 0.f;
    for (int ic = 0; ic < 32; ++ic) {
        __syncthreads();
        float bb1 = b1[ic];
        for (int i = t; i < 676; i += NT) {
            int yy = i / 26, xx = i - yy * 26;
            const float* xp = xs + yy * 28 + xx;
            const float* wp = w1s + ic * 9;
            float s = bb1;
#pragma unroll
            for (int ky = 0; ky < 3; ++ky)
#pragma unroll
                for (int kx = 0; kx < 3; ++kx)
                    s += xp[ky * 28 + kx] * wp[ky * 3 + kx];
            h1s[i] = fmaxf(s, 0.f);
        }
        for (int i = t; i < 576; i += NT) {
            int oc = i / 9, k = i - oc * 9;
            w2s[i] = w2[oc * 288 + ic * 9 + k];
        }
        __syncthreads();
        if (active) {
            float wr[4][9];
#pragma unroll
            for (int j = 0; j < 4; ++j)
#pragma unroll
                for (int k = 0; k < 9; ++k)
                    wr[j][k] = w2s[(ocq * 4 + j) * 9 + k];
            float c0[3], c1[3];
#pragma unroll
            for (int q = 0; q < 3; ++q) { c0[q] = h1s[(r + q) * 26]; c1[q] = h1s[(r + q) * 26 + 1]; }
#pragma unroll
            for (int xo = 0; xo < 24; ++xo) {
                float c2[3];
#pragma unroll
                for (int q = 0; q < 3; ++q) c2[q] = h1s[(r + q) * 26 + xo + 2];
#pragma unroll
                for (int j = 0; j < 4; ++j) {
                    acc[j][xo] += wr[j][0]*c0[0] + wr[j][1]*c1[0] + wr[j][2]*c2[0]
                                + wr[j][3]*c0[1] + wr[j][4]*c1[1] + wr[j][5]*c2[1]
                                + wr[j][6]*c0[2] + wr[j][7]*c1[2] + wr[j][8]*c2[2];
                }
#pragma unroll
                for (int q = 0; q < 3; ++q) { c0[q] = c1[q]; c1[q] = c2[q]; }
            }
        }
    }
    __syncthreads();
    if (active && (r & 1)) {
#pragma unroll
        for (int j = 0; j < 4; ++j) {
            int oc = ocq * 4 + j;
            float bb = b2[oc];
#pragma unroll
            for (int px = 0; px < 12; ++px) {
                float v0 = fmaxf(acc[j][2*px]   + bb, 0.f);
                float v1 = fmaxf(acc[j][2*px+1] + bb, 0.f);
                buf[oc * 144 + (r >> 1) * 12 + px] = fmaxf(v0, v1);
            }
        }
    }
    __syncthreads();
    if (active && !(r & 1)) {
#pragma unroll
        for (int j = 0; j < 4; ++j) {
            int oc = ocq * 4 + j;
            float bb = b2[oc];
#pragma unroll
            for (int px = 0; px < 12; ++px) {
                float v0 = fmaxf(acc[j][2*px]   + bb, 0.f);
                float v1 = fmaxf(acc[j][2*px+1] + bb, 0.f);
                int idx = oc * 144 + (r >> 1) * 12 + px;
                buf[idx] = fmaxf(fmaxf(v0, v1), buf[idx]);
            }
        }
    }
    __syncthreads();
}
__global__ __launch_bounds__(512) void fused_kernel(
    const float* __restrict__ x, const float* __restrict__ w1, const float* __restrict__ b1,
    const float* __restrict__ w2, const float* __restrict__ b2,
    const float* __restrict__ fw1, const float* __restrict__ fb1,
    const float* __restrict__ fw2, const float* __restrict__ fb2,
    const float* __restrict__ q_rx, const float* __restrict__ q_rz3,
    const float* __restrict__ q_ps6, const float* __restrict__ q_rot7,
    const float* __restrict__ q_mrz8, const float* __restrict__ q_crx9,
    const float* __restrict__ q_cry10, const float* __restrict__ q_crz11,
    const float* __restrict__ q_u2, const float* __restrict__ q_u3,
    float* __restrict__ out)
{
    __shared__ float buf[9216];
    __shared__ float2 st[1024];
    __shared__ float hred[512];
    __shared__ float hvec[128];
    __shared__ float angs[10];
    __shared__ float red[8][10];
    __shared__ float evs[10];
    const int n = blockIdx.x, t = threadIdx.x;
    conv_stage<512>(buf, n, t, x, w1, b1, w2, b2);
    {
        const int j = t >> 2, q = t & 3;
        const float* wrow = fw1 + (size_t)j * 9216 + q * 2304;
        const float* arow = buf + q * 2304;
        float s = 0.f;
        for (int k = 0; k < 2304; k += 4) {
            float4 w = *(const float4*)(wrow + k);
            s += w.x * arow[k] + w.y * arow[k+1] + w.z * arow[k+2] + w.w * arow[k+3];
        }
        hred[t] = s;
    }
    __syncthreads();
    if (t < 128)
        hvec[t] = fmaxf(fb1[t] + hred[t*4] + hred[t*4+1] + hred[t*4+2] + hred[t*4+3], 0.f);
    __syncthreads();
    if (t < 10) {
        float d = fb2[t];
#pragma unroll 16
        for (int k = 0; k < 128; ++k) d += hvec[k] * fw2[t * 128 + k];
        angs[t] = 6.283185307179586f / (1.f + expf(-d));
    }
    __syncthreads();
    run_circ(st, red, evs, t, angs, q_rx, q_rz3, q_ps6, q_rot7, q_mrz8,
             q_crx9, q_cry10, q_crz11, q_u2, q_u3, out + n * 10);
}

// ===================== launch =====================
extern "C" void kernel_launch(void* const* d_in, const int* in_sizes, int n_in,
                              void* d_out, int out_size, void* d_ws, size_t ws_size,
                              hipStream_t stream)
{
    (void)in_sizes; (void)n_in;
    const float* x    = (const float*)d_in[0];
    const float* w1   = (const float*)d_in[1];
    const float* b1   = (const float*)d_in[2];
    const float* w2   = (const float*)d_in[3];
    const float* b2   = (const float*)d_in[4];
    const float* fw1  = (const float*)d_in[5];
    const float* fb1  = (const float*)d_in[6];
    const float* fw2  = (const float*)d_in[7];
    const float* fb2  = (const float*)d_in[8];
    const float* qrx  = (const float*)d_in[9];
    const float* qrz3 = (const float*)d_in[10];
    const float* qps6 = (const float*)d_in[11];
    const float* qrot7 = (const float*)d_in[12];
    const float* qmrz8 = (const float*)d_in[13];
    const float* qcrx9 = (const float*)d_in[14];
    const float* qcry10 = (const float*)d_in[15];
    const float* qcrz11 = (const float*)d_in[16];
    const float* qu2  = (const float*)d_in[17];
    const float* qu3  = (const float*)d_in[18];
    float* out = (float*)d_out;

    const size_t flat_bytes = (size_t)1024 * 9216 * 2;
    const size_t part_bytes = (size_t)16 * 1024 * 128 * 4;
    const size_t w2t_bytes  = (size_t)18432 * 2;
    const size_t fw1h_bytes = (size_t)128 * 9216 * 2;
    const size_t o_flat = 0;
    const size_t o_part = o_flat + flat_bytes;
    const size_t o_w2t  = o_part + part_bytes;
    const size_t o_fw1h = o_w2t + w2t_bytes;
    const size_t need   = o_fw1h + fw1h_bytes;

    (void)hipGetLastError();

    if (ws_size >= need) {
        _Float16* flat = (_Float16*)((char*)d_ws + o_flat);
        float*    part = (float*)((char*)d_ws + o_part);
        _Float16* w2t  = (_Float16*)((char*)d_ws + o_w2t);
        _Float16* fw1h = (_Float16*)((char*)d_ws + o_fw1h);
        prep_all<<<1224, 256, 0, stream>>>(fw1, fw1h, w2, w2t);
        convnet_mfma<<<1024, 256, 0, stream>>>(x, w1, b1, w2t, b2, flat);
        fc1_mfma<<<dim3(16, 2, 16), 256, 0, stream>>>(flat, fw1h, part);
        circuit_wave<<<256, 256, 0, stream>>>(part, fb1, fw2, fb2,
                                              qrx, qrz3, qps6, qrot7, qmrz8,
                                              qcrx9, qcry10, qcrz11, qu2, qu3, out);
    } else {
        fused_kernel<<<1024, 512, 0, stream>>>(x, w1, b1, w2, b2, fw1, fb1, fw2, fb2,
                                               qrx, qrz3, qps6, qrot7, qmrz8,
                                               qcrx9, qcry10, qcrz11, qu2, qu3, out);
    }
    if (hipGetLastError() != hipSuccess) {
        (void)hipMemsetAsync(d_out, 0x7F, (size_t)out_size * 2, stream);
    }
}

// Round 11
// 186.543 us; speedup vs baseline: 1.0510x; 1.0098x over previous
//
#include <hip/hip_runtime.h>
#include <hip/hip_bf16.h>

#define PI_F 3.14159265358979323846f

// Loader insurance: keep a kernel with the stub's exact name (not launched).
__global__ void Static_82300163326800_kernel() {}

typedef _Float16 f16x8 __attribute__((ext_vector_type(8)));
typedef _Float16 f16x4 __attribute__((ext_vector_type(4)));
typedef float f32x4 __attribute__((ext_vector_type(4)));

// ===================== shared gate-matrix helpers =====================
struct M2 { float2 m00, m01, m10, m11; };

__device__ __forceinline__ float2 cmul2(float2 a, float2 b) {
    return make_float2(a.x*b.x - a.y*b.y, a.x*b.y + a.y*b.x);
}
__device__ __forceinline__ float2 cadd2(float2 a, float2 b) {
    return make_float2(a.x+b.x, a.y+b.y);
}
__device__ __forceinline__ M2 m2mul(M2 b, M2 a) {   // gate a first, then b => b*a
    return { cadd2(cmul2(b.m00,a.m00), cmul2(b.m01,a.m10)),
             cadd2(cmul2(b.m00,a.m01), cmul2(b.m01,a.m11)),
             cadd2(cmul2(b.m10,a.m00), cmul2(b.m11,a.m10)),
             cadd2(cmul2(b.m10,a.m01), cmul2(b.m11,a.m11)) };
}
__device__ __forceinline__ M2 mrx(float th) {
    float s, c; __sincosf(0.5f * th, &s, &c);
    return { make_float2(c,0.f), make_float2(0.f,-s), make_float2(0.f,-s), make_float2(c,0.f) };
}
__device__ __forceinline__ M2 mry(float th) {
    float s, c; __sincosf(0.5f * th, &s, &c);
    return { make_float2(c,0.f), make_float2(-s,0.f), make_float2(s,0.f), make_float2(c,0.f) };
}
__device__ __forceinline__ M2 mrot(float phi, float th, float om) {
    float s, c;  __sincosf(0.5f * th, &s, &c);
    float sa, ca; __sincosf(0.5f * (phi + om), &sa, &ca);
    float sd, cd; __sincosf(0.5f * (phi - om), &sd, &cd);
    return { make_float2(ca*c, -sa*c), make_float2(-cd*s, -sd*s),
             make_float2(cd*s, -sd*s), make_float2(ca*c,  sa*c) };
}
__device__ __forceinline__ M2 mu2(float phi, float lam) {
    const float r = 0.7071067811865476f;
    float sl, cl;   __sincosf(lam, &sl, &cl);
    float sp, cp;   __sincosf(phi, &sp, &cp);
    float spl, cpl; __sincosf(phi + lam, &spl, &cpl);
    return { make_float2(r,0.f), make_float2(-r*cl,-r*sl),
             make_float2(r*cp, r*sp), make_float2(r*cpl, r*spl) };
}
__device__ __forceinline__ M2 mu3(float th, float phi, float lam) {
    float s, c;     __sincosf(0.5f * th, &s, &c);
    float sl, cl;   __sincosf(lam, &sl, &cl);
    float sp, cp;   __sincosf(phi, &sp, &cp);
    float spl, cpl; __sincosf(phi + lam, &spl, &cpl);
    return { make_float2(c,0.f), make_float2(-cl*s,-sl*s),
             make_float2(cp*s, sp*s), make_float2(cpl*c, spl*c) };
}

// ===================== per-wave register circuit primitives =====================
// Amplitude index i = (lane<<4) | r.  wire w<=5 -> lane bit (5-w); w>=6 -> r bit (9-w).
// Two-phase shuffle batches (all shfls, then math) so they stay in flight.

__device__ __forceinline__ void applyL(float2* s, M2 m, int lane, int q) {
    const int bitv = (lane >> q) & 1;
    const float2 cA = bitv ? m.m11 : m.m00;
    const float2 cB = bitv ? m.m10 : m.m01;
    float ox[16], oy[16];
#pragma unroll
    for (int r = 0; r < 16; ++r) {
        ox[r] = __shfl_xor(s[r].x, 1 << q);
        oy[r] = __shfl_xor(s[r].y, 1 << q);
    }
#pragma unroll
    for (int r = 0; r < 16; ++r)
        s[r] = make_float2(cA.x*s[r].x - cA.y*s[r].y + cB.x*ox[r] - cB.y*oy[r],
                           cA.x*s[r].y + cA.y*s[r].x + cB.x*oy[r] + cB.y*ox[r]);
}
template<int P>
__device__ __forceinline__ void applyR(float2* s, M2 m) {
#pragma unroll
    for (int r0 = 0; r0 < 16; ++r0) {
        if (r0 & (1 << P)) continue;
        const int r1 = r0 | (1 << P);
        float2 a = s[r0], d = s[r1];
        s[r0] = cadd2(cmul2(m.m00, a), cmul2(m.m01, d));
        s[r1] = cadd2(cmul2(m.m10, a), cmul2(m.m11, d));
    }
}
__device__ __forceinline__ void diagL(float2* s, float2 d0, float2 d1, int lane, int q) {
    const int bitv = (lane >> q) & 1;
    const float2 f = bitv ? d1 : d0;
#pragma unroll
    for (int r = 0; r < 16; ++r) s[r] = cmul2(f, s[r]);
}
template<int P>
__device__ __forceinline__ void diagR(float2* s, float2 d0, float2 d1) {
#pragma unroll
    for (int r = 0; r < 16; ++r) {
        const float2 f = (r & (1 << P)) ? d1 : d0;
        s[r] = cmul2(f, s[r]);
    }
}
__device__ __forceinline__ void cnotLL(float2* s, int lane, int qc, int qw) {
    const int cb = (lane >> qc) & 1;
    float ox[16], oy[16];
#pragma unroll
    for (int r = 0; r < 16; ++r) {
        ox[r] = __shfl_xor(s[r].x, 1 << qw);
        oy[r] = __shfl_xor(s[r].y, 1 << qw);
    }
#pragma unroll
    for (int r = 0; r < 16; ++r)
        s[r] = cb ? make_float2(ox[r], oy[r]) : s[r];
}
__device__ __forceinline__ void capplyLL(float2* s, M2 m, int lane, int qc, int qw) {
    const int cb = (lane >> qc) & 1, tb = (lane >> qw) & 1;
    float2 cA = tb ? m.m11 : m.m00;
    float2 cB = tb ? m.m10 : m.m01;
    cA = cb ? cA : make_float2(1.f, 0.f);
    cB = cb ? cB : make_float2(0.f, 0.f);
    float ox[16], oy[16];
#pragma unroll
    for (int r = 0; r < 16; ++r) {
        ox[r] = __shfl_xor(s[r].x, 1 << qw);
        oy[r] = __shfl_xor(s[r].y, 1 << qw);
    }
#pragma unroll
    for (int r = 0; r < 16; ++r)
        s[r] = make_float2(cA.x*s[r].x - cA.y*s[r].y + cB.x*ox[r] - cB.y*oy[r],
                           cA.x*s[r].y + cA.y*s[r].x + cB.x*oy[r] + cB.y*ox[r]);
}
__device__ __forceinline__ void cdiagLL(float2* s, float2 d0, float2 d1, int lane, int qc, int qw) {
    const int cb = (lane >> qc) & 1, tb = (lane >> qw) & 1;
    float2 f = tb ? d1 : d0;
    f = cb ? f : make_float2(1.f, 0.f);
#pragma unroll
    for (int r = 0; r < 16; ++r) s[r] = cmul2(f, s[r]);
}
template<int P>
__device__ __forceinline__ void capplyRL(float2* s, M2 m, int lane, int qc) {
    const int cb = (lane >> qc) & 1;
#pragma unroll
    for (int r0 = 0; r0 < 16; ++r0) {
        if (r0 & (1 << P)) continue;
        const int r1 = r0 | (1 << P);
        float2 a = s[r0], d = s[r1];
        float2 na = cadd2(cmul2(m.m00, a), cmul2(m.m01, d));
        float2 nd = cadd2(cmul2(m.m10, a), cmul2(m.m11, d));
        s[r0] = cb ? na : a;
        s[r1] = cb ? nd : d;
    }
}

// ===================== per-wave circuit kernel: 1 wave = 1 sample ==============
// r7-measured-fast configuration: reads precomputed angles, launch_bounds(256,1),
// no readfirstlane wrapping, no waves_per_eu cap. (r9/r10's fc2-fusion header
// regressed this kernel 44 -> ~100 us; reverted.)
__global__ __launch_bounds__(256, 1) void circuit_wave(
    const float* __restrict__ ang_g,
    const float* __restrict__ q_rx, const float* __restrict__ q_rz3,
    const float* __restrict__ q_ps6, const float* __restrict__ q_rot7,
    const float* __restrict__ q_mrz8, const float* __restrict__ q_crx9,
    const float* __restrict__ q_cry10, const float* __restrict__ q_crz11,
    const float* __restrict__ q_u2, const float* __restrict__ q_u3,
    float* __restrict__ out)
{
    const int t = threadIdx.x, lane = t & 63, wv = t >> 6;
    const int b = blockIdx.x * 4 + wv;
    float ang[10];
#pragma unroll
    for (int j = 0; j < 10; ++j) ang[j] = ang_g[b * 10 + j];

    float2 s[16];
#pragma unroll
    for (int r = 0; r < 16; ++r) s[r] = make_float2(0.f, 0.f);
    if (lane == 0) s[0].x = 1.f;

    // L1: trainable RX on wires 0..9
    applyL(s, mrx(q_rx[0]), lane, 5);
    applyL(s, mrx(q_rx[1]), lane, 4);
    applyL(s, mrx(q_rx[2]), lane, 3);
    applyL(s, mrx(q_rx[3]), lane, 2);
    applyL(s, mrx(q_rx[4]), lane, 1);
    applyL(s, mrx(q_rx[5]), lane, 0);
    applyR<3>(s, mrx(q_rx[6]));
    applyR<2>(s, mrx(q_rx[7]));
    applyR<1>(s, mrx(q_rx[8]));
    applyR<0>(s, mrx(q_rx[9]));
    // L2 fused: RY(ang[k]) on k, then the ten commuting RX(ang0) -> RX(10*ang0)
    applyL(s, mry(ang[0]), lane, 5);
    applyL(s, mry(ang[1]), lane, 4);
    applyL(s, mry(ang[2]), lane, 3);
    applyL(s, mry(ang[3]), lane, 2);
    applyL(s, mry(ang[4]), lane, 1);
    applyL(s, mry(ang[5]), lane, 0);
    applyR<3>(s, mry(ang[6]));
    applyR<2>(s, mry(ang[7]));
    applyR<1>(s, mry(ang[8]));
    applyR<0>(s, mry(ang[9]));
    applyL(s, mrx(10.f * ang[0]), lane, 5);
    // CNOT ring (k,k+1) then (9,0)
    cnotLL(s, lane, 5, 4);
    cnotLL(s, lane, 4, 3);
    cnotLL(s, lane, 3, 2);
    cnotLL(s, lane, 2, 1);
    cnotLL(s, lane, 1, 0);
    { // (5,6): ctrl lane bit0, target r bit3
        const int cb = lane & 1;
#pragma unroll
        for (int r0 = 0; r0 < 8; ++r0) {
            float2 a = s[r0], d = s[r0 + 8];
            s[r0] = cb ? d : a; s[r0 + 8] = cb ? a : d;
        }
    }
    { // (6,7)
        float2 u;
        u = s[8];  s[8]  = s[12]; s[12] = u;
        u = s[9];  s[9]  = s[13]; s[13] = u;
        u = s[10]; s[10] = s[14]; s[14] = u;
        u = s[11]; s[11] = s[15]; s[15] = u;
    }
    { // (7,8)
        float2 u;
        u = s[4];  s[4]  = s[6];  s[6]  = u;
        u = s[5];  s[5]  = s[7];  s[7]  = u;
        u = s[12]; s[12] = s[14]; s[14] = u;
        u = s[13]; s[13] = s[15]; s[15] = u;
    }
    { // (8,9)
        float2 u;
        u = s[2];  s[2]  = s[3];  s[3]  = u;
        u = s[6];  s[6]  = s[7];  s[7]  = u;
        u = s[10]; s[10] = s[11]; s[11] = u;
        u = s[14]; s[14] = s[15]; s[15] = u;
    }
    { // (9,0): r bit0 ctrl, target lane bit5
        float ox[8], oy[8];
#pragma unroll
        for (int k = 0; k < 8; ++k) {
            ox[k] = __shfl_xor(s[2*k+1].x, 32);
            oy[k] = __shfl_xor(s[2*k+1].y, 32);
        }
#pragma unroll
        for (int k = 0; k < 8; ++k) s[2*k+1] = make_float2(ox[k], oy[k]);
    }

    applyL(s, mrx(ang[1]), lane, 4);
    applyL(s, mrx(-PI_F / 4.f), lane, 0);
    applyL(s, mry(ang[2]), lane, 3);
    { float sn, cs; __sincosf(0.5f * ang[3], &sn, &cs);
      diagL(s, make_float2(cs,-sn), make_float2(cs,sn), lane, 2); }          // RZ on 3
    diagL(s, make_float2(1.f,0.f), make_float2(0.f,1.f), lane, 1);           // S on 4
    diagL(s, make_float2(1.f,0.f),
          make_float2(0.7071067811865476f, 0.7071067811865476f), lane, 0);   // T on 5
    { float sn, cs; __sincosf(0.5f * q_rz3[0], &sn, &cs);
      diagR<3>(s, make_float2(cs,-sn), make_float2(cs,sn)); }                // RZ on 6
    { M2 m = { make_float2(0.5f,0.5f), make_float2(0.5f,-0.5f),
               make_float2(0.5f,-0.5f), make_float2(0.5f,0.5f) };
      applyR<2>(s, m); }                                                     // SX on 7
    { // CZ;CNOT;CY on (0,5) fused: phase -i iff wire0 bit = 1
        const int cb = (lane >> 5) & 1;
#pragma unroll
        for (int r = 0; r < 16; ++r)
            s[r] = cb ? make_float2(s[r].y, -s[r].x) : s[r];
    }
    { // CY(3,8): ctrl lane bit2, target r bit1
        const int cb = (lane >> 2) & 1;
#pragma unroll
        for (int r0 = 0; r0 < 16; ++r0) {
            if (r0 & 2) continue;
            const int r1 = r0 | 2;
            float2 a = s[r0], d = s[r1];
            float2 na = make_float2(d.y, -d.x);
            float2 nd = make_float2(-a.y, a.x);
            s[r0] = cb ? na : a; s[r1] = cb ? nd : d;
        }
    }
    { // SWAP(2,3): lane bits 3,2
        const int pr = ((lane >> 3) & 1) ^ ((lane >> 2) & 1);
        float ox[16], oy[16];
#pragma unroll
        for (int r = 0; r < 16; ++r) {
            ox[r] = __shfl_xor(s[r].x, 12);
            oy[r] = __shfl_xor(s[r].y, 12);
        }
#pragma unroll
        for (int r = 0; r < 16; ++r)
            s[r] = pr ? make_float2(ox[r], oy[r]) : s[r];
    }
    { // CSWAP(4;5,6): ctrl lane bit1; swap lane bit0 <-> r bit3
        float ox[16], oy[16];
#pragma unroll
        for (int r = 0; r < 16; ++r) {
            ox[r] = __shfl_xor(s[r ^ 8].x, 1);
            oy[r] = __shfl_xor(s[r ^ 8].y, 1);
        }
        const int cb = (lane >> 1) & 1, lb = lane & 1;
#pragma unroll
        for (int r = 0; r < 16; ++r) {
            const int pr = cb & ((r & 8) ? (1 - lb) : lb);
            s[r] = pr ? make_float2(ox[r], oy[r]) : s[r];
        }
    }
    { // TOFF(8,5;0): ctrl r bit1 & lane bit0; target lane bit5
        const int lb = lane & 1;
        float ox[8], oy[8];
        const int idx8[8] = {2,3,6,7,10,11,14,15};
#pragma unroll
        for (int k = 0; k < 8; ++k) {
            ox[k] = __shfl_xor(s[idx8[k]].x, 32);
            oy[k] = __shfl_xor(s[idx8[k]].y, 32);
        }
#pragma unroll
        for (int k = 0; k < 8; ++k)
            s[idx8[k]] = lb ? make_float2(ox[k], oy[k]) : s[idx8[k]];
    }
    { float sn, cs; __sincosf(q_ps6[0], &sn, &cs);
      diagR<1>(s, make_float2(1.f,0.f), make_float2(cs,sn)); }               // PS on 8
    { float sn, cs; __sincosf(ang[7], &sn, &cs);
      diagR<2>(s, make_float2(1.f,0.f), make_float2(cs,sn)); }               // PS on 7
    applyL(s, mrot(q_rot7[0], q_rot7[1], q_rot7[2]), lane, 1);               // ROT on 4
    applyL(s, mrot(ang[6], ang[7], ang[8]), lane, 0);                        // ROT on 5
    { // multiRZ(q_mrz8) wires (2,3,4,5,6)
        float sh, ch; __sincosf(0.5f * q_mrz8[0], &sh, &ch);
        const int lp = __popc(lane & 0xF) & 1;
        const float sg0 = lp ? sh : -sh;
#pragma unroll
        for (int r = 0; r < 16; ++r) {
            const float sg = (r & 8) ? -sg0 : sg0;
            float2 a = s[r];
            s[r] = make_float2(ch*a.x - sg*a.y, ch*a.y + sg*a.x);
        }
    }
    { // multiRZ(ang[5]) wires (3,4,6,7,8)
        float sh, ch; __sincosf(0.5f * ang[5], &sh, &ch);
        const int lp = __popc(lane & 6) & 1;
        const float sg0 = lp ? sh : -sh;
#pragma unroll
        for (int r = 0; r < 16; ++r) {
            const int rp = __popc(r & 14) & 1;
            const float sg = rp ? -sg0 : sg0;
            float2 a = s[r];
            s[r] = make_float2(ch*a.x - sg*a.y, ch*a.y + sg*a.x);
        }
    }
    capplyLL(s, mrx(ang[6]), lane, 5, 4);       // CRX(0,1)
    capplyLL(s, mrx(q_crx9[0]), lane, 1, 0);    // CRX(4,5)
    capplyLL(s, mry(ang[6]), lane, 5, 4);       // CRY(0,1)
    capplyLL(s, mry(q_cry10[0]), lane, 1, 0);   // CRY(4,5)
    { float sn, cs; __sincosf(0.5f * ang[6], &sn, &cs);
      cdiagLL(s, make_float2(cs,-sn), make_float2(cs,sn), lane, 5, 4); }     // CRZ(0,1)
    { float sn, cs; __sincosf(0.5f * q_crz11[0], &sn, &cs);
      cdiagLL(s, make_float2(cs,-sn), make_float2(cs,sn), lane, 1, 0); }     // CRZ(4,5)
    capplyRL<3>(s, mrot(-PI_F/4.f, PI_F/4.f, PI_F/2.f), lane, 0);            // CROT(5,6)
    { // CROT(7,8): pairs {4,5,12,13}
        M2 m = mrot(ang[5], ang[6], ang[7]);
        const int idx4[4] = {4, 5, 12, 13};
#pragma unroll
        for (int k = 0; k < 4; ++k) {
            const int r0 = idx4[k], r1 = r0 | 2;
            float2 a = s[r0], d = s[r1];
            s[r0] = cadd2(cmul2(m.m00, a), cmul2(m.m01, d));
            s[r1] = cadd2(cmul2(m.m10, a), cmul2(m.m11, d));
        }
    }
    { float sn, cs; __sincosf(PI_F / 7.f, &sn, &cs);
      diagL(s, make_float2(1.f,0.f), make_float2(cs,sn), lane, 4); }         // U1 on 1
    { float sn, cs; __sincosf(ang[9], &sn, &cs);
      diagL(s, make_float2(1.f,0.f), make_float2(cs,sn), lane, 3); }         // PS on 2
    applyR<1>(s, mu2(q_u2[0], q_u2[1]));                                     // U2 on 8
    applyL(s, mu2(ang[0], ang[1]), lane, 1);                                 // U2 on 4
    applyL(s, m2mul(mu3(ang[4], ang[5], ang[6]),
                    mu3(q_u3[0], q_u3[1], q_u3[2])), lane, 0);               // U3*U3 on 5
    cnotLL(s, lane, 4, 3);                                                   // CNOT(1,2)

    // <Y_w> then log_softmax
    float ev[10];
#pragma unroll
    for (int w = 0; w < 6; ++w) {
        const int q = 5 - w;
        const int bitv = (lane >> q) & 1;
        float ox[16], oy[16];
#pragma unroll
        for (int r = 0; r < 16; ++r) {
            ox[r] = __shfl_xor(s[r].x, 1 << q);
            oy[r] = __shfl_xor(s[r].y, 1 << q);
        }
        float acc = 0.f;
#pragma unroll
        for (int r = 0; r < 16; ++r)
            acc += s[r].x * oy[r] - s[r].y * ox[r];
        ev[w] = bitv ? 0.f : 2.f * acc;
    }
#pragma unroll
    for (int w = 6; w < 10; ++w) {
        const int P = 9 - w;
        float acc = 0.f;
#pragma unroll
        for (int r0 = 0; r0 < 16; ++r0) {
            if (r0 & (1 << P)) continue;
            const int r1 = r0 | (1 << P);
            acc += s[r0].x * s[r1].y - s[r0].y * s[r1].x;
        }
        ev[w] = 2.f * acc;
    }
#pragma unroll
    for (int w = 0; w < 10; ++w) {
        float v = ev[w];
        v += __shfl_down(v, 32); v += __shfl_down(v, 16); v += __shfl_down(v, 8);
        v += __shfl_down(v, 4);  v += __shfl_down(v, 2);  v += __shfl_down(v, 1);
        ev[w] = v;
    }
    if (lane == 0) {
        float mx = ev[0];
#pragma unroll
        for (int i = 1; i < 10; ++i) mx = fmaxf(mx, ev[i]);
        float ss = 0.f;
#pragma unroll
        for (int i = 0; i < 10; ++i) ss += expf(ev[i] - mx);
        const float ls = logf(ss);
#pragma unroll
        for (int i = 0; i < 10; ++i) out[b * 10 + i] = ev[i] - mx - ls;
    }
}

// ============ prep (merged): fw1 -> f16 and w2 -> transposed f16 ============
__global__ __launch_bounds__(256) void prep_all(
    const float* __restrict__ fw1, _Float16* __restrict__ fw1h,
    const float* __restrict__ w2, _Float16* __restrict__ w2t)
{
    const int blk = blockIdx.x;
    if (blk < 1152) {
        int i = blk * 256 + threadIdx.x;   // 294912 float4 groups
        float4 v = ((const float4*)fw1)[i];
        f16x4 o = { (_Float16)v.x, (_Float16)v.y, (_Float16)v.z, (_Float16)v.w };
        *(f16x4*)(fw1h + i * 4) = o;
    } else {
        int idx = (blk - 1152) * 256 + threadIdx.x;
        if (idx < 18432) {
            int oc = idx / 288, r = idx - oc * 288;
            int s = r >> 5, ic = r & 31;
            w2t[idx] = (_Float16)w2[oc * 288 + ic * 9 + s];
        }
    }
}

// ===================== MFMA convnet =====================
__global__ __launch_bounds__(256, 2) void convnet_mfma(
    const float* __restrict__ x, const float* __restrict__ w1, const float* __restrict__ b1,
    const _Float16* __restrict__ w2t, const float* __restrict__ b2,
    _Float16* __restrict__ flat)
{
    __shared__ float xs[784];
    __shared__ __align__(16) float w1t[288];              // [k][ic] transposed
    __shared__ __align__(16) _Float16 h1t[676 * 40];      // [pix][ic], stride 40
    const int n = blockIdx.x, t = threadIdx.x;
    const int lane = t & 63, wv = t >> 6;
    const int m = lane & 15, quad = lane >> 4;

    for (int i = t; i < 784; i += 256) xs[i] = x[n * 784 + i];
    for (int i = t; i < 288; i += 256) {   // grid-stride: 288 > 256 (r8 bug fix)
        int ic = i / 9, k = i - ic * 9;
        w1t[k * 32 + ic] = w1[i];
    }
    __syncthreads();

    // conv1
    {
        const int icg = t & 3;
        float w[9][8];
#pragma unroll
        for (int k = 0; k < 9; ++k) {
            float4 a = *(const float4*)&w1t[k * 32 + icg * 8];
            float4 bsec = *(const float4*)&w1t[k * 32 + icg * 8 + 4];
            w[k][0] = a.x; w[k][1] = a.y; w[k][2] = a.z; w[k][3] = a.w;
            w[k][4] = bsec.x; w[k][5] = bsec.y; w[k][6] = bsec.z; w[k][7] = bsec.w;
        }
        float bb[8];
#pragma unroll
        for (int j = 0; j < 8; ++j) bb[j] = b1[icg * 8 + j];
        for (int pix = t >> 2; pix < 676; pix += 64) {
            const int yy = pix / 26, xx = pix - yy * 26;
            const float* xp = xs + yy * 28 + xx;
            float acc[8];
#pragma unroll
            for (int j = 0; j < 8; ++j) acc[j] = bb[j];
#pragma unroll
            for (int ky = 0; ky < 3; ++ky)
#pragma unroll
                for (int kx = 0; kx < 3; ++kx) {
                    const float xv = xp[ky * 28 + kx];
                    const int k = ky * 3 + kx;
#pragma unroll
                    for (int j = 0; j < 8; ++j) acc[j] += xv * w[k][j];
                }
            f16x8 o;
#pragma unroll
            for (int j = 0; j < 8; ++j) o[j] = (_Float16)fmaxf(acc[j], 0.f);
            *(f16x8*)&h1t[pix * 40 + icg * 8] = o;
        }
    }

    f16x8 bq[9][4];
#pragma unroll
    for (int s = 0; s < 9; ++s)
#pragma unroll
        for (int nt = 0; nt < 4; ++nt)
            bq[s][nt] = *(const f16x8*)(w2t + (nt * 16 + m) * 288 + s * 32 + quad * 8);

    __syncthreads();

    float bb2[4];
#pragma unroll
    for (int nt = 0; nt < 4; ++nt) bb2[nt] = b2[nt * 16 + m];

    _Float16* outp = flat + (size_t)n * 9216;

    for (int q = 0; q < 9; ++q) {
        const int mt = wv + q * 4;
        const int a = mt / 3, b3 = mt - a * 3;
        const int y0 = 2 * a + (m & 1), x0 = 8 * b3 + (m >> 1);
        f32x4 acc[4] = {};
#pragma unroll
        for (int s = 0; s < 9; ++s) {
            const int ky = s / 3, kx = s - ky * 3;
            f16x8 af = *(const f16x8*)&h1t[((y0 + ky) * 26 + x0 + kx) * 40 + quad * 8];
#pragma unroll
            for (int nt = 0; nt < 4; ++nt)
                acc[nt] = __builtin_amdgcn_mfma_f32_16x16x32_f16(af, bq[s][nt], acc[nt], 0, 0, 0);
        }
        const int pooled_idx = a * 12 + 4 * b3 + quad;
#pragma unroll
        for (int nt = 0; nt < 4; ++nt) {
            float v = fmaxf(fmaxf(acc[nt][0], acc[nt][1]), fmaxf(acc[nt][2], acc[nt][3]));
            outp[(nt * 16 + m) * 144 + pooled_idx] = (_Float16)fmaxf(v + bb2[nt], 0.f);
        }
    }
}

// ===================== fc1 MFMA: [1024,9216]f16 @ [128,9216]^T f16, K split 16 ======
__global__ __launch_bounds__(256) void fc1_mfma(
    const _Float16* __restrict__ A, const _Float16* __restrict__ B, float* __restrict__ part)
{
    const int m0 = blockIdx.x * 64, n0 = blockIdx.y * 64, kb = blockIdx.z;
    const int t = threadIdx.x, lane = t & 63, wv = t >> 6;
    const int r = lane & 15, quad = lane >> 4;
    const _Float16* ap = A + (size_t)(m0 + wv * 16 + r) * 9216 + kb * 576 + quad * 8;
    const _Float16* bp = B + (size_t)(n0 + r) * 9216 + kb * 576 + quad * 8;
    f32x4 acc[4] = {};
    for (int ks = 0; ks < 576; ks += 32) {
        f16x8 af = *(const f16x8*)(ap + ks);
#pragma unroll
        for (int nt = 0; nt < 4; ++nt) {
            f16x8 bfr = *(const f16x8*)(bp + (size_t)nt * 16 * 9216 + ks);
            acc[nt] = __builtin_amdgcn_mfma_f32_16x16x32_f16(af, bfr, acc[nt], 0, 0, 0);
        }
    }
    float* pp = part + (size_t)kb * 131072 + (size_t)(m0 + wv * 16 + quad * 4) * 128 + n0 + r;
#pragma unroll
    for (int nt = 0; nt < 4; ++nt)
#pragma unroll
        for (int reg = 0; reg < 4; ++reg)
            pp[reg * 128 + nt * 16] = acc[nt][reg];
}

// ===================== fc2 + sigmoid*2pi (sums 16 split-K slabs) =====================
__global__ __launch_bounds__(128) void fc2_kernel(
    const float* __restrict__ part, const float* __restrict__ fb1,
    const float* __restrict__ fw2, const float* __restrict__ fb2, float* __restrict__ angO)
{
    __shared__ float h[128];
    const int b = blockIdx.x, t = threadIdx.x;
    float s = fb1[t];
#pragma unroll
    for (int kb = 0; kb < 16; ++kb) s += part[(size_t)kb * 131072 + b * 128 + t];
    h[t] = fmaxf(s, 0.f);
    __syncthreads();
    if (t < 10) {
        float d = fb2[t];
#pragma unroll 16
        for (int k = 0; k < 128; ++k) d += h[k] * fw2[t * 128 + k];
        angO[b * 10 + t] = 6.283185307179586f / (1.f + expf(-d));
    }
}

// ===================== FALLBACK: fully fused fp32, zero workspace =====================
__device__ __forceinline__ int ins1(int x, int p) {
    return ((x >> p) << (p + 1)) | (x & ((1 << p) - 1));
}
__device__ __forceinline__ void apply1(float2* st, int t, int w, M2 m) {
    int p = 9 - w;
    int i0 = ins1(t, p), i1 = i0 | (1 << p);
    float2 a = st[i0], d = st[i1];
    st[i0] = cadd2(cmul2(m.m00, a), cmul2(m.m01, d));
    st[i1] = cadd2(cmul2(m.m10, a), cmul2(m.m11, d));
}
__device__ __forceinline__ void diag1(float2* st, int t, int w, float2 d0, float2 d1) {
    int p = 9 - w;
    int i0 = ins1(t, p), i1 = i0 | (1 << p);
    st[i0] = cmul2(d0, st[i0]);
    st[i1] = cmul2(d1, st[i1]);
}
__device__ __forceinline__ void capply1(float2* st, int t, int c, int w, M2 m) {
    if (t < 256) {
        int pc = 9 - c, pw = 9 - w;
        int pl = pc < pw ? pc : pw, ph = pc + pw - pl;
        int base = ins1(ins1(t, pl), ph) | (1 << pc);
        int i0 = base, i1 = base | (1 << pw);
        float2 a = st[i0], d = st[i1];
        st[i0] = cadd2(cmul2(m.m00, a), cmul2(m.m01, d));
        st[i1] = cadd2(cmul2(m.m10, a), cmul2(m.m11, d));
    }
}
__device__ __forceinline__ void cdiag1(float2* st, int t, int c, int w, float2 d0, float2 d1) {
    if (t < 256) {
        int pc = 9 - c, pw = 9 - w;
        int pl = pc < pw ? pc : pw, ph = pc + pw - pl;
        int base = ins1(ins1(t, pl), ph) | (1 << pc);
        st[base] = cmul2(d0, st[base]);
        st[base | (1 << pw)] = cmul2(d1, st[base | (1 << pw)]);
    }
}
__device__ __forceinline__ void cnotg(float2* st, int t, int c, int w) {
    if (t < 256) {
        int pc = 9 - c, pw = 9 - w;
        int pl = pc < pw ? pc : pw, ph = pc + pw - pl;
        int base = ins1(ins1(t, pl), ph) | (1 << pc);
        int i1 = base | (1 << pw);
        float2 a = st[base]; st[base] = st[i1]; st[i1] = a;
    }
}
__device__ __forceinline__ void czg(float2* st, int t, int c, int w) {
    if (t < 256) {
        int pc = 9 - c, pw = 9 - w;
        int pl = pc < pw ? pc : pw, ph = pc + pw - pl;
        int i = ins1(ins1(t, pl), ph) | (1 << pc) | (1 << pw);
        st[i] = make_float2(-st[i].x, -st[i].y);
    }
}
__device__ __forceinline__ void swapg(float2* st, int t, int a, int b_) {
    if (t < 256) {
        int pa = 9 - a, pb = 9 - b_;
        int pl = pa < pb ? pa : pb, ph = pa + pb - pl;
        int base = ins1(ins1(t, pl), ph);
        int iA = base | (1 << pa), iB = base | (1 << pb);
        float2 u = st[iA]; st[iA] = st[iB]; st[iB] = u;
    }
}
__device__ __forceinline__ void cswap456f(float2* st, int t) {
    if (t < 128) {
        int base = ins1(ins1(ins1(t, 3), 4), 5) | (1 << 5);
        int iA = base | (1 << 4), iB = base | (1 << 3);
        float2 u = st[iA]; st[iA] = st[iB]; st[iB] = u;
    }
}
__device__ __forceinline__ void toff850f(float2* st, int t) {
    if (t < 128) {
        int base = ins1(ins1(ins1(t, 1), 4), 9) | (1 << 1) | (1 << 4);
        int i1 = base | (1 << 9);
        float2 u = st[base]; st[base] = st[i1]; st[i1] = u;
    }
}
__device__ __forceinline__ void mrzg(float2* st, int t, int mask, float th) {
    float sh, ch; __sincosf(0.5f * th, &sh, &ch);
#pragma unroll
    for (int q = 0; q < 2; ++q) {
        int i = t + q * 512;
        float sg = (__popc(i & mask) & 1) ? sh : -sh;
        float2 a = st[i];
        st[i] = make_float2(ch*a.x - sg*a.y, ch*a.y + sg*a.x);
    }
}
__device__ __forceinline__ void run_circ(
    float2* st, float (*red)[10], float* evs, int t, const float* ang,
    const float* q_rx, const float* q_rz3, const float* q_ps6, const float* q_rot7,
    const float* q_mrz8, const float* q_crx9, const float* q_cry10, const float* q_crz11,
    const float* q_u2, const float* q_u3, float* outf)
{
    st[t] = make_float2(t == 0 ? 1.f : 0.f, 0.f);
    st[t + 512] = make_float2(0.f, 0.f);
#pragma unroll
    for (int k = 0; k < 10; ++k) { M2 m = mrx(q_rx[k]); __syncthreads(); apply1(st, t, k, m); }
    {
        M2 mx0 = mrx(ang[0]);
#pragma unroll
        for (int k = 0; k < 10; ++k) {
            M2 m = mry(ang[k]); __syncthreads(); apply1(st, t, k, m);
            __syncthreads(); apply1(st, t, 0, mx0);
        }
    }
#pragma unroll
    for (int k = 0; k < 9; ++k) { __syncthreads(); cnotg(st, t, k, k + 1); }
    __syncthreads(); cnotg(st, t, 9, 0);
    { M2 m = mrx(ang[1]);      __syncthreads(); apply1(st, t, 1, m); }
    { M2 m = mrx(-PI_F / 4.f); __syncthreads(); apply1(st, t, 5, m); }
    { M2 m = mry(ang[2]);      __syncthreads(); apply1(st, t, 2, m); }
    { float s, c; __sincosf(0.5f * ang[3], &s, &c);
      __syncthreads(); diag1(st, t, 3, make_float2(c,-s), make_float2(c,s)); }
    __syncthreads(); diag1(st, t, 4, make_float2(1.f,0.f), make_float2(0.f,1.f));
    __syncthreads(); diag1(st, t, 5, make_float2(1.f,0.f),
                           make_float2(0.7071067811865476f, 0.7071067811865476f));
    { float s, c; __sincosf(0.5f * q_rz3[0], &s, &c);
      __syncthreads(); diag1(st, t, 6, make_float2(c,-s), make_float2(c,s)); }
    { M2 m = { make_float2(0.5f,0.5f), make_float2(0.5f,-0.5f),
               make_float2(0.5f,-0.5f), make_float2(0.5f,0.5f) };
      __syncthreads(); apply1(st, t, 7, m); }
    __syncthreads(); czg(st, t, 0, 5);
    __syncthreads(); cnotg(st, t, 0, 5);
    { M2 y = { make_float2(0.f,0.f), make_float2(0.f,-1.f),
               make_float2(0.f,1.f), make_float2(0.f,0.f) };
      __syncthreads(); capply1(st, t, 0, 5, y);
      __syncthreads(); capply1(st, t, 3, 8, y); }
    __syncthreads(); swapg(st, t, 2, 3);
    __syncthreads(); cswap456f(st, t);
    __syncthreads(); toff850f(st, t);
    { float s, c; __sincosf(q_ps6[0], &s, &c);
      __syncthreads(); diag1(st, t, 8, make_float2(1.f,0.f), make_float2(c,s)); }
    { float s, c; __sincosf(ang[7], &s, &c);
      __syncthreads(); diag1(st, t, 7, make_float2(1.f,0.f), make_float2(c,s)); }
    { M2 m = mrot(q_rot7[0], q_rot7[1], q_rot7[2]); __syncthreads(); apply1(st, t, 4, m); }
    { M2 m = mrot(ang[6], ang[7], ang[8]);          __syncthreads(); apply1(st, t, 5, m); }
    __syncthreads(); mrzg(st, t, 0xF8, q_mrz8[0]);
    __syncthreads(); mrzg(st, t, 0x6E, ang[5]);
    { M2 m = mrx(ang[6]);      __syncthreads(); capply1(st, t, 0, 1, m); }
    { M2 m = mrx(q_crx9[0]);   __syncthreads(); capply1(st, t, 4, 5, m); }
    { M2 m = mry(ang[6]);      __syncthreads(); capply1(st, t, 0, 1, m); }
    { M2 m = mry(q_cry10[0]);  __syncthreads(); capply1(st, t, 4, 5, m); }
    { float s, c; __sincosf(0.5f * ang[6], &s, &c);
      __syncthreads(); cdiag1(st, t, 0, 1, make_float2(c,-s), make_float2(c,s)); }
    { float s, c; __sincosf(0.5f * q_crz11[0], &s, &c);
      __syncthreads(); cdiag1(st, t, 4, 5, make_float2(c,-s), make_float2(c,s)); }
    { M2 m = mrot(-PI_F/4.f, PI_F/4.f, PI_F/2.f); __syncthreads(); capply1(st, t, 5, 6, m); }
    { M2 m = mrot(ang[5], ang[6], ang[7]);        __syncthreads(); capply1(st, t, 7, 8, m); }
    { float s, c; __sincosf(PI_F/7.f, &s, &c);
      __syncthreads(); diag1(st, t, 1, make_float2(1.f,0.f), make_float2(c,s)); }
    { float s, c; __sincosf(ang[9], &s, &c);
      __syncthreads(); diag1(st, t, 2, make_float2(1.f,0.f), make_float2(c,s)); }
    { M2 m = mu2(q_u2[0], q_u2[1]); __syncthreads(); apply1(st, t, 8, m); }
    { M2 m = mu2(ang[0], ang[1]);   __syncthreads(); apply1(st, t, 4, m); }
    { M2 m = mu3(q_u3[0], q_u3[1], q_u3[2]); __syncthreads(); apply1(st, t, 5, m); }
    { M2 m = mu3(ang[4], ang[5], ang[6]);    __syncthreads(); apply1(st, t, 5, m); }
    __syncthreads(); cnotg(st, t, 1, 2);
    __syncthreads();
    float loc[10];
#pragma unroll
    for (int w = 0; w < 10; ++w) {
        int p = 9 - w;
        int i0 = ins1(t, p), i1 = i0 | (1 << p);
        float2 a = st[i0], c = st[i1];
        loc[w] = 2.f * (a.x * c.y - a.y * c.x);
    }
    int lane = t & 63, wvv = t >> 6;
#pragma unroll
    for (int w = 0; w < 10; ++w) {
        float v = loc[w];
        v += __shfl_down(v, 32); v += __shfl_down(v, 16); v += __shfl_down(v, 8);
        v += __shfl_down(v, 4);  v += __shfl_down(v, 2);  v += __shfl_down(v, 1);
        if (lane == 0) red[wvv][w] = v;
    }
    __syncthreads();
    if (t < 10) {
        float e = 0.f;
#pragma unroll
        for (int i = 0; i < 8; ++i) e += red[i][t];
        evs[t] = e;
    }
    __syncthreads();
    if (t < 10) {
        float mx = evs[0];
#pragma unroll
        for (int i = 1; i < 10; ++i) mx = fmaxf(mx, evs[i]);
        float ss = 0.f;
#pragma unroll
        for (int i = 0; i < 10; ++i) ss += expf(evs[i] - mx);
        outf[t] = evs[t] - mx - logf(ss);
    }
}
template <int NT>
__device__ __forceinline__ void conv_stage(
    float* buf, int n, int t,
    const float* __restrict__ x, const float* __restrict__ w1, const float* __restrict__ b1,
    const float* __restrict__ w2, const float* __restrict__ b2)
{
    float* xs  = buf;
    float* w1s = buf + 784;
    float* h1s = buf + 1072;
    float* w2s = buf + 1748;
    const int ocq = t / 24, r = t - ocq * 24;
    const bool active = (t < 384);
    for (int i = t; i < 784; i += NT) xs[i] = x[n * 784 + i];
    for (int i = t; i < 288; i += NT) w1s[i] = w1[i];
    float acc[4][24];
#pragma unroll
    for (int j = 0; j < 4; ++j)
#pragma unroll
        for (int xo = 0; xo < 24; ++xo) acc[j][xo] = 0.f;
    for (int ic = 0; ic < 32; ++ic) {
        __syncthreads();
        float bb1 = b1[ic];
        for (int i = t; i < 676; i += NT) {
            int yy = i / 26, xx = i - yy * 26;
            const float* xp = xs + yy * 28 + xx;
            const float* wp = w1s + ic * 9;
            float s = bb1;
#pragma unroll
            for (int ky = 0; ky < 3; ++ky)
#pragma unroll
                for (int kx = 0; kx < 3; ++kx)
                    s += xp[ky * 28 + kx] * wp[ky * 3 + kx];
            h1s[i] = fmaxf(s, 0.f);
        }
        for (int i = t; i < 576; i += NT) {
            int oc = i / 9, k = i - oc * 9;
            w2s[i] = w2[oc * 288 + ic * 9 + k];
        }
        __syncthreads();
        if (active) {
            float wr[4][9];
#pragma unroll
            for (int j = 0; j < 4; ++j)
#pragma unroll
                for (int k = 0; k < 9; ++k)
                    wr[j][k] = w2s[(ocq * 4 + j) * 9 + k];
            float c0[3], c1[3];
#pragma unroll
            for (int q = 0; q < 3; ++q) { c0[q] = h1s[(r + q) * 26]; c1[q] = h1s[(r + q) * 26 + 1]; }
#pragma unroll
            for (int xo = 0; xo < 24; ++xo) {
                float c2[3];
#pragma unroll
                for (int q = 0; q < 3; ++q) c2[q] = h1s[(r + q) * 26 + xo + 2];
#pragma unroll
                for (int j = 0; j < 4; ++j) {
                    acc[j][xo] += wr[j][0]*c0[0] + wr[j][1]*c1[0] + wr[j][2]*c2[0]
                                + wr[j][3]*c0[1] + wr[j][4]*c1[1] + wr[j][5]*c2[1]
                                + wr[j][6]*c0[2] + wr[j][7]*c1[2] + wr[j][8]*c2[2];
                }
#pragma unroll
                for (int q = 0; q < 3; ++q) { c0[q] = c1[q]; c1[q] = c2[q]; }
            }
        }
    }
    __syncthreads();
    if (active && (r & 1)) {
#pragma unroll
        for (int j = 0; j < 4; ++j) {
            int oc = ocq * 4 + j;
            float bb = b2[oc];
#pragma unroll
            for (int px = 0; px < 12; ++px) {
                float v0 = fmaxf(acc[j][2*px]   + bb, 0.f);
                float v1 = fmaxf(acc[j][2*px+1] + bb, 0.f);
                buf[oc * 144 + (r >> 1) * 12 + px] = fmaxf(v0, v1);
            }
        }
    }
    __syncthreads();
    if (active && !(r & 1)) {
#pragma unroll
        for (int j = 0; j < 4; ++j) {
            int oc = ocq * 4 + j;
            float bb = b2[oc];
#pragma unroll
            for (int px = 0; px < 12; ++px) {
                float v0 = fmaxf(acc[j][2*px]   + bb, 0.f);
                float v1 = fmaxf(acc[j][2*px+1] + bb, 0.f);
                int idx = oc * 144 + (r >> 1) * 12 + px;
                buf[idx] = fmaxf(fmaxf(v0, v1), buf[idx]);
            }
        }
    }
    __syncthreads();
}
__global__ __launch_bounds__(512) void fused_kernel(
    const float* __restrict__ x, const float* __restrict__ w1, const float* __restrict__ b1,
    const float* __restrict__ w2, const float* __restrict__ b2,
    const float* __restrict__ fw1, const float* __restrict__ fb1,
    const float* __restrict__ fw2, const float* __restrict__ fb2,
    const float* __restrict__ q_rx, const float* __restrict__ q_rz3,
    const float* __restrict__ q_ps6, const float* __restrict__ q_rot7,
    const float* __restrict__ q_mrz8, const float* __restrict__ q_crx9,
    const float* __restrict__ q_cry10, const float* __restrict__ q_crz11,
    const float* __restrict__ q_u2, const float* __restrict__ q_u3,
    float* __restrict__ out)
{
    __shared__ float buf[9216];
    __shared__ float2 st[1024];
    __shared__ float hred[512];
    __shared__ float hvec[128];
    __shared__ float angs[10];
    __shared__ float red[8][10];
    __shared__ float evs[10];
    const int n = blockIdx.x, t = threadIdx.x;
    conv_stage<512>(buf, n, t, x, w1, b1, w2, b2);
    {
        const int j = t >> 2, q = t & 3;
        const float* wrow = fw1 + (size_t)j * 9216 + q * 2304;
        const float* arow = buf + q * 2304;
        float s = 0.f;
        for (int k = 0; k < 2304; k += 4) {
            float4 w = *(const float4*)(wrow + k);
            s += w.x * arow[k] + w.y * arow[k+1] + w.z * arow[k+2] + w.w * arow[k+3];
        }
        hred[t] = s;
    }
    __syncthreads();
    if (t < 128)
        hvec[t] = fmaxf(fb1[t] + hred[t*4] + hred[t*4+1] + hred[t*4+2] + hred[t*4+3], 0.f);
    __syncthreads();
    if (t < 10) {
        float d = fb2[t];
#pragma unroll 16
        for (int k = 0; k < 128; ++k) d += hvec[k] * fw2[t * 128 + k];
        angs[t] = 6.283185307179586f / (1.f + expf(-d));
    }
    __syncthreads();
    run_circ(st, red, evs, t, angs, q_rx, q_rz3, q_ps6, q_rot7, q_mrz8,
             q_crx9, q_cry10, q_crz11, q_u2, q_u3, out + n * 10);
}

// ===================== launch =====================
extern "C" void kernel_launch(void* const* d_in, const int* in_sizes, int n_in,
                              void* d_out, int out_size, void* d_ws, size_t ws_size,
                              hipStream_t stream)
{
    (void)in_sizes; (void)n_in;
    const float* x    = (const float*)d_in[0];
    const float* w1   = (const float*)d_in[1];
    const float* b1   = (const float*)d_in[2];
    const float* w2   = (const float*)d_in[3];
    const float* b2   = (const float*)d_in[4];
    const float* fw1  = (const float*)d_in[5];
    const float* fb1  = (const float*)d_in[6];
    const float* fw2  = (const float*)d_in[7];
    const float* fb2  = (const float*)d_in[8];
    const float* qrx  = (const float*)d_in[9];
    const float* qrz3 = (const float*)d_in[10];
    const float* qps6 = (const float*)d_in[11];
    const float* qrot7 = (const float*)d_in[12];
    const float* qmrz8 = (const float*)d_in[13];
    const float* qcrx9 = (const float*)d_in[14];
    const float* qcry10 = (const float*)d_in[15];
    const float* qcrz11 = (const float*)d_in[16];
    const float* qu2  = (const float*)d_in[17];
    const float* qu3  = (const float*)d_in[18];
    float* out = (float*)d_out;

    const size_t flat_bytes = (size_t)1024 * 9216 * 2;
    const size_t part_bytes = (size_t)16 * 1024 * 128 * 4;
    const size_t ang_bytes  = (size_t)1024 * 10 * 4;
    const size_t w2t_bytes  = (size_t)18432 * 2;
    const size_t fw1h_bytes = (size_t)128 * 9216 * 2;
    const size_t o_flat = 0;
    const size_t o_part = o_flat + flat_bytes;
    const size_t o_ang  = o_part + part_bytes;
    const size_t o_w2t  = o_ang + ang_bytes;
    const size_t o_fw1h = o_w2t + w2t_bytes;
    const size_t need   = o_fw1h + fw1h_bytes;

    (void)hipGetLastError();

    if (ws_size >= need) {
        _Float16* flat = (_Float16*)((char*)d_ws + o_flat);
        float*    part = (float*)((char*)d_ws + o_part);
        float*    angb = (float*)((char*)d_ws + o_ang);
        _Float16* w2t  = (_Float16*)((char*)d_ws + o_w2t);
        _Float16* fw1h = (_Float16*)((char*)d_ws + o_fw1h);
        prep_all<<<1224, 256, 0, stream>>>(fw1, fw1h, w2, w2t);
        convnet_mfma<<<1024, 256, 0, stream>>>(x, w1, b1, w2t, b2, flat);
        fc1_mfma<<<dim3(16, 2, 16), 256, 0, stream>>>(flat, fw1h, part);
        fc2_kernel<<<1024, 128, 0, stream>>>(part, fb1, fw2, fb2, angb);
        circuit_wave<<<256, 256, 0, stream>>>(angb, qrx, qrz3, qps6, qrot7, qmrz8,
                                              qcrx9, qcry10, qcrz11, qu2, qu3, out);
    } else {
        fused_kernel<<<1024, 512, 0, stream>>>(x, w1, b1, w2, b2, fw1, fb1, fw2, fb2,
                                               qrx, qrz3, qps6, qrot7, qmrz8,
                                               qcrx9, qcry10, qcrz11, qu2, qu3, out);
    }
    if (hipGetLastError() != hipSuccess) {
        (void)hipMemsetAsync(d_out, 0x7F, (size_t)out_size * 2, stream);
    }
}

// Round 12
// 180.014 us; speedup vs baseline: 1.0891x; 1.0363x over previous
//
#include <hip/hip_runtime.h>
#include <hip/hip_bf16.h>

#define PI_F 3.14159265358979323846f

// Loader insurance: keep a kernel with the stub's exact name (not launched).
__global__ void Static_82300163326800_kernel() {}

typedef _Float16 f16x8 __attribute__((ext_vector_type(8)));
typedef _Float16 f16x4 __attribute__((ext_vector_type(4)));
typedef float f32x4 __attribute__((ext_vector_type(4)));

// ===================== shared gate-matrix helpers =====================
struct M2 { float2 m00, m01, m10, m11; };

__device__ __forceinline__ float2 cmul2(float2 a, float2 b) {
    return make_float2(a.x*b.x - a.y*b.y, a.x*b.y + a.y*b.x);
}
__device__ __forceinline__ float2 cadd2(float2 a, float2 b) {
    return make_float2(a.x+b.x, a.y+b.y);
}
__device__ __forceinline__ M2 m2mul(M2 b, M2 a) {   // gate a first, then b => b*a
    return { cadd2(cmul2(b.m00,a.m00), cmul2(b.m01,a.m10)),
             cadd2(cmul2(b.m00,a.m01), cmul2(b.m01,a.m11)),
             cadd2(cmul2(b.m10,a.m00), cmul2(b.m11,a.m10)),
             cadd2(cmul2(b.m10,a.m01), cmul2(b.m11,a.m11)) };
}
__device__ __forceinline__ M2 mrx(float th) {
    float s, c; __sincosf(0.5f * th, &s, &c);
    return { make_float2(c,0.f), make_float2(0.f,-s), make_float2(0.f,-s), make_float2(c,0.f) };
}
__device__ __forceinline__ M2 mry(float th) {
    float s, c; __sincosf(0.5f * th, &s, &c);
    return { make_float2(c,0.f), make_float2(-s,0.f), make_float2(s,0.f), make_float2(c,0.f) };
}
__device__ __forceinline__ M2 mrzM(float th) {
    float s, c; __sincosf(0.5f * th, &s, &c);
    return { make_float2(c,-s), make_float2(0.f,0.f), make_float2(0.f,0.f), make_float2(c,s) };
}
__device__ __forceinline__ M2 mrot(float phi, float th, float om) {
    float s, c;  __sincosf(0.5f * th, &s, &c);
    float sa, ca; __sincosf(0.5f * (phi + om), &sa, &ca);
    float sd, cd; __sincosf(0.5f * (phi - om), &sd, &cd);
    return { make_float2(ca*c, -sa*c), make_float2(-cd*s, -sd*s),
             make_float2(cd*s, -sd*s), make_float2(ca*c,  sa*c) };
}
__device__ __forceinline__ M2 mu2(float phi, float lam) {
    const float r = 0.7071067811865476f;
    float sl, cl;   __sincosf(lam, &sl, &cl);
    float sp, cp;   __sincosf(phi, &sp, &cp);
    float spl, cpl; __sincosf(phi + lam, &spl, &cpl);
    return { make_float2(r,0.f), make_float2(-r*cl,-r*sl),
             make_float2(r*cp, r*sp), make_float2(r*cpl, r*spl) };
}
__device__ __forceinline__ M2 mu3(float th, float phi, float lam) {
    float s, c;     __sincosf(0.5f * th, &s, &c);
    float sl, cl;   __sincosf(lam, &sl, &cl);
    float sp, cp;   __sincosf(phi, &sp, &cp);
    float spl, cpl; __sincosf(phi + lam, &spl, &cpl);
    return { make_float2(c,0.f), make_float2(-cl*s,-sl*s),
             make_float2(cp*s, sp*s), make_float2(cpl*c, spl*c) };
}

// ===================== per-wave register circuit primitives =====================
// Amplitude index i = (lane<<4) | r.  wire w<=5 -> lane bit (5-w); w>=6 -> r bit (9-w).
// Two-phase shuffle batches (all shfls, then math) so they stay in flight.

__device__ __forceinline__ void applyL(float2* s, M2 m, int lane, int q) {
    const int bitv = (lane >> q) & 1;
    const float2 cA = bitv ? m.m11 : m.m00;
    const float2 cB = bitv ? m.m10 : m.m01;
    float ox[16], oy[16];
#pragma unroll
    for (int r = 0; r < 16; ++r) {
        ox[r] = __shfl_xor(s[r].x, 1 << q);
        oy[r] = __shfl_xor(s[r].y, 1 << q);
    }
#pragma unroll
    for (int r = 0; r < 16; ++r)
        s[r] = make_float2(cA.x*s[r].x - cA.y*s[r].y + cB.x*ox[r] - cB.y*oy[r],
                           cA.x*s[r].y + cA.y*s[r].x + cB.x*oy[r] + cB.y*ox[r]);
}
template<int P>
__device__ __forceinline__ void applyR(float2* s, M2 m) {
#pragma unroll
    for (int r0 = 0; r0 < 16; ++r0) {
        if (r0 & (1 << P)) continue;
        const int r1 = r0 | (1 << P);
        float2 a = s[r0], d = s[r1];
        s[r0] = cadd2(cmul2(m.m00, a), cmul2(m.m01, d));
        s[r1] = cadd2(cmul2(m.m10, a), cmul2(m.m11, d));
    }
}
__device__ __forceinline__ void diagL(float2* s, float2 d0, float2 d1, int lane, int q) {
    const int bitv = (lane >> q) & 1;
    const float2 f = bitv ? d1 : d0;
#pragma unroll
    for (int r = 0; r < 16; ++r) s[r] = cmul2(f, s[r]);
}
template<int P>
__device__ __forceinline__ void diagR(float2* s, float2 d0, float2 d1) {
#pragma unroll
    for (int r = 0; r < 16; ++r) {
        const float2 f = (r & (1 << P)) ? d1 : d0;
        s[r] = cmul2(f, s[r]);
    }
}
__device__ __forceinline__ void cnotLL(float2* s, int lane, int qc, int qw) {
    const int cb = (lane >> qc) & 1;
    float ox[16], oy[16];
#pragma unroll
    for (int r = 0; r < 16; ++r) {
        ox[r] = __shfl_xor(s[r].x, 1 << qw);
        oy[r] = __shfl_xor(s[r].y, 1 << qw);
    }
#pragma unroll
    for (int r = 0; r < 16; ++r)
        s[r] = cb ? make_float2(ox[r], oy[r]) : s[r];
}
__device__ __forceinline__ void capplyLL(float2* s, M2 m, int lane, int qc, int qw) {
    const int cb = (lane >> qc) & 1, tb = (lane >> qw) & 1;
    float2 cA = tb ? m.m11 : m.m00;
    float2 cB = tb ? m.m10 : m.m01;
    cA = cb ? cA : make_float2(1.f, 0.f);
    cB = cb ? cB : make_float2(0.f, 0.f);
    float ox[16], oy[16];
#pragma unroll
    for (int r = 0; r < 16; ++r) {
        ox[r] = __shfl_xor(s[r].x, 1 << qw);
        oy[r] = __shfl_xor(s[r].y, 1 << qw);
    }
#pragma unroll
    for (int r = 0; r < 16; ++r)
        s[r] = make_float2(cA.x*s[r].x - cA.y*s[r].y + cB.x*ox[r] - cB.y*oy[r],
                           cA.x*s[r].y + cA.y*s[r].x + cB.x*oy[r] + cB.y*ox[r]);
}
__device__ __forceinline__ void cdiagLL(float2* s, float2 d0, float2 d1, int lane, int qc, int qw) {
    const int cb = (lane >> qc) & 1, tb = (lane >> qw) & 1;
    float2 f = tb ? d1 : d0;
    f = cb ? f : make_float2(1.f, 0.f);
#pragma unroll
    for (int r = 0; r < 16; ++r) s[r] = cmul2(f, s[r]);
}
template<int P>
__device__ __forceinline__ void capplyRL(float2* s, M2 m, int lane, int qc) {
    const int cb = (lane >> qc) & 1;
#pragma unroll
    for (int r0 = 0; r0 < 16; ++r0) {
        if (r0 & (1 << P)) continue;
        const int r1 = r0 | (1 << P);
        float2 a = s[r0], d = s[r1];
        float2 na = cadd2(cmul2(m.m00, a), cmul2(m.m01, d));
        float2 nd = cadd2(cmul2(m.m10, a), cmul2(m.m11, d));
        s[r0] = cb ? na : a;
        s[r1] = cb ? nd : d;
    }
}

// ===================== per-wave circuit kernel: 1 wave = 1 sample ==============
// r11 config (measured-fast) + algebraic gate fusion:
//  - L1 RX(q_rx[k]) and L2 RY(ang[k]) fused per wire (commute through other wires);
//    wire0 additionally absorbs the ten commuting RX(ang0) = RX(10*ang0).
//  - CRX;CRY;CRZ on (0,1) and on (4,5) fused into two controlled-U gates.
//  - T*RX(-pi/4) on wire5 and PS(ang7)*SX on wire7 folded (register-only wins).
__global__ __launch_bounds__(256, 1) void circuit_wave(
    const float* __restrict__ ang_g,
    const float* __restrict__ q_rx, const float* __restrict__ q_rz3,
    const float* __restrict__ q_ps6, const float* __restrict__ q_rot7,
    const float* __restrict__ q_mrz8, const float* __restrict__ q_crx9,
    const float* __restrict__ q_cry10, const float* __restrict__ q_crz11,
    const float* __restrict__ q_u2, const float* __restrict__ q_u3,
    float* __restrict__ out)
{
    const int t = threadIdx.x, lane = t & 63, wv = t >> 6;
    const int b = blockIdx.x * 4 + wv;
    float ang[10];
#pragma unroll
    for (int j = 0; j < 10; ++j) ang[j] = ang_g[b * 10 + j];

    float2 s[16];
#pragma unroll
    for (int r = 0; r < 16; ++r) s[r] = make_float2(0.f, 0.f);
    if (lane == 0) s[0].x = 1.f;

    // L1+L2 fused: G_k = RY(ang[k])*RX(q_rx[k]); wire0 also x RX(10*ang0).
    applyL(s, m2mul(mrx(10.f * ang[0]), m2mul(mry(ang[0]), mrx(q_rx[0]))), lane, 5);
    applyL(s, m2mul(mry(ang[1]), mrx(q_rx[1])), lane, 4);
    applyL(s, m2mul(mry(ang[2]), mrx(q_rx[2])), lane, 3);
    applyL(s, m2mul(mry(ang[3]), mrx(q_rx[3])), lane, 2);
    applyL(s, m2mul(mry(ang[4]), mrx(q_rx[4])), lane, 1);
    applyL(s, m2mul(mry(ang[5]), mrx(q_rx[5])), lane, 0);
    applyR<3>(s, m2mul(mry(ang[6]), mrx(q_rx[6])));
    applyR<2>(s, m2mul(mry(ang[7]), mrx(q_rx[7])));
    applyR<1>(s, m2mul(mry(ang[8]), mrx(q_rx[8])));
    applyR<0>(s, m2mul(mry(ang[9]), mrx(q_rx[9])));
    // CNOT ring (k,k+1) then (9,0)
    cnotLL(s, lane, 5, 4);
    cnotLL(s, lane, 4, 3);
    cnotLL(s, lane, 3, 2);
    cnotLL(s, lane, 2, 1);
    cnotLL(s, lane, 1, 0);
    { // (5,6): ctrl lane bit0, target r bit3
        const int cb = lane & 1;
#pragma unroll
        for (int r0 = 0; r0 < 8; ++r0) {
            float2 a = s[r0], d = s[r0 + 8];
            s[r0] = cb ? d : a; s[r0 + 8] = cb ? a : d;
        }
    }
    { // (6,7)
        float2 u;
        u = s[8];  s[8]  = s[12]; s[12] = u;
        u = s[9];  s[9]  = s[13]; s[13] = u;
        u = s[10]; s[10] = s[14]; s[14] = u;
        u = s[11]; s[11] = s[15]; s[15] = u;
    }
    { // (7,8)
        float2 u;
        u = s[4];  s[4]  = s[6];  s[6]  = u;
        u = s[5];  s[5]  = s[7];  s[7]  = u;
        u = s[12]; s[12] = s[14]; s[14] = u;
        u = s[13]; s[13] = s[15]; s[15] = u;
    }
    { // (8,9)
        float2 u;
        u = s[2];  s[2]  = s[3];  s[3]  = u;
        u = s[6];  s[6]  = s[7];  s[7]  = u;
        u = s[10]; s[10] = s[11]; s[11] = u;
        u = s[14]; s[14] = s[15]; s[15] = u;
    }
    { // (9,0): r bit0 ctrl, target lane bit5
        float ox[8], oy[8];
#pragma unroll
        for (int k = 0; k < 8; ++k) {
            ox[k] = __shfl_xor(s[2*k+1].x, 32);
            oy[k] = __shfl_xor(s[2*k+1].y, 32);
        }
#pragma unroll
        for (int k = 0; k < 8; ++k) s[2*k+1] = make_float2(ox[k], oy[k]);
    }

    applyL(s, mrx(ang[1]), lane, 4);
    { // wire5: RX(-pi/4) then T fused (gates in between act on other wires)
        M2 Tm = { make_float2(1.f,0.f), make_float2(0.f,0.f), make_float2(0.f,0.f),
                  make_float2(0.7071067811865476f, 0.7071067811865476f) };
        applyL(s, m2mul(Tm, mrx(-PI_F / 4.f)), lane, 0);
    }
    applyL(s, mry(ang[2]), lane, 3);
    { float sn, cs; __sincosf(0.5f * ang[3], &sn, &cs);
      diagL(s, make_float2(cs,-sn), make_float2(cs,sn), lane, 2); }          // RZ on 3
    diagL(s, make_float2(1.f,0.f), make_float2(0.f,1.f), lane, 1);           // S on 4
    { float sn, cs; __sincosf(0.5f * q_rz3[0], &sn, &cs);
      diagR<3>(s, make_float2(cs,-sn), make_float2(cs,sn)); }                // RZ on 6
    { // wire7: SX then PS(ang[7]) fused (intervening gates don't touch wire 7)
        float sn, cs; __sincosf(ang[7], &sn, &cs);
        M2 SXm = { make_float2(0.5f,0.5f), make_float2(0.5f,-0.5f),
                   make_float2(0.5f,-0.5f), make_float2(0.5f,0.5f) };
        M2 PSm = { make_float2(1.f,0.f), make_float2(0.f,0.f),
                   make_float2(0.f,0.f), make_float2(cs,sn) };
        applyR<2>(s, m2mul(PSm, SXm));
    }
    { // CZ;CNOT;CY on (0,5) fused: phase -i iff wire0 bit = 1
        const int cb = (lane >> 5) & 1;
#pragma unroll
        for (int r = 0; r < 16; ++r)
            s[r] = cb ? make_float2(s[r].y, -s[r].x) : s[r];
    }
    { // CY(3,8): ctrl lane bit2, target r bit1
        const int cb = (lane >> 2) & 1;
#pragma unroll
        for (int r0 = 0; r0 < 16; ++r0) {
            if (r0 & 2) continue;
            const int r1 = r0 | 2;
            float2 a = s[r0], d = s[r1];
            float2 na = make_float2(d.y, -d.x);
            float2 nd = make_float2(-a.y, a.x);
            s[r0] = cb ? na : a; s[r1] = cb ? nd : d;
        }
    }
    { // SWAP(2,3): lane bits 3,2
        const int pr = ((lane >> 3) & 1) ^ ((lane >> 2) & 1);
        float ox[16], oy[16];
#pragma unroll
        for (int r = 0; r < 16; ++r) {
            ox[r] = __shfl_xor(s[r].x, 12);
            oy[r] = __shfl_xor(s[r].y, 12);
        }
#pragma unroll
        for (int r = 0; r < 16; ++r)
            s[r] = pr ? make_float2(ox[r], oy[r]) : s[r];
    }
    { // CSWAP(4;5,6): ctrl lane bit1; swap lane bit0 <-> r bit3
        float ox[16], oy[16];
#pragma unroll
        for (int r = 0; r < 16; ++r) {
            ox[r] = __shfl_xor(s[r ^ 8].x, 1);
            oy[r] = __shfl_xor(s[r ^ 8].y, 1);
        }
        const int cb = (lane >> 1) & 1, lb = lane & 1;
#pragma unroll
        for (int r = 0; r < 16; ++r) {
            const int pr = cb & ((r & 8) ? (1 - lb) : lb);
            s[r] = pr ? make_float2(ox[r], oy[r]) : s[r];
        }
    }
    { // TOFF(8,5;0): ctrl r bit1 & lane bit0; target lane bit5
        const int lb = lane & 1;
        float ox[8], oy[8];
        const int idx8[8] = {2,3,6,7,10,11,14,15};
#pragma unroll
        for (int k = 0; k < 8; ++k) {
            ox[k] = __shfl_xor(s[idx8[k]].x, 32);
            oy[k] = __shfl_xor(s[idx8[k]].y, 32);
        }
#pragma unroll
        for (int k = 0; k < 8; ++k)
            s[idx8[k]] = lb ? make_float2(ox[k], oy[k]) : s[idx8[k]];
    }
    { float sn, cs; __sincosf(q_ps6[0], &sn, &cs);
      diagR<1>(s, make_float2(1.f,0.f), make_float2(cs,sn)); }               // PS on 8
    applyL(s, mrot(q_rot7[0], q_rot7[1], q_rot7[2]), lane, 1);               // ROT on 4
    applyL(s, mrot(ang[6], ang[7], ang[8]), lane, 0);                        // ROT on 5
    { // multiRZ(q_mrz8) wires (2,3,4,5,6)
        float sh, ch; __sincosf(0.5f * q_mrz8[0], &sh, &ch);
        const int lp = __popc(lane & 0xF) & 1;
        const float sg0 = lp ? sh : -sh;
#pragma unroll
        for (int r = 0; r < 16; ++r) {
            const float sg = (r & 8) ? -sg0 : sg0;
            float2 a = s[r];
            s[r] = make_float2(ch*a.x - sg*a.y, ch*a.y + sg*a.x);
        }
    }
    { // multiRZ(ang[5]) wires (3,4,6,7,8)
        float sh, ch; __sincosf(0.5f * ang[5], &sh, &ch);
        const int lp = __popc(lane & 6) & 1;
        const float sg0 = lp ? sh : -sh;
#pragma unroll
        for (int r = 0; r < 16; ++r) {
            const int rp = __popc(r & 14) & 1;
            const float sg = rp ? -sg0 : sg0;
            float2 a = s[r];
            s[r] = make_float2(ch*a.x - sg*a.y, ch*a.y + sg*a.x);
        }
    }
    { // CRX;CRY;CRZ fused: (0,1) with angle ang[6] thrice; (4,5) with q_crx9/q_cry10/q_crz11
        M2 U01 = m2mul(mrzM(ang[6]), m2mul(mry(ang[6]), mrx(ang[6])));
        capplyLL(s, U01, lane, 5, 4);
        M2 U45 = m2mul(mrzM(q_crz11[0]), m2mul(mry(q_cry10[0]), mrx(q_crx9[0])));
        capplyLL(s, U45, lane, 1, 0);
    }
    capplyRL<3>(s, mrot(-PI_F/4.f, PI_F/4.f, PI_F/2.f), lane, 0);            // CROT(5,6)
    { // CROT(7,8): pairs {4,5,12,13}
        M2 m = mrot(ang[5], ang[6], ang[7]);
        const int idx4[4] = {4, 5, 12, 13};
#pragma unroll
        for (int k = 0; k < 4; ++k) {
            const int r0 = idx4[k], r1 = r0 | 2;
            float2 a = s[r0], d = s[r1];
            s[r0] = cadd2(cmul2(m.m00, a), cmul2(m.m01, d));
            s[r1] = cadd2(cmul2(m.m10, a), cmul2(m.m11, d));
        }
    }
    { float sn, cs; __sincosf(PI_F / 7.f, &sn, &cs);
      diagL(s, make_float2(1.f,0.f), make_float2(cs,sn), lane, 4); }         // U1 on 1
    { float sn, cs; __sincosf(ang[9], &sn, &cs);
      diagL(s, make_float2(1.f,0.f), make_float2(cs,sn), lane, 3); }         // PS on 2
    applyR<1>(s, mu2(q_u2[0], q_u2[1]));                                     // U2 on 8
    applyL(s, mu2(ang[0], ang[1]), lane, 1);                                 // U2 on 4
    applyL(s, m2mul(mu3(ang[4], ang[5], ang[6]),
                    mu3(q_u3[0], q_u3[1], q_u3[2])), lane, 0);               // U3*U3 on 5
    cnotLL(s, lane, 4, 3);                                                   // CNOT(1,2)

    // <Y_w> then log_softmax
    float ev[10];
#pragma unroll
    for (int w = 0; w < 6; ++w) {
        const int q = 5 - w;
        const int bitv = (lane >> q) & 1;
        float ox[16], oy[16];
#pragma unroll
        for (int r = 0; r < 16; ++r) {
            ox[r] = __shfl_xor(s[r].x, 1 << q);
            oy[r] = __shfl_xor(s[r].y, 1 << q);
        }
        float acc = 0.f;
#pragma unroll
        for (int r = 0; r < 16; ++r)
            acc += s[r].x * oy[r] - s[r].y * ox[r];
        ev[w] = bitv ? 0.f : 2.f * acc;
    }
#pragma unroll
    for (int w = 6; w < 10; ++w) {
        const int P = 9 - w;
        float acc = 0.f;
#pragma unroll
        for (int r0 = 0; r0 < 16; ++r0) {
            if (r0 & (1 << P)) continue;
            const int r1 = r0 | (1 << P);
            acc += s[r0].x * s[r1].y - s[r0].y * s[r1].x;
        }
        ev[w] = 2.f * acc;
    }
#pragma unroll
    for (int w = 0; w < 10; ++w) {
        float v = ev[w];
        v += __shfl_down(v, 32); v += __shfl_down(v, 16); v += __shfl_down(v, 8);
        v += __shfl_down(v, 4);  v += __shfl_down(v, 2);  v += __shfl_down(v, 1);
        ev[w] = v;
    }
    if (lane == 0) {
        float mx = ev[0];
#pragma unroll
        for (int i = 1; i < 10; ++i) mx = fmaxf(mx, ev[i]);
        float ss = 0.f;
#pragma unroll
        for (int i = 0; i < 10; ++i) ss += expf(ev[i] - mx);
        const float ls = logf(ss);
#pragma unroll
        for (int i = 0; i < 10; ++i) out[b * 10 + i] = ev[i] - mx - ls;
    }
}

// ============ prep (merged): fw1 -> f16 and w2 -> transposed f16 ============
__global__ __launch_bounds__(256) void prep_all(
    const float* __restrict__ fw1, _Float16* __restrict__ fw1h,
    const float* __restrict__ w2, _Float16* __restrict__ w2t)
{
    const int blk = blockIdx.x;
    if (blk < 1152) {
        int i = blk * 256 + threadIdx.x;   // 294912 float4 groups
        float4 v = ((const float4*)fw1)[i];
        f16x4 o = { (_Float16)v.x, (_Float16)v.y, (_Float16)v.z, (_Float16)v.w };
        *(f16x4*)(fw1h + i * 4) = o;
    } else {
        int idx = (blk - 1152) * 256 + threadIdx.x;
        if (idx < 18432) {
            int oc = idx / 288, r = idx - oc * 288;
            int s = r >> 5, ic = r & 31;
            w2t[idx] = (_Float16)w2[oc * 288 + ic * 9 + s];
        }
    }
}

// ===================== MFMA convnet =====================
__global__ __launch_bounds__(256, 2) void convnet_mfma(
    const float* __restrict__ x, const float* __restrict__ w1, const float* __restrict__ b1,
    const _Float16* __restrict__ w2t, const float* __restrict__ b2,
    _Float16* __restrict__ flat)
{
    __shared__ float xs[784];
    __shared__ __align__(16) float w1t[288];              // [k][ic] transposed
    __shared__ __align__(16) _Float16 h1t[676 * 40];      // [pix][ic], stride 40
    const int n = blockIdx.x, t = threadIdx.x;
    const int lane = t & 63, wv = t >> 6;
    const int m = lane & 15, quad = lane >> 4;

    for (int i = t; i < 784; i += 256) xs[i] = x[n * 784 + i];
    for (int i = t; i < 288; i += 256) {   // grid-stride: 288 > 256 (r8 bug fix)
        int ic = i / 9, k = i - ic * 9;
        w1t[k * 32 + ic] = w1[i];
    }
    __syncthreads();

    // conv1
    {
        const int icg = t & 3;
        float w[9][8];
#pragma unroll
        for (int k = 0; k < 9; ++k) {
            float4 a = *(const float4*)&w1t[k * 32 + icg * 8];
            float4 bsec = *(const float4*)&w1t[k * 32 + icg * 8 + 4];
            w[k][0] = a.x; w[k][1] = a.y; w[k][2] = a.z; w[k][3] = a.w;
            w[k][4] = bsec.x; w[k][5] = bsec.y; w[k][6] = bsec.z; w[k][7] = bsec.w;
        }
        float bb[8];
#pragma unroll
        for (int j = 0; j < 8; ++j) bb[j] = b1[icg * 8 + j];
        for (int pix = t >> 2; pix < 676; pix += 64) {
            const int yy = pix / 26, xx = pix - yy * 26;
            const float* xp = xs + yy * 28 + xx;
            float acc[8];
#pragma unroll
            for (int j = 0; j < 8; ++j) acc[j] = bb[j];
#pragma unroll
            for (int ky = 0; ky < 3; ++ky)
#pragma unroll
                for (int kx = 0; kx < 3; ++kx) {
                    const float xv = xp[ky * 28 + kx];
                    const int k = ky * 3 + kx;
#pragma unroll
                    for (int j = 0; j < 8; ++j) acc[j] += xv * w[k][j];
                }
            f16x8 o;
#pragma unroll
            for (int j = 0; j < 8; ++j) o[j] = (_Float16)fmaxf(acc[j], 0.f);
            *(f16x8*)&h1t[pix * 40 + icg * 8] = o;
        }
    }

    f16x8 bq[9][4];
#pragma unroll
    for (int s = 0; s < 9; ++s)
#pragma unroll
        for (int nt = 0; nt < 4; ++nt)
            bq[s][nt] = *(const f16x8*)(w2t + (nt * 16 + m) * 288 + s * 32 + quad * 8);

    __syncthreads();

    float bb2[4];
#pragma unroll
    for (int nt = 0; nt < 4; ++nt) bb2[nt] = b2[nt * 16 + m];

    _Float16* outp = flat + (size_t)n * 9216;

    for (int q = 0; q < 9; ++q) {
        const int mt = wv + q * 4;
        const int a = mt / 3, b3 = mt - a * 3;
        const int y0 = 2 * a + (m & 1), x0 = 8 * b3 + (m >> 1);
        f32x4 acc[4] = {};
#pragma unroll
        for (int s = 0; s < 9; ++s) {
            const int ky = s / 3, kx = s - ky * 3;
            f16x8 af = *(const f16x8*)&h1t[((y0 + ky) * 26 + x0 + kx) * 40 + quad * 8];
#pragma unroll
            for (int nt = 0; nt < 4; ++nt)
                acc[nt] = __builtin_amdgcn_mfma_f32_16x16x32_f16(af, bq[s][nt], acc[nt], 0, 0, 0);
        }
        const int pooled_idx = a * 12 + 4 * b3 + quad;
#pragma unroll
        for (int nt = 0; nt < 4; ++nt) {
            float v = fmaxf(fmaxf(acc[nt][0], acc[nt][1]), fmaxf(acc[nt][2], acc[nt][3]));
            outp[(nt * 16 + m) * 144 + pooled_idx] = (_Float16)fmaxf(v + bb2[nt], 0.f);
        }
    }
}

// ===================== fc1 MFMA: [1024,9216]f16 @ [128,9216]^T f16, K split 16 ======
__global__ __launch_bounds__(256) void fc1_mfma(
    const _Float16* __restrict__ A, const _Float16* __restrict__ B, float* __restrict__ part)
{
    const int m0 = blockIdx.x * 64, n0 = blockIdx.y * 64, kb = blockIdx.z;
    const int t = threadIdx.x, lane = t & 63, wv = t >> 6;
    const int r = lane & 15, quad = lane >> 4;
    const _Float16* ap = A + (size_t)(m0 + wv * 16 + r) * 9216 + kb * 576 + quad * 8;
    const _Float16* bp = B + (size_t)(n0 + r) * 9216 + kb * 576 + quad * 8;
    f32x4 acc[4] = {};
    for (int ks = 0; ks < 576; ks += 32) {
        f16x8 af = *(const f16x8*)(ap + ks);
#pragma unroll
        for (int nt = 0; nt < 4; ++nt) {
            f16x8 bfr = *(const f16x8*)(bp + (size_t)nt * 16 * 9216 + ks);
            acc[nt] = __builtin_amdgcn_mfma_f32_16x16x32_f16(af, bfr, acc[nt], 0, 0, 0);
        }
    }
    float* pp = part + (size_t)kb * 131072 + (size_t)(m0 + wv * 16 + quad * 4) * 128 + n0 + r;
#pragma unroll
    for (int nt = 0; nt < 4; ++nt)
#pragma unroll
        for (int reg = 0; reg < 4; ++reg)
            pp[reg * 128 + nt * 16] = acc[nt][reg];
}

// ===================== fc2 + sigmoid*2pi (sums 16 split-K slabs) =====================
__global__ __launch_bounds__(128) void fc2_kernel(
    const float* __restrict__ part, const float* __restrict__ fb1,
    const float* __restrict__ fw2, const float* __restrict__ fb2, float* __restrict__ angO)
{
    __shared__ float h[128];
    const int b = blockIdx.x, t = threadIdx.x;
    float s = fb1[t];
#pragma unroll
    for (int kb = 0; kb < 16; ++kb) s += part[(size_t)kb * 131072 + b * 128 + t];
    h[t] = fmaxf(s, 0.f);
    __syncthreads();
    if (t < 10) {
        float d = fb2[t];
#pragma unroll 16
        for (int k = 0; k < 128; ++k) d += h[k] * fw2[t * 128 + k];
        angO[b * 10 + t] = 6.283185307179586f / (1.f + expf(-d));
    }
}

// ===================== FALLBACK: fully fused fp32, zero workspace =====================
__device__ __forceinline__ int ins1(int x, int p) {
    return ((x >> p) << (p + 1)) | (x & ((1 << p) - 1));
}
__device__ __forceinline__ void apply1(float2* st, int t, int w, M2 m) {
    int p = 9 - w;
    int i0 = ins1(t, p), i1 = i0 | (1 << p);
    float2 a = st[i0], d = st[i1];
    st[i0] = cadd2(cmul2(m.m00, a), cmul2(m.m01, d));
    st[i1] = cadd2(cmul2(m.m10, a), cmul2(m.m11, d));
}
__device__ __forceinline__ void diag1(float2* st, int t, int w, float2 d0, float2 d1) {
    int p = 9 - w;
    int i0 = ins1(t, p), i1 = i0 | (1 << p);
    st[i0] = cmul2(d0, st[i0]);
    st[i1] = cmul2(d1, st[i1]);
}
__device__ __forceinline__ void capply1(float2* st, int t, int c, int w, M2 m) {
    if (t < 256) {
        int pc = 9 - c, pw = 9 - w;
        int pl = pc < pw ? pc : pw, ph = pc + pw - pl;
        int base = ins1(ins1(t, pl), ph) | (1 << pc);
        int i0 = base, i1 = base | (1 << pw);
        float2 a = st[i0], d = st[i1];
        st[i0] = cadd2(cmul2(m.m00, a), cmul2(m.m01, d));
        st[i1] = cadd2(cmul2(m.m10, a), cmul2(m.m11, d));
    }
}
__device__ __forceinline__ void cdiag1(float2* st, int t, int c, int w, float2 d0, float2 d1) {
    if (t < 256) {
        int pc = 9 - c, pw = 9 - w;
        int pl = pc < pw ? pc : pw, ph = pc + pw - pl;
        int base = ins1(ins1(t, pl), ph) | (1 << pc);
        st[base] = cmul2(d0, st[base]);
        st[base | (1 << pw)] = cmul2(d1, st[base | (1 << pw)]);
    }
}
__device__ __forceinline__ void cnotg(float2* st, int t, int c, int w) {
    if (t < 256) {
        int pc = 9 - c, pw = 9 - w;
        int pl = pc < pw ? pc : pw, ph = pc + pw - pl;
        int base = ins1(ins1(t, pl), ph) | (1 << pc);
        int i1 = base | (1 << pw);
        float2 a = st[base]; st[base] = st[i1]; st[i1] = a;
    }
}
__device__ __forceinline__ void czg(float2* st, int t, int c, int w) {
    if (t < 256) {
        int pc = 9 - c, pw = 9 - w;
        int pl = pc < pw ? pc : pw, ph = pc + pw - pl;
        int i = ins1(ins1(t, pl), ph) | (1 << pc) | (1 << pw);
        st[i] = make_float2(-st[i].x, -st[i].y);
    }
}
__device__ __forceinline__ void swapg(float2* st, int t, int a, int b_) {
    if (t < 256) {
        int pa = 9 - a, pb = 9 - b_;
        int pl = pa < pb ? pa : pb, ph = pa + pb - pl;
        int base = ins1(ins1(t, pl), ph);
        int iA = base | (1 << pa), iB = base | (1 << pb);
        float2 u = st[iA]; st[iA] = st[iB]; st[iB] = u;
    }
}
__device__ __forceinline__ void cswap456f(float2* st, int t) {
    if (t < 128) {
        int base = ins1(ins1(ins1(t, 3), 4), 5) | (1 << 5);
        int iA = base | (1 << 4), iB = base | (1 << 3);
        float2 u = st[iA]; st[iA] = st[iB]; st[iB] = u;
    }
}
__device__ __forceinline__ void toff850f(float2* st, int t) {
    if (t < 128) {
        int base = ins1(ins1(ins1(t, 1), 4), 9) | (1 << 1) | (1 << 4);
        int i1 = base | (1 << 9);
        float2 u = st[base]; st[base] = st[i1]; st[i1] = u;
    }
}
__device__ __forceinline__ void mrzg(float2* st, int t, int mask, float th) {
    float sh, ch; __sincosf(0.5f * th, &sh, &ch);
#pragma unroll
    for (int q = 0; q < 2; ++q) {
        int i = t + q * 512;
        float sg = (__popc(i & mask) & 1) ? sh : -sh;
        float2 a = st[i];
        st[i] = make_float2(ch*a.x - sg*a.y, ch*a.y + sg*a.x);
    }
}
__device__ __forceinline__ void run_circ(
    float2* st, float (*red)[10], float* evs, int t, const float* ang,
    const float* q_rx, const float* q_rz3, const float* q_ps6, const float* q_rot7,
    const float* q_mrz8, const float* q_crx9, const float* q_cry10, const float* q_crz11,
    const float* q_u2, const float* q_u3, float* outf)
{
    st[t] = make_float2(t == 0 ? 1.f : 0.f, 0.f);
    st[t + 512] = make_float2(0.f, 0.f);
#pragma unroll
    for (int k = 0; k < 10; ++k) { M2 m = mrx(q_rx[k]); __syncthreads(); apply1(st, t, k, m); }
    {
        M2 mx0 = mrx(ang[0]);
#pragma unroll
        for (int k = 0; k < 10; ++k) {
            M2 m = mry(ang[k]); __syncthreads(); apply1(st, t, k, m);
            __syncthreads(); apply1(st, t, 0, mx0);
        }
    }
#pragma unroll
    for (int k = 0; k < 9; ++k) { __syncthreads(); cnotg(st, t, k, k + 1); }
    __syncthreads(); cnotg(st, t, 9, 0);
    { M2 m = mrx(ang[1]);      __syncthreads(); apply1(st, t, 1, m); }
    { M2 m = mrx(-PI_F / 4.f); __syncthreads(); apply1(st, t, 5, m); }
    { M2 m = mry(ang[2]);      __syncthreads(); apply1(st, t, 2, m); }
    { float s, c; __sincosf(0.5f * ang[3], &s, &c);
      __syncthreads(); diag1(st, t, 3, make_float2(c,-s), make_float2(c,s)); }
    __syncthreads(); diag1(st, t, 4, make_float2(1.f,0.f), make_float2(0.f,1.f));
    __syncthreads(); diag1(st, t, 5, make_float2(1.f,0.f),
                           make_float2(0.7071067811865476f, 0.7071067811865476f));
    { float s, c; __sincosf(0.5f * q_rz3[0], &s, &c);
      __syncthreads(); diag1(st, t, 6, make_float2(c,-s), make_float2(c,s)); }
    { M2 m = { make_float2(0.5f,0.5f), make_float2(0.5f,-0.5f),
               make_float2(0.5f,-0.5f), make_float2(0.5f,0.5f) };
      __syncthreads(); apply1(st, t, 7, m); }
    __syncthreads(); czg(st, t, 0, 5);
    __syncthreads(); cnotg(st, t, 0, 5);
    { M2 y = { make_float2(0.f,0.f), make_float2(0.f,-1.f),
               make_float2(0.f,1.f), make_float2(0.f,0.f) };
      __syncthreads(); capply1(st, t, 0, 5, y);
      __syncthreads(); capply1(st, t, 3, 8, y); }
    __syncthreads(); swapg(st, t, 2, 3);
    __syncthreads(); cswap456f(st, t);
    __syncthreads(); toff850f(st, t);
    { float s, c; __sincosf(q_ps6[0], &s, &c);
      __syncthreads(); diag1(st, t, 8, make_float2(1.f,0.f), make_float2(c,s)); }
    { float s, c; __sincosf(ang[7], &s, &c);
      __syncthreads(); diag1(st, t, 7, make_float2(1.f,0.f), make_float2(c,s)); }
    { M2 m = mrot(q_rot7[0], q_rot7[1], q_rot7[2]); __syncthreads(); apply1(st, t, 4, m); }
    { M2 m = mrot(ang[6], ang[7], ang[8]);          __syncthreads(); apply1(st, t, 5, m); }
    __syncthreads(); mrzg(st, t, 0xF8, q_mrz8[0]);
    __syncthreads(); mrzg(st, t, 0x6E, ang[5]);
    { M2 m = mrx(ang[6]);      __syncthreads(); capply1(st, t, 0, 1, m); }
    { M2 m = mrx(q_crx9[0]);   __syncthreads(); capply1(st, t, 4, 5, m); }
    { M2 m = mry(ang[6]);      __syncthreads(); capply1(st, t, 0, 1, m); }
    { M2 m = mry(q_cry10[0]);  __syncthreads(); capply1(st, t, 4, 5, m); }
    { float s, c; __sincosf(0.5f * ang[6], &s, &c);
      __syncthreads(); cdiag1(st, t, 0, 1, make_float2(c,-s), make_float2(c,s)); }
    { float s, c; __sincosf(0.5f * q_crz11[0], &s, &c);
      __syncthreads(); cdiag1(st, t, 4, 5, make_float2(c,-s), make_float2(c,s)); }
    { M2 m = mrot(-PI_F/4.f, PI_F/4.f, PI_F/2.f); __syncthreads(); capply1(st, t, 5, 6, m); }
    { M2 m = mrot(ang[5], ang[6], ang[7]);        __syncthreads(); capply1(st, t, 7, 8, m); }
    { float s, c; __sincosf(PI_F/7.f, &s, &c);
      __syncthreads(); diag1(st, t, 1, make_float2(1.f,0.f), make_float2(c,s)); }
    { float s, c; __sincosf(ang[9], &s, &c);
      __syncthreads(); diag1(st, t, 2, make_float2(1.f,0.f), make_float2(c,s)); }
    { M2 m = mu2(q_u2[0], q_u2[1]); __syncthreads(); apply1(st, t, 8, m); }
    { M2 m = mu2(ang[0], ang[1]);   __syncthreads(); apply1(st, t, 4, m); }
    { M2 m = mu3(q_u3[0], q_u3[1], q_u3[2]); __syncthreads(); apply1(st, t, 5, m); }
    { M2 m = mu3(ang[4], ang[5], ang[6]);    __syncthreads(); apply1(st, t, 5, m); }
    __syncthreads(); cnotg(st, t, 1, 2);
    __syncthreads();
    float loc[10];
#pragma unroll
    for (int w = 0; w < 10; ++w) {
        int p = 9 - w;
        int i0 = ins1(t, p), i1 = i0 | (1 << p);
        float2 a = st[i0], c = st[i1];
        loc[w] = 2.f * (a.x * c.y - a.y * c.x);
    }
    int lane = t & 63, wvv = t >> 6;
#pragma unroll
    for (int w = 0; w < 10; ++w) {
        float v = loc[w];
        v += __shfl_down(v, 32); v += __shfl_down(v, 16); v += __shfl_down(v, 8);
        v += __shfl_down(v, 4);  v += __shfl_down(v, 2);  v += __shfl_down(v, 1);
        if (lane == 0) red[wvv][w] = v;
    }
    __syncthreads();
    if (t < 10) {
        float e = 0.f;
#pragma unroll
        for (int i = 0; i < 8; ++i) e += red[i][t];
        evs[t] = e;
    }
    __syncthreads();
    if (t < 10) {
        float mx = evs[0];
#pragma unroll
        for (int i = 1; i < 10; ++i) mx = fmaxf(mx, evs[i]);
        float ss = 0.f;
#pragma unroll
        for (int i = 0; i < 10; ++i) ss += expf(evs[i] - mx);
        outf[t] = evs[t] - mx - logf(ss);
    }
}
template <int NT>
__device__ __forceinline__ void conv_stage(
    float* buf, int n, int t,
    const float* __restrict__ x, const float* __restrict__ w1, const float* __restrict__ b1,
    const float* __restrict__ w2, const float* __restrict__ b2)
{
    float* xs  = buf;
    float* w1s = buf + 784;
    float* h1s = buf + 1072;
    float* w2s = buf + 1748;
    const int ocq = t / 24, r = t - ocq * 24;
    const bool active = (t < 384);
    for (int i = t; i < 784; i += NT) xs[i] = x[n * 784 + i];
    for (int i = t; i < 288; i += NT) w1s[i] = w1[i];
    float acc[4][24];
#pragma unroll
    for (int j = 0; j < 4; ++j)
#pragma unroll
        for (int xo = 0; xo < 24; ++xo) acc[j][xo] = 0.f;
    for (int ic = 0; ic < 32; ++ic) {
        __syncthreads();
        float bb1 = b1[ic];
        for (int i = t; i < 676; i += NT) {
            int yy = i / 26, xx = i - yy * 26;
            const float* xp = xs + yy * 28 + xx;
            const float* wp = w1s + ic * 9;
            float s = bb1;
#pragma unroll
            for (int ky = 0; ky < 3; ++ky)
#pragma unroll
                for (int kx = 0; kx < 3; ++kx)
                    s += xp[ky * 28 + kx] * wp[ky * 3 + kx];
            h1s[i] = fmaxf(s, 0.f);
        }
        for (int i = t; i < 576; i += NT) {
            int oc = i / 9, k = i - oc * 9;
            w2s[i] = w2[oc * 288 + ic * 9 + k];
        }
        __syncthreads();
        if (active) {
            float wr[4][9];
#pragma unroll
            for (int j = 0; j < 4; ++j)
#pragma unroll
                for (int k = 0; k < 9; ++k)
                    wr[j][k] = w2s[(ocq * 4 + j) * 9 + k];
            float c0[3], c1[3];
#pragma unroll
            for (int q = 0; q < 3; ++q) { c0[q] = h1s[(r + q) * 26]; c1[q] = h1s[(r + q) * 26 + 1]; }
#pragma unroll
            for (int xo = 0; xo < 24; ++xo) {
                float c2[3];
#pragma unroll
                for (int q = 0; q < 3; ++q) c2[q] = h1s[(r + q) * 26 + xo + 2];
#pragma unroll
                for (int j = 0; j < 4; ++j) {
                    acc[j][xo] += wr[j][0]*c0[0] + wr[j][1]*c1[0] + wr[j][2]*c2[0]
                                + wr[j][3]*c0[1] + wr[j][4]*c1[1] + wr[j][5]*c2[1]
                                + wr[j][6]*c0[2] + wr[j][7]*c1[2] + wr[j][8]*c2[2];
                }
#pragma unroll
                for (int q = 0; q < 3; ++q) { c0[q] = c1[q]; c1[q] = c2[q]; }
            }
        }
    }
    __syncthreads();
    if (active && (r & 1)) {
#pragma unroll
        for (int j = 0; j < 4; ++j) {
            int oc = ocq * 4 + j;
            float bb = b2[oc];
#pragma unroll
            for (int px = 0; px < 12; ++px) {
                float v0 = fmaxf(acc[j][2*px]   + bb, 0.f);
                float v1 = fmaxf(acc[j][2*px+1] + bb, 0.f);
                buf[oc * 144 + (r >> 1) * 12 + px] = fmaxf(v0, v1);
            }
        }
    }
    __syncthreads();
    if (active && !(r & 1)) {
#pragma unroll
        for (int j = 0; j < 4; ++j) {
            int oc = ocq * 4 + j;
            float bb = b2[oc];
#pragma unroll
            for (int px = 0; px < 12; ++px) {
                float v0 = fmaxf(acc[j][2*px]   + bb, 0.f);
                float v1 = fmaxf(acc[j][2*px+1] + bb, 0.f);
                int idx = oc * 144 + (r >> 1) * 12 + px;
                buf[idx] = fmaxf(fmaxf(v0, v1), buf[idx]);
            }
        }
    }
    __syncthreads();
}
__global__ __launch_bounds__(512) void fused_kernel(
    const float* __restrict__ x, const float* __restrict__ w1, const float* __restrict__ b1,
    const float* __restrict__ w2, const float* __restrict__ b2,
    const float* __restrict__ fw1, const float* __restrict__ fb1,
    const float* __restrict__ fw2, const float* __restrict__ fb2,
    const float* __restrict__ q_rx, const float* __restrict__ q_rz3,
    const float* __restrict__ q_ps6, const float* __restrict__ q_rot7,
    const float* __restrict__ q_mrz8, const float* __restrict__ q_crx9,
    const float* __restrict__ q_cry10, const float* __restrict__ q_crz11,
    const float* __restrict__ q_u2, const float* __restrict__ q_u3,
    float* __restrict__ out)
{
    __shared__ float buf[9216];
    __shared__ float2 st[1024];
    __shared__ float hred[512];
    __shared__ float hvec[128];
    __shared__ float angs[10];
    __shared__ float red[8][10];
    __shared__ float evs[10];
    const int n = blockIdx.x, t = threadIdx.x;
    conv_stage<512>(buf, n, t, x, w1, b1, w2, b2);
    {
        const int j = t >> 2, q = t & 3;
        const float* wrow = fw1 + (size_t)j * 9216 + q * 2304;
        const float* arow = buf + q * 2304;
        float s = 0.f;
        for (int k = 0; k < 2304; k += 4) {
            float4 w = *(const float4*)(wrow + k);
            s += w.x * arow[k] + w.y * arow[k+1] + w.z * arow[k+2] + w.w * arow[k+3];
        }
        hred[t] = s;
    }
    __syncthreads();
    if (t < 128)
        hvec[t] = fmaxf(fb1[t] + hred[t*4] + hred[t*4+1] + hred[t*4+2] + hred[t*4+3], 0.f);
    __syncthreads();
    if (t < 10) {
        float d = fb2[t];
#pragma unroll 16
        for (int k = 0; k < 128; ++k) d += hvec[k] * fw2[t * 128 + k];
        angs[t] = 6.283185307179586f / (1.f + expf(-d));
    }
    __syncthreads();
    run_circ(st, red, evs, t, angs, q_rx, q_rz3, q_ps6, q_rot7, q_mrz8,
             q_crx9, q_cry10, q_crz11, q_u2, q_u3, out + n * 10);
}

// ===================== launch =====================
extern "C" void kernel_launch(void* const* d_in, const int* in_sizes, int n_in,
                              void* d_out, int out_size, void* d_ws, size_t ws_size,
                              hipStream_t stream)
{
    (void)in_sizes; (void)n_in;
    const float* x    = (const float*)d_in[0];
    const float* w1   = (const float*)d_in[1];
    const float* b1   = (const float*)d_in[2];
    const float* w2   = (const float*)d_in[3];
    const float* b2   = (const float*)d_in[4];
    const float* fw1  = (const float*)d_in[5];
    const float* fb1  = (const float*)d_in[6];
    const float* fw2  = (const float*)d_in[7];
    const float* fb2  = (const float*)d_in[8];
    const float* qrx  = (const float*)d_in[9];
    const float* qrz3 = (const float*)d_in[10];
    const float* qps6 = (const float*)d_in[11];
    const float* qrot7 = (const float*)d_in[12];
    const float* qmrz8 = (const float*)d_in[13];
    const float* qcrx9 = (const float*)d_in[14];
    const float* qcry10 = (const float*)d_in[15];
    const float* qcrz11 = (const float*)d_in[16];
    const float* qu2  = (const float*)d_in[17];
    const float* qu3  = (const float*)d_in[18];
    float* out = (float*)d_out;

    const size_t flat_bytes = (size_t)1024 * 9216 * 2;
    const size_t part_bytes = (size_t)16 * 1024 * 128 * 4;
    const size_t ang_bytes  = (size_t)1024 * 10 * 4;
    const size_t w2t_bytes  = (size_t)18432 * 2;
    const size_t fw1h_bytes = (size_t)128 * 9216 * 2;
    const size_t o_flat = 0;
    const size_t o_part = o_flat + flat_bytes;
    const size_t o_ang  = o_part + part_bytes;
    const size_t o_w2t  = o_ang + ang_bytes;
    const size_t o_fw1h = o_w2t + w2t_bytes;
    const size_t need   = o_fw1h + fw1h_bytes;

    (void)hipGetLastError();

    if (ws_size >= need) {
        _Float16* flat = (_Float16*)((char*)d_ws + o_flat);
        float*    part = (float*)((char*)d_ws + o_part);
        float*    angb = (float*)((char*)d_ws + o_ang);
        _Float16* w2t  = (_Float16*)((char*)d_ws + o_w2t);
        _Float16* fw1h = (_Float16*)((char*)d_ws + o_fw1h);
        prep_all<<<1224, 256, 0, stream>>>(fw1, fw1h, w2, w2t);
        convnet_mfma<<<1024, 256, 0, stream>>>(x, w1, b1, w2t, b2, flat);
        fc1_mfma<<<dim3(16, 2, 16), 256, 0, stream>>>(flat, fw1h, part);
        fc2_kernel<<<1024, 128, 0, stream>>>(part, fb1, fw2, fb2, angb);
        circuit_wave<<<256, 256, 0, stream>>>(angb, qrx, qrz3, qps6, qrot7, qmrz8,
                                              qcrx9, qcry10, qcrz11, qu2, qu3, out);
    } else {
        fused_kernel<<<1024, 512, 0, stream>>>(x, w1, b1, w2, b2, fw1, fb1, fw2, fb2,
                                               qrx, qrz3, qps6, qrot7, qmrz8,
                                               qcrx9, qcry10, qcrz11, qu2, qu3, out);
    }
    if (hipGetLastError() != hipSuccess) {
        (void)hipMemsetAsync(d_out, 0x7F, (size_t)out_size * 2, stream);
    }
}